// Round 1
// baseline (2472.837 us; speedup 1.0000x reference)
//
#include <hip/hip_runtime.h>
#include <hip/hip_bf16.h>

typedef unsigned int u32;
typedef unsigned long long u64;
typedef unsigned short u16;

typedef float f32x4 __attribute__((ext_vector_type(4)));
typedef __bf16 bf16x8 __attribute__((ext_vector_type(8)));
typedef unsigned short u16x8 __attribute__((ext_vector_type(8)));

#define FH 64
#define NPIX 4096
#define NA 36864          // 64*64*9 anchors
#define PRE_NMS 6000
#define NPROP 1000
#define KROI 50176        // 14*14*256
#define SORTN 8192
#define MASKW 94          // ceil(6000/64)
#define KSPLIT 8
#define KCHUNK (KROI / KSPLIT)  // 6272
#define BN_EPS 1e-3f

__device__ __forceinline__ u16 f2bf(float v) {
    __bf16 h = (__bf16)v;
    return __builtin_bit_cast(u16, h);
}
__device__ __forceinline__ bf16x8 ldfrag(const u16* p) {
    return __builtin_bit_cast(bf16x8, *(const u16x8*)p);
}

// ---------------------------------------------------------------------------
// Generic fp32 tiled GEMM: C[M][N] = A[M][K] @ B[K][N] (+bias, epilogues)
// EPI: 0 = +bias, 1 = relu(+bias), 2 = relu(bn(+bias))
// ---------------------------------------------------------------------------
template <int EPI>
__global__ __launch_bounds__(256) void gemm_f32(
    const float* __restrict__ A, const float* __restrict__ B, float* __restrict__ C,
    int M, int N, int K, const float* __restrict__ bias,
    const float* __restrict__ g, const float* __restrict__ be,
    const float* __restrict__ mu, const float* __restrict__ var) {
    __shared__ float As[16][68];
    __shared__ float Bs[16][68];
    const int bm = blockIdx.x * 64, bn = blockIdx.y * 64;
    const int tid = threadIdx.x, tx = tid & 15, ty = tid >> 4;
    float acc[4][4] = {};
    for (int k0 = 0; k0 < K; k0 += 16) {
#pragma unroll
        for (int i = 0; i < 4; ++i) {
            int e = tid + 256 * i; int kk = e & 15; int m = e >> 4;
            int gm = bm + m;
            As[kk][m] = (gm < M) ? A[(size_t)gm * K + k0 + kk] : 0.f;
        }
#pragma unroll
        for (int i = 0; i < 4; ++i) {
            int e = tid + 256 * i; int n = e & 63; int kk = e >> 6;
            int gn = bn + n;
            Bs[kk][n] = (gn < N) ? B[(size_t)(k0 + kk) * N + gn] : 0.f;
        }
        __syncthreads();
#pragma unroll
        for (int kk = 0; kk < 16; ++kk) {
            float4 ra = *(const float4*)&As[kk][ty * 4];
            float4 rb = *(const float4*)&Bs[kk][tx * 4];
            const float av[4] = {ra.x, ra.y, ra.z, ra.w};
            const float bv[4] = {rb.x, rb.y, rb.z, rb.w};
#pragma unroll
            for (int i = 0; i < 4; ++i)
#pragma unroll
                for (int j = 0; j < 4; ++j) acc[i][j] = fmaf(av[i], bv[j], acc[i][j]);
        }
        __syncthreads();
    }
#pragma unroll
    for (int i = 0; i < 4; ++i) {
        int gm = bm + ty * 4 + i;
        if (gm >= M) continue;
#pragma unroll
        for (int j = 0; j < 4; ++j) {
            int gn = bn + tx * 4 + j;
            if (gn >= N) continue;
            float v = acc[i][j] + bias[gn];
            if constexpr (EPI == 1) v = fmaxf(v, 0.f);
            if constexpr (EPI == 2) {
                float sc = g[gn] / sqrtf(var[gn] + BN_EPS);
                v = (v - mu[gn]) * sc + be[gn];
                v = fmaxf(v, 0.f);
            }
            C[(size_t)gm * N + gn] = v;
        }
    }
}

// ---------------------------------------------------------------------------
// 3x3 SAME conv as implicit-im2col GEMM. X: [64][64][256], B: [2304][N].
// One block per image row (m-tile = 64 cols). K=2304 in BK=16 chunks; each
// chunk lies in one (dy,dx) group since 16 | 256.
// ---------------------------------------------------------------------------
template <int EPI>
__global__ __launch_bounds__(256) void conv3_gemm(
    const float* __restrict__ X, const float* __restrict__ B, float* __restrict__ C,
    int N, const float* __restrict__ bias) {
    __shared__ float As[16][68];
    __shared__ float Bs[16][68];
    const int r = blockIdx.x;
    const int bn = blockIdx.y * 64;
    const int tid = threadIdx.x, tx = tid & 15, ty = tid >> 4;
    float acc[4][4] = {};
    for (int k0 = 0; k0 < 2304; k0 += 16) {
        const int g = k0 >> 8;
        const int dy = g / 3, dx = g - dy * 3;
        const int sr = r + dy - 1;
        const int ch0 = k0 & 255;
#pragma unroll
        for (int i = 0; i < 4; ++i) {
            int e = tid + 256 * i; int kk = e & 15; int m = e >> 4;
            int sc = m + dx - 1;
            float v = 0.f;
            if (sr >= 0 && sr < 64 && sc >= 0 && sc < 64)
                v = X[(size_t)((sr << 6) + sc) * 256 + ch0 + kk];
            As[kk][m] = v;
        }
#pragma unroll
        for (int i = 0; i < 4; ++i) {
            int e = tid + 256 * i; int n = e & 63; int kk = e >> 6;
            int gn = bn + n;
            Bs[kk][n] = (gn < N) ? B[(size_t)(k0 + kk) * N + gn] : 0.f;
        }
        __syncthreads();
#pragma unroll
        for (int kk = 0; kk < 16; ++kk) {
            float4 ra = *(const float4*)&As[kk][ty * 4];
            float4 rb = *(const float4*)&Bs[kk][tx * 4];
            const float av[4] = {ra.x, ra.y, ra.z, ra.w};
            const float bv[4] = {rb.x, rb.y, rb.z, rb.w};
#pragma unroll
            for (int i = 0; i < 4; ++i)
#pragma unroll
                for (int j = 0; j < 4; ++j) acc[i][j] = fmaf(av[i], bv[j], acc[i][j]);
        }
        __syncthreads();
    }
#pragma unroll
    for (int i = 0; i < 4; ++i) {
        int pm = (r << 6) + ty * 4 + i;
#pragma unroll
        for (int j = 0; j < 4; ++j) {
            int gn = bn + tx * 4 + j;
            if (gn >= N) continue;
            float v = acc[i][j] + bias[gn];
            if constexpr (EPI == 1) v = fmaxf(v, 0.f);
            C[(size_t)pm * N + gn] = v;
        }
    }
}

// ---------------------------------------------------------------------------
// RPN softmax pair -> probs (out0) + sort keys (score_bits<<32 | ~index)
// ---------------------------------------------------------------------------
__global__ __launch_bounds__(256) void rpn_probs_keys(
    const float* __restrict__ cls, float* __restrict__ out0, u64* __restrict__ keys) {
    int i = blockIdx.x * 256 + threadIdx.x;
    if (i >= NA) return;
    float l0 = cls[2 * i], l1 = cls[2 * i + 1];
    float m = fmaxf(l0, l1);
    float e0 = expf(l0 - m), e1 = expf(l1 - m);
    float s = e0 + e1;
    float p0 = e0 / s, p1 = e1 / s;
    out0[2 * i] = p0;
    out0[2 * i + 1] = p1;
    keys[i] = ((u64)__float_as_uint(p1) << 32) | (u64)(0xFFFFFFFFu - (u32)i);
}

// ---------------------------------------------------------------------------
// Exact 6000-th largest key via 8-pass MSB radix select (single block).
// ---------------------------------------------------------------------------
__global__ __launch_bounds__(1024) void radix_select(
    const u64* __restrict__ keys, u64* __restrict__ thresh, u32* __restrict__ counter) {
    __shared__ u32 hist[256];
    __shared__ u64 sPrefix, sMask;
    __shared__ int sRank;
    int tid = threadIdx.x;
    if (tid == 0) { sPrefix = 0; sMask = 0; sRank = PRE_NMS; }
    __syncthreads();
    for (int p = 56; p >= 0; p -= 8) {
        if (tid < 256) hist[tid] = 0;
        __syncthreads();
        u64 pref = sPrefix, msk = sMask;
        for (int i = tid; i < NA; i += 1024) {
            u64 k = keys[i];
            if ((k & msk) == pref) atomicAdd(&hist[(u32)((k >> p) & 255)], 1u);
        }
        __syncthreads();
        if (tid == 0) {
            int cum = 0, rank = sRank, sel = 0;
            for (int d = 255; d >= 0; --d) {
                int c = (int)hist[d];
                if (cum + c >= rank) { sel = d; sRank = rank - cum; break; }
                cum += c;
            }
            sPrefix = pref | ((u64)(u32)sel << p);
            sMask = msk | (0xFFull << p);
        }
        __syncthreads();
    }
    if (tid == 0) { thresh[0] = sPrefix; *counter = 0; }
}

__global__ __launch_bounds__(256) void compact_topk(
    const u64* __restrict__ keys, const u64* __restrict__ thresh,
    u32* __restrict__ counter, u64* __restrict__ skeys) {
    int i = blockIdx.x * 256 + threadIdx.x;
    if (i < SORTN - PRE_NMS) skeys[PRE_NMS + i] = 0;  // pad slots (never hit by atomics)
    if (i >= NA) return;
    u64 k = keys[i];
    if (k >= thresh[0]) {
        u32 pos = atomicAdd(counter, 1u);
        skeys[pos] = k;
    }
}

// Bitonic sort 8192 u64 keys, descending, in 64KB LDS (single block).
__global__ __launch_bounds__(1024) void sort_topk(u64* __restrict__ skeys) {
    __shared__ u64 s[SORTN];
    int tid = threadIdx.x;
    for (int i = tid; i < SORTN; i += 1024) s[i] = skeys[i];
    __syncthreads();
    for (int k = 2; k <= SORTN; k <<= 1) {
        for (int j = k >> 1; j > 0; j >>= 1) {
            for (int i = tid; i < SORTN; i += 1024) {
                int ixj = i ^ j;
                if (ixj > i) {
                    u64 a = s[i], b = s[ixj];
                    bool up = ((i & k) == 0);
                    bool sw = up ? (a < b) : (a > b);  // descending overall
                    if (sw) { s[i] = b; s[ixj] = a; }
                }
            }
            __syncthreads();
        }
    }
    for (int i = tid; i < SORTN; i += 1024) skeys[i] = s[i];
}

// ---------------------------------------------------------------------------
// decode anchors+deltas -> clipped, normalized proposals (6000 x 4)
// ---------------------------------------------------------------------------
__global__ __launch_bounds__(256) void decode_props(
    const u64* __restrict__ skeys, const float* __restrict__ deltas,
    const int* __restrict__ ih, const int* __restrict__ iw, float* __restrict__ props) {
    int i = blockIdx.x * 256 + threadIdx.x;
    if (i >= PRE_NMS) return;
    u32 idx = 0xFFFFFFFFu - (u32)(skeys[i] & 0xFFFFFFFFull);
    float H = (float)(*ih), W = (float)(*iw);
    int a = idx % 9;
    int cell = idx / 9;
    int r = cell >> 6, c = cell & 63;
    float sy = H / 64.0f, sx = W / 64.0f;
    float cy = ((float)r + 0.5f) * sy, cx = ((float)c + 0.5f) * sx;
    const float scales[3] = {64.f, 128.f, 256.f};
    const float ratios[3] = {0.5f, 1.f, 2.f};
    float sq = sqrtf(ratios[a % 3]);
    float scl = scales[a / 3];
    float ah = scl * sq, aw = scl / sq;
    float ay1 = cy - ah * 0.5f, ax1 = cx - aw * 0.5f;
    float h = ah, w = aw;  // ay2-ay1 == ah exactly
    float d0 = deltas[(size_t)idx * 4 + 0], d1 = deltas[(size_t)idx * 4 + 1];
    float d2 = deltas[(size_t)idx * 4 + 2], d3 = deltas[(size_t)idx * 4 + 3];
    float ncy = ay1 + 0.5f * h + d0 * h;
    float ncx = ax1 + 0.5f * w + d1 * w;
    float nh = h * expf(d2), nw = w * expf(d3);
    float y1 = ncy - 0.5f * nh, x1 = ncx - 0.5f * nw;
    float y2 = ncy + 0.5f * nh, x2 = ncx + 0.5f * nw;
    props[i * 4 + 0] = fminf(fmaxf(y1, 0.f), H) / H;
    props[i * 4 + 1] = fminf(fmaxf(x1, 0.f), W) / W;
    props[i * 4 + 2] = fminf(fmaxf(y2, 0.f), H) / H;
    props[i * 4 + 3] = fminf(fmaxf(x2, 0.f), W) / W;
}

// ---------------------------------------------------------------------------
// NMS: pairwise suppression bitmask, then single-wave greedy scan.
// ---------------------------------------------------------------------------
__global__ __launch_bounds__(256) void nms_masks(
    const float* __restrict__ props, u64* __restrict__ masks) {
    int i = blockIdx.x * 256 + threadIdx.x;
    int w = blockIdx.y;
    if (i >= PRE_NMS) return;
    float y1 = props[i * 4], x1 = props[i * 4 + 1], y2 = props[i * 4 + 2], x2 = props[i * 4 + 3];
    float ai = (y2 - y1) * (x2 - x1);
    u64 bits = 0;
    int jbase = w * 64;
    for (int b = 0; b < 64; ++b) {
        int j = jbase + b;
        if (j >= PRE_NMS) break;
        float by1 = props[j * 4], bx1 = props[j * 4 + 1], by2 = props[j * 4 + 2], bx2 = props[j * 4 + 3];
        float iy1 = fmaxf(y1, by1), ix1 = fmaxf(x1, bx1);
        float iy2 = fminf(y2, by2), ix2 = fminf(x2, bx2);
        float inter = fmaxf(iy2 - iy1, 0.f) * fmaxf(ix2 - ix1, 0.f);
        float aj = (by2 - by1) * (bx2 - bx1);
        float iou = inter / (ai + aj - inter + 1e-8f);
        if (iou > 0.7f) bits |= (1ull << b);
    }
    masks[(size_t)i * MASKW + w] = bits;
}

__global__ __launch_bounds__(64) void nms_greedy(
    const u64* __restrict__ masks, int* __restrict__ sel, int* __restrict__ keptOut) {
    int lane = threadIdx.x;
    u64 rem0 = 0, rem1 = 0;  // lane owns removed-words {lane, lane+64}
    int kept = 0;
    for (int j = 0; j < PRE_NMS && kept < NPROP; ++j) {
        int w = j >> 6;
        u64 word = (w < 64) ? rem0 : rem1;
        u64 wv = __shfl(word, w & 63);
        if (!((wv >> (j & 63)) & 1ull)) {
            if (lane == 0) sel[kept] = j;
            const u64* mrow = masks + (size_t)j * MASKW;
            if (lane < MASKW) rem0 |= mrow[lane];
            if (lane + 64 < MASKW) rem1 |= mrow[lane + 64];
            ++kept;
        }
    }
    if (lane == 0) *keptOut = kept;
}

__global__ __launch_bounds__(256) void write_proposals(
    const float* __restrict__ props, const int* __restrict__ sel,
    const int* __restrict__ keptPtr, float* __restrict__ out2) {
    int i = blockIdx.x * 256 + threadIdx.x;
    if (i >= NPROP * 4) return;
    int p = i >> 2, d = i & 3;
    int kept = *keptPtr;
    out2[i] = (p < kept) ? props[sel[p] * 4 + d] : 0.f;
}

// ---------------------------------------------------------------------------
// ROI-align: 14x14 bilinear samples per proposal -> bf16 rois [1000][196*256]
// ---------------------------------------------------------------------------
__global__ __launch_bounds__(256) void roi_align_k(
    const float* __restrict__ X2, const float* __restrict__ boxes, u16* __restrict__ rois) {
    int p = blockIdx.x;
    int c = threadIdx.x;
    float y1 = boxes[p * 4], x1 = boxes[p * 4 + 1], y2 = boxes[p * 4 + 2], x2 = boxes[p * 4 + 3];
    for (int py = 0; py < 14; ++py) {
        float ty = (float)py / 13.0f;
        float ys = (y1 + ty * (y2 - y1)) * 63.0f;
        float fy = fminf(fmaxf(floorf(ys), 0.f), 62.f);
        int y0 = (int)fy;
        float wy = fminf(fmaxf(ys - fy, 0.f), 1.f);
        for (int px = 0; px < 14; ++px) {
            float tx = (float)px / 13.0f;
            float xs = (x1 + tx * (x2 - x1)) * 63.0f;
            float fx = fminf(fmaxf(floorf(xs), 0.f), 62.f);
            int x0 = (int)fx;
            float wx = fminf(fmaxf(xs - fx, 0.f), 1.f);
            const float* r0 = X2 + (size_t)((y0) * 64 + x0) * 256 + c;
            const float* r1 = r0 + 64 * 256;
            float v00 = r0[0], v01 = r0[256];
            float v10 = r1[0], v11 = r1[256];
            float top = v00 * (1.f - wx) + v01 * wx;
            float bot = v10 * (1.f - wx) + v11 * wx;
            float v = top * (1.f - wy) + bot * wy;
            rois[((size_t)p * 196 + py * 14 + px) * 256 + c] = f2bf(v);
        }
    }
}

// ---------------------------------------------------------------------------
// w_rc1 [50176][1024] f32 -> transposed bf16 [1024][50176]
// ---------------------------------------------------------------------------
__global__ __launch_bounds__(256) void convert_w1(
    const float* __restrict__ Wf, u16* __restrict__ WT) {
    __shared__ u16 tile[64][65];
    int k0 = blockIdx.x * 64, n0 = blockIdx.y * 64;
    int tid = threadIdx.x;
#pragma unroll
    for (int i = 0; i < 16; ++i) {
        int e = tid + 256 * i; int kk = e >> 6; int n = e & 63;
        tile[kk][n] = f2bf(Wf[(size_t)(k0 + kk) * 1024 + n0 + n]);
    }
    __syncthreads();
#pragma unroll
    for (int i = 0; i < 16; ++i) {
        int e = tid + 256 * i; int nn = e >> 6; int kk = e & 63;
        WT[(size_t)(n0 + nn) * KROI + k0 + kk] = tile[kk][nn];
    }
}

// ---------------------------------------------------------------------------
// h1 GEMM: [1000][50176]bf16 @ [50176][1024]bf16 -> split-K partials f32
// 64x64 block tile, 4 waves of 32x32, mfma_f32_16x16x32_bf16.
// ---------------------------------------------------------------------------
__global__ __launch_bounds__(256) void h1_gemm(
    const u16* __restrict__ Abf, const u16* __restrict__ Bbf, float* __restrict__ part) {
    __shared__ u16 As[64][72];
    __shared__ u16 Bs[64][72];
    const int tid = threadIdx.x;
    const int bm = blockIdx.x * 64, bn = blockIdx.y * 64;
    const int ks = blockIdx.z;
    const size_t kbase = (size_t)ks * KCHUNK;
    const int wave = tid >> 6, lane = tid & 63;
    const int wm = (wave >> 1) * 32, wn = (wave & 1) * 32;
    const int fr = lane & 15, fg = lane >> 4;
    f32x4 acc[2][2] = {};
    const int srow = tid >> 2, soff = (tid & 3) * 16;
    const int gm = bm + srow;
    const size_t arow = (size_t)gm * KROI + soff;
    const size_t brow = (size_t)(bn + srow) * KROI + soff;
    for (int k0 = 0; k0 < KCHUNK; k0 += 64) {
        size_t gk = kbase + k0;
        u16x8 a0 = {0, 0, 0, 0, 0, 0, 0, 0}, a1 = {0, 0, 0, 0, 0, 0, 0, 0};
        if (gm < NPROP) {
            a0 = *(const u16x8*)&Abf[arow + gk];
            a1 = *(const u16x8*)&Abf[arow + gk + 8];
        }
        u16x8 b0 = *(const u16x8*)&Bbf[brow + gk];
        u16x8 b1 = *(const u16x8*)&Bbf[brow + gk + 8];
        __syncthreads();
        *(u16x8*)&As[srow][soff] = a0;
        *(u16x8*)&As[srow][soff + 8] = a1;
        *(u16x8*)&Bs[srow][soff] = b0;
        *(u16x8*)&Bs[srow][soff + 8] = b1;
        __syncthreads();
#pragma unroll
        for (int kk = 0; kk < 64; kk += 32) {
            bf16x8 fa0 = ldfrag(&As[wm + fr][kk + fg * 8]);
            bf16x8 fa1 = ldfrag(&As[wm + 16 + fr][kk + fg * 8]);
            bf16x8 fb0 = ldfrag(&Bs[wn + fr][kk + fg * 8]);
            bf16x8 fb1 = ldfrag(&Bs[wn + 16 + fr][kk + fg * 8]);
            acc[0][0] = __builtin_amdgcn_mfma_f32_16x16x32_bf16(fa0, fb0, acc[0][0], 0, 0, 0);
            acc[0][1] = __builtin_amdgcn_mfma_f32_16x16x32_bf16(fa0, fb1, acc[0][1], 0, 0, 0);
            acc[1][0] = __builtin_amdgcn_mfma_f32_16x16x32_bf16(fa1, fb0, acc[1][0], 0, 0, 0);
            acc[1][1] = __builtin_amdgcn_mfma_f32_16x16x32_bf16(fa1, fb1, acc[1][1], 0, 0, 0);
        }
    }
    float* P = part + ((size_t)ks << 20);
#pragma unroll
    for (int fi = 0; fi < 2; ++fi)
#pragma unroll
        for (int fj = 0; fj < 2; ++fj) {
            int r0 = bm + wm + fi * 16 + fg * 4;
            int c0 = bn + wn + fj * 16 + fr;
#pragma unroll
            for (int j = 0; j < 4; ++j) P[(size_t)(r0 + j) * 1024 + c0] = acc[fi][fj][j];
        }
}

__global__ __launch_bounds__(256) void reduce_h1(
    const float* __restrict__ part, const float* __restrict__ bias,
    const float* __restrict__ g, const float* __restrict__ be,
    const float* __restrict__ mu, const float* __restrict__ var, float* __restrict__ h1) {
    int i = blockIdx.x * 256 + threadIdx.x;
    if (i >= NPROP * 1024) return;
    int n = i & 1023, m = i >> 10;
    float s = 0.f;
#pragma unroll
    for (int k = 0; k < KSPLIT; ++k) s += part[((size_t)k << 20) + ((size_t)m << 10) + n];
    s += bias[n];
    float sc = g[n] / sqrtf(var[n] + BN_EPS);
    s = (s - mu[n]) * sc + be[n];
    h1[i] = fmaxf(s, 0.f);
}

__global__ __launch_bounds__(128) void softmax_cls(
    const float* __restrict__ logits, float* __restrict__ out3) {
    __shared__ float sm[128];
    int row = blockIdx.x, t = threadIdx.x;
    float v = (t < 81) ? logits[(size_t)row * 81 + t] : -1e30f;
    sm[t] = v;
    __syncthreads();
    for (int s = 64; s > 0; s >>= 1) {
        if (t < s) sm[t] = fmaxf(sm[t], sm[t + s]);
        __syncthreads();
    }
    float mx = sm[0];
    __syncthreads();
    float e = (t < 81) ? expf(v - mx) : 0.f;
    sm[t] = e;
    __syncthreads();
    for (int s = 64; s > 0; s >>= 1) {
        if (t < s) sm[t] += sm[t + s];
        __syncthreads();
    }
    float denom = sm[0];
    if (t < 81) out3[(size_t)row * 81 + t] = e / denom;
}

// ---------------------------------------------------------------------------
extern "C" void kernel_launch(void* const* d_in, const int* in_sizes, int n_in,
                              void* d_out, int out_size, void* d_ws, size_t ws_size,
                              hipStream_t stream) {
    const float* feature = (const float*)d_in[0];
    const float* w_fpn1 = (const float*)d_in[1];
    const float* b_fpn1 = (const float*)d_in[2];
    const float* w_fpn2 = (const float*)d_in[3];
    const float* b_fpn2 = (const float*)d_in[4];
    const float* w_rpn = (const float*)d_in[5];
    const float* b_rpn = (const float*)d_in[6];
    const float* w_cls = (const float*)d_in[7];
    const float* b_cls = (const float*)d_in[8];
    const float* w_dlt = (const float*)d_in[9];
    const float* b_dlt = (const float*)d_in[10];
    const float* w_rc1 = (const float*)d_in[11];
    const float* b_rc1 = (const float*)d_in[12];
    const float* g1 = (const float*)d_in[13];
    const float* be1 = (const float*)d_in[14];
    const float* m1 = (const float*)d_in[15];
    const float* v1 = (const float*)d_in[16];
    const float* w_rc2 = (const float*)d_in[17];
    const float* b_rc2 = (const float*)d_in[18];
    const float* g2 = (const float*)d_in[19];
    const float* be2 = (const float*)d_in[20];
    const float* m2 = (const float*)d_in[21];
    const float* v2 = (const float*)d_in[22];
    const float* w_log = (const float*)d_in[23];
    const float* b_log = (const float*)d_in[24];
    const float* w_bfc = (const float*)d_in[25];
    const float* b_bfc = (const float*)d_in[26];
    const int* image_h = (const int*)d_in[27];
    const int* image_w = (const int*)d_in[28];
    (void)in_sizes; (void)n_in; (void)out_size; (void)ws_size;

    float* out0 = (float*)d_out;          // rpn_probs  (36864,2)
    float* out1 = out0 + 73728;           // rpn_deltas (36864,4)
    float* out2 = out1 + 147456;          // proposals  (1000,4)
    float* out3 = out2 + 4000;            // cls_probs  (1000,81)
    float* out4 = out3 + 81000;           // box_deltas (1000,324)

    char* wsb = (char*)d_ws;
    size_t off = 0;
    auto take = [&](size_t b) -> void* {
        off = (off + 255) & ~(size_t)255;
        void* p = wsb + off;
        off += b;
        return p;
    };
    float* x1 = (float*)take((size_t)4096 * 256 * 4);
    float* x2 = (float*)take((size_t)4096 * 256 * 4);
    float* shr = (float*)take((size_t)4096 * 512 * 4);
    float* clsT = (float*)take((size_t)NA * 2 * 4);
    u64* keys = (u64*)take((size_t)NA * 8);
    u64* skeys = (u64*)take((size_t)SORTN * 8);
    float* props = (float*)take((size_t)PRE_NMS * 4 * 4);
    u64* masks = (u64*)take((size_t)PRE_NMS * MASKW * 8);
    int* sel = (int*)take((size_t)NPROP * 4);
    u64* misc = (u64*)take(256);
    u32* counter = (u32*)((char*)misc + 8);
    int* keptp = (int*)((char*)misc + 16);
    u16* rois = (u16*)take((size_t)NPROP * KROI * 2);
    u16* wT = (u16*)take((size_t)1024 * KROI * 2);
    float* part = (float*)take((size_t)KSPLIT * 1024 * 1024 * 4);
    float* h1 = (float*)take((size_t)NPROP * 1024 * 4);
    float* h2 = (float*)take((size_t)NPROP * 1024 * 4);
    float* logitsT = (float*)take((size_t)NPROP * 81 * 4);

    // RPN trunk (fp32 for score-ordering fidelity)
    gemm_f32<0><<<dim3(64, 4), 256, 0, stream>>>(feature, w_fpn1, x1, 4096, 256, 1024, b_fpn1, nullptr, nullptr, nullptr, nullptr);
    conv3_gemm<0><<<dim3(64, 4), 256, 0, stream>>>(x1, w_fpn2, x2, 256, b_fpn2);
    conv3_gemm<1><<<dim3(64, 8), 256, 0, stream>>>(x2, w_rpn, shr, 512, b_rpn);
    gemm_f32<0><<<dim3(64, 1), 256, 0, stream>>>(shr, w_cls, clsT, 4096, 18, 512, b_cls, nullptr, nullptr, nullptr, nullptr);
    gemm_f32<0><<<dim3(64, 1), 256, 0, stream>>>(shr, w_dlt, out1, 4096, 36, 512, b_dlt, nullptr, nullptr, nullptr, nullptr);
    rpn_probs_keys<<<dim3(144), 256, 0, stream>>>(clsT, out0, keys);

    // top-6000 (exact lax.top_k order) + NMS
    radix_select<<<1, 1024, 0, stream>>>(keys, misc, counter);
    compact_topk<<<dim3(144), 256, 0, stream>>>(keys, misc, counter, skeys);
    sort_topk<<<1, 1024, 0, stream>>>(skeys);
    decode_props<<<dim3(24), 256, 0, stream>>>(skeys, out1, image_h, image_w, props);
    nms_masks<<<dim3(24, 94), 256, 0, stream>>>(props, masks);
    nms_greedy<<<1, 64, 0, stream>>>(masks, sel, keptp);
    write_proposals<<<dim3(16), 256, 0, stream>>>(props, sel, keptp, out2);

    // ROI head
    convert_w1<<<dim3(784, 16), 256, 0, stream>>>(w_rc1, wT);
    roi_align_k<<<dim3(1000), 256, 0, stream>>>(x2, out2, rois);
    h1_gemm<<<dim3(16, 16, KSPLIT), 256, 0, stream>>>(rois, wT, part);
    reduce_h1<<<dim3(4000), 256, 0, stream>>>(part, b_rc1, g1, be1, m1, v1, h1);
    gemm_f32<2><<<dim3(16, 16), 256, 0, stream>>>(h1, w_rc2, h2, 1000, 1024, 1024, b_rc2, g2, be2, m2, v2);
    gemm_f32<0><<<dim3(16, 2), 256, 0, stream>>>(h2, w_log, logitsT, 1000, 81, 1024, b_log, nullptr, nullptr, nullptr, nullptr);
    gemm_f32<0><<<dim3(16, 6), 256, 0, stream>>>(h2, w_bfc, out4, 1000, 324, 1024, b_bfc, nullptr, nullptr, nullptr, nullptr);
    softmax_cls<<<dim3(1000), 128, 0, stream>>>(logitsT, out3);
}

// Round 2
// 2035.415 us; speedup vs baseline: 1.2149x; 1.2149x over previous
//
#include <hip/hip_runtime.h>
#include <hip/hip_bf16.h>

typedef unsigned int u32;
typedef unsigned long long u64;
typedef unsigned short u16;

typedef float f32x4 __attribute__((ext_vector_type(4)));
typedef __bf16 bf16x8 __attribute__((ext_vector_type(8)));
typedef unsigned short u16x8 __attribute__((ext_vector_type(8)));

#define FH 64
#define NPIX 4096
#define NA 36864          // 64*64*9 anchors
#define PRE_NMS 6000
#define NPROP 1000
#define KROI 50176        // 14*14*256
#define SORTN 8192
#define MASKW 94          // ceil(6000/64)
#define KSPLIT 8
#define KCHUNK (KROI / KSPLIT)  // 6272
#define BN_EPS 1e-3f

__device__ __forceinline__ u16 f2bf(float v) {
    __bf16 h = (__bf16)v;
    return __builtin_bit_cast(u16, h);
}
__device__ __forceinline__ bf16x8 ldfrag(const u16* p) {
    return __builtin_bit_cast(bf16x8, *(const u16x8*)p);
}

// ---------------------------------------------------------------------------
// Generic fp32 tiled GEMM: C[M][N] = A[M][K] @ B[K][N] (+bias, epilogues)
// EPI: 0 = +bias, 1 = relu(+bias), 2 = relu(bn(+bias))
// ---------------------------------------------------------------------------
template <int EPI>
__global__ __launch_bounds__(256) void gemm_f32(
    const float* __restrict__ A, const float* __restrict__ B, float* __restrict__ C,
    int M, int N, int K, const float* __restrict__ bias,
    const float* __restrict__ g, const float* __restrict__ be,
    const float* __restrict__ mu, const float* __restrict__ var) {
    __shared__ float As[16][68];
    __shared__ float Bs[16][68];
    const int bm = blockIdx.x * 64, bn = blockIdx.y * 64;
    const int tid = threadIdx.x, tx = tid & 15, ty = tid >> 4;
    float acc[4][4] = {};
    for (int k0 = 0; k0 < K; k0 += 16) {
#pragma unroll
        for (int i = 0; i < 4; ++i) {
            int e = tid + 256 * i; int kk = e & 15; int m = e >> 4;
            int gm = bm + m;
            As[kk][m] = (gm < M) ? A[(size_t)gm * K + k0 + kk] : 0.f;
        }
#pragma unroll
        for (int i = 0; i < 4; ++i) {
            int e = tid + 256 * i; int n = e & 63; int kk = e >> 6;
            int gn = bn + n;
            Bs[kk][n] = (gn < N) ? B[(size_t)(k0 + kk) * N + gn] : 0.f;
        }
        __syncthreads();
#pragma unroll
        for (int kk = 0; kk < 16; ++kk) {
            float4 ra = *(const float4*)&As[kk][ty * 4];
            float4 rb = *(const float4*)&Bs[kk][tx * 4];
            const float av[4] = {ra.x, ra.y, ra.z, ra.w};
            const float bv[4] = {rb.x, rb.y, rb.z, rb.w};
#pragma unroll
            for (int i = 0; i < 4; ++i)
#pragma unroll
                for (int j = 0; j < 4; ++j) acc[i][j] = fmaf(av[i], bv[j], acc[i][j]);
        }
        __syncthreads();
    }
#pragma unroll
    for (int i = 0; i < 4; ++i) {
        int gm = bm + ty * 4 + i;
        if (gm >= M) continue;
#pragma unroll
        for (int j = 0; j < 4; ++j) {
            int gn = bn + tx * 4 + j;
            if (gn >= N) continue;
            float v = acc[i][j] + bias[gn];
            if constexpr (EPI == 1) v = fmaxf(v, 0.f);
            if constexpr (EPI == 2) {
                float sc = g[gn] / sqrtf(var[gn] + BN_EPS);
                v = (v - mu[gn]) * sc + be[gn];
                v = fmaxf(v, 0.f);
            }
            C[(size_t)gm * N + gn] = v;
        }
    }
}

// ---------------------------------------------------------------------------
// 3x3 SAME conv as implicit-im2col GEMM. X: [64][64][256], B: [2304][N].
// ---------------------------------------------------------------------------
template <int EPI>
__global__ __launch_bounds__(256) void conv3_gemm(
    const float* __restrict__ X, const float* __restrict__ B, float* __restrict__ C,
    int N, const float* __restrict__ bias) {
    __shared__ float As[16][68];
    __shared__ float Bs[16][68];
    const int r = blockIdx.x;
    const int bn = blockIdx.y * 64;
    const int tid = threadIdx.x, tx = tid & 15, ty = tid >> 4;
    float acc[4][4] = {};
    for (int k0 = 0; k0 < 2304; k0 += 16) {
        const int g = k0 >> 8;
        const int dy = g / 3, dx = g - dy * 3;
        const int sr = r + dy - 1;
        const int ch0 = k0 & 255;
#pragma unroll
        for (int i = 0; i < 4; ++i) {
            int e = tid + 256 * i; int kk = e & 15; int m = e >> 4;
            int sc = m + dx - 1;
            float v = 0.f;
            if (sr >= 0 && sr < 64 && sc >= 0 && sc < 64)
                v = X[(size_t)((sr << 6) + sc) * 256 + ch0 + kk];
            As[kk][m] = v;
        }
#pragma unroll
        for (int i = 0; i < 4; ++i) {
            int e = tid + 256 * i; int n = e & 63; int kk = e >> 6;
            int gn = bn + n;
            Bs[kk][n] = (gn < N) ? B[(size_t)(k0 + kk) * N + gn] : 0.f;
        }
        __syncthreads();
#pragma unroll
        for (int kk = 0; kk < 16; ++kk) {
            float4 ra = *(const float4*)&As[kk][ty * 4];
            float4 rb = *(const float4*)&Bs[kk][tx * 4];
            const float av[4] = {ra.x, ra.y, ra.z, ra.w};
            const float bv[4] = {rb.x, rb.y, rb.z, rb.w};
#pragma unroll
            for (int i = 0; i < 4; ++i)
#pragma unroll
                for (int j = 0; j < 4; ++j) acc[i][j] = fmaf(av[i], bv[j], acc[i][j]);
        }
        __syncthreads();
    }
#pragma unroll
    for (int i = 0; i < 4; ++i) {
        int pm = (r << 6) + ty * 4 + i;
#pragma unroll
        for (int j = 0; j < 4; ++j) {
            int gn = bn + tx * 4 + j;
            if (gn >= N) continue;
            float v = acc[i][j] + bias[gn];
            if constexpr (EPI == 1) v = fmaxf(v, 0.f);
            C[(size_t)pm * N + gn] = v;
        }
    }
}

// ---------------------------------------------------------------------------
// RPN softmax pair -> probs (out0) + sort keys (score_bits<<32 | ~index)
// ---------------------------------------------------------------------------
__global__ __launch_bounds__(256) void rpn_probs_keys(
    const float* __restrict__ cls, float* __restrict__ out0, u64* __restrict__ keys) {
    int i = blockIdx.x * 256 + threadIdx.x;
    if (i >= NA) return;
    float l0 = cls[2 * i], l1 = cls[2 * i + 1];
    float m = fmaxf(l0, l1);
    float e0 = expf(l0 - m), e1 = expf(l1 - m);
    float s = e0 + e1;
    float p0 = e0 / s, p1 = e1 / s;
    out0[2 * i] = p0;
    out0[2 * i + 1] = p1;
    keys[i] = ((u64)__float_as_uint(p1) << 32) | (u64)(0xFFFFFFFFu - (u32)i);
}

// ---------------------------------------------------------------------------
// Exact 6000-th largest key via 8-pass MSB radix select (single block).
// ---------------------------------------------------------------------------
__global__ __launch_bounds__(1024) void radix_select(
    const u64* __restrict__ keys, u64* __restrict__ thresh, u32* __restrict__ counter) {
    __shared__ u32 hist[256];
    __shared__ u64 sPrefix, sMask;
    __shared__ int sRank;
    int tid = threadIdx.x;
    if (tid == 0) { sPrefix = 0; sMask = 0; sRank = PRE_NMS; }
    __syncthreads();
    for (int p = 56; p >= 0; p -= 8) {
        if (tid < 256) hist[tid] = 0;
        __syncthreads();
        u64 pref = sPrefix, msk = sMask;
        for (int i = tid; i < NA; i += 1024) {
            u64 k = keys[i];
            if ((k & msk) == pref) atomicAdd(&hist[(u32)((k >> p) & 255)], 1u);
        }
        __syncthreads();
        if (tid == 0) {
            int cum = 0, rank = sRank, sel = 0;
            for (int d = 255; d >= 0; --d) {
                int c = (int)hist[d];
                if (cum + c >= rank) { sel = d; sRank = rank - cum; break; }
                cum += c;
            }
            sPrefix = pref | ((u64)(u32)sel << p);
            sMask = msk | (0xFFull << p);
        }
        __syncthreads();
    }
    if (tid == 0) { thresh[0] = sPrefix; *counter = 0; }
}

__global__ __launch_bounds__(256) void compact_topk(
    const u64* __restrict__ keys, const u64* __restrict__ thresh,
    u32* __restrict__ counter, u64* __restrict__ skeys) {
    int i = blockIdx.x * 256 + threadIdx.x;
    if (i < SORTN - PRE_NMS) skeys[PRE_NMS + i] = 0;  // pad slots (never hit by atomics)
    if (i >= NA) return;
    u64 k = keys[i];
    if (k >= thresh[0]) {
        u32 pos = atomicAdd(counter, 1u);
        skeys[pos] = k;
    }
}

// Bitonic sort 8192 u64 keys, descending, in 64KB LDS (single block).
__global__ __launch_bounds__(1024) void sort_topk(u64* __restrict__ skeys) {
    __shared__ u64 s[SORTN];
    int tid = threadIdx.x;
    for (int i = tid; i < SORTN; i += 1024) s[i] = skeys[i];
    __syncthreads();
    for (int k = 2; k <= SORTN; k <<= 1) {
        for (int j = k >> 1; j > 0; j >>= 1) {
            for (int i = tid; i < SORTN; i += 1024) {
                int ixj = i ^ j;
                if (ixj > i) {
                    u64 a = s[i], b = s[ixj];
                    bool up = ((i & k) == 0);
                    bool sw = up ? (a < b) : (a > b);  // descending overall
                    if (sw) { s[i] = b; s[ixj] = a; }
                }
            }
            __syncthreads();
        }
    }
    for (int i = tid; i < SORTN; i += 1024) skeys[i] = s[i];
}

// ---------------------------------------------------------------------------
// decode anchors+deltas -> clipped, normalized proposals (6000 x 4)
// ---------------------------------------------------------------------------
__global__ __launch_bounds__(256) void decode_props(
    const u64* __restrict__ skeys, const float* __restrict__ deltas,
    const int* __restrict__ ih, const int* __restrict__ iw, float* __restrict__ props) {
    int i = blockIdx.x * 256 + threadIdx.x;
    if (i >= PRE_NMS) return;
    u32 idx = 0xFFFFFFFFu - (u32)(skeys[i] & 0xFFFFFFFFull);
    float H = (float)(*ih), W = (float)(*iw);
    int a = idx % 9;
    int cell = idx / 9;
    int r = cell >> 6, c = cell & 63;
    float sy = H / 64.0f, sx = W / 64.0f;
    float cy = ((float)r + 0.5f) * sy, cx = ((float)c + 0.5f) * sx;
    const float scales[3] = {64.f, 128.f, 256.f};
    const float ratios[3] = {0.5f, 1.f, 2.f};
    float sq = sqrtf(ratios[a % 3]);
    float scl = scales[a / 3];
    float ah = scl * sq, aw = scl / sq;
    float ay1 = cy - ah * 0.5f, ax1 = cx - aw * 0.5f;
    float h = ah, w = aw;
    float d0 = deltas[(size_t)idx * 4 + 0], d1 = deltas[(size_t)idx * 4 + 1];
    float d2 = deltas[(size_t)idx * 4 + 2], d3 = deltas[(size_t)idx * 4 + 3];
    float ncy = ay1 + 0.5f * h + d0 * h;
    float ncx = ax1 + 0.5f * w + d1 * w;
    float nh = h * expf(d2), nw = w * expf(d3);
    float y1 = ncy - 0.5f * nh, x1 = ncx - 0.5f * nw;
    float y2 = ncy + 0.5f * nh, x2 = ncx + 0.5f * nw;
    props[i * 4 + 0] = fminf(fmaxf(y1, 0.f), H) / H;
    props[i * 4 + 1] = fminf(fmaxf(x1, 0.f), W) / W;
    props[i * 4 + 2] = fminf(fmaxf(y2, 0.f), H) / H;
    props[i * 4 + 3] = fminf(fmaxf(x2, 0.f), W) / W;
}

// ---------------------------------------------------------------------------
// NMS: pairwise suppression bitmask (+ diagonal words), chunked greedy scan.
// ---------------------------------------------------------------------------
__global__ __launch_bounds__(256) void nms_masks(
    const float* __restrict__ props, u64* __restrict__ masks, u64* __restrict__ diag) {
    int i = blockIdx.x * 256 + threadIdx.x;
    int w = blockIdx.y;
    if (i >= PRE_NMS) return;
    float y1 = props[i * 4], x1 = props[i * 4 + 1], y2 = props[i * 4 + 2], x2 = props[i * 4 + 3];
    float ai = (y2 - y1) * (x2 - x1);
    u64 bits = 0;
    int jbase = w * 64;
    for (int b = 0; b < 64; ++b) {
        int j = jbase + b;
        if (j >= PRE_NMS) break;
        float by1 = props[j * 4], bx1 = props[j * 4 + 1], by2 = props[j * 4 + 2], bx2 = props[j * 4 + 3];
        float iy1 = fmaxf(y1, by1), ix1 = fmaxf(x1, bx1);
        float iy2 = fminf(y2, by2), ix2 = fminf(x2, bx2);
        float inter = fmaxf(iy2 - iy1, 0.f) * fmaxf(ix2 - ix1, 0.f);
        float aj = (by2 - by1) * (bx2 - bx1);
        float iou = inter / (ai + aj - inter + 1e-8f);
        if (iou > 0.7f) bits |= (1ull << b);
    }
    masks[(size_t)i * MASKW + w] = bits;
    if (w == (i >> 6)) diag[i] = bits;
}

// Chunked greedy scan: per 64-box chunk, in-register resolve via shfl chain
// over alive bits only; kept-row suppression OR'd in batches of 4 so the
// global loads overlap. Single wave.
__global__ __launch_bounds__(64) void nms_greedy(
    const u64* __restrict__ masks, const u64* __restrict__ diag,
    int* __restrict__ sel, int* __restrict__ keptOut) {
    __shared__ u64 sdiag[PRE_NMS];
    int lane = threadIdx.x;
    for (int i = lane; i < PRE_NMS; i += 64) sdiag[i] = diag[i];
    __syncthreads();
    u64 rem0 = 0, rem1 = 0;  // lane owns removed-words {lane, lane+64}
    int kept = 0;
    for (int c = 0; c < MASKW && kept < NPROP; ++c) {
        int jbase = c * 64;
        u64 word = (c < 64) ? rem0 : rem1;
        u64 removed = __shfl(word, c & 63);
        int limit = PRE_NMS - jbase;  // >= 48
        u64 alive = ~removed;
        if (limit < 64) alive &= (1ull << limit) - 1ull;
        if (!alive) continue;
        u64 mymask = (jbase + lane < PRE_NMS) ? sdiag[jbase + lane] : 0ull;
        u64 keptbits = 0;
        while (alive && kept < NPROP) {
            int b = __ffsll((long long)alive) - 1;
            alive &= ~(1ull << b);
            u64 m = __shfl(mymask, b);
            keptbits |= (1ull << b);
            if (lane == 0) sel[kept] = jbase + b;
            ++kept;
            alive &= ~m;
        }
        // propagate suppression: OR kept rows into distributed removed vector,
        // 4 rows per batch so loads overlap.
        u64 kb = keptbits;
        while (kb) {
            int b0 = __ffsll((long long)kb) - 1; kb &= kb - 1;
            int b1 = -1, b2 = -1, b3 = -1;
            if (kb) { b1 = __ffsll((long long)kb) - 1; kb &= kb - 1; }
            if (kb) { b2 = __ffsll((long long)kb) - 1; kb &= kb - 1; }
            if (kb) { b3 = __ffsll((long long)kb) - 1; kb &= kb - 1; }
            const u64* r0 = masks + (size_t)(jbase + b0) * MASKW;
            u64 a0 = r0[lane];
            u64 c0 = (lane < MASKW - 64) ? r0[lane + 64] : 0ull;
            u64 a1 = 0, c1 = 0, a2 = 0, c2 = 0, a3 = 0, c3 = 0;
            if (b1 >= 0) {
                const u64* r1 = masks + (size_t)(jbase + b1) * MASKW;
                a1 = r1[lane];
                c1 = (lane < MASKW - 64) ? r1[lane + 64] : 0ull;
            }
            if (b2 >= 0) {
                const u64* r2 = masks + (size_t)(jbase + b2) * MASKW;
                a2 = r2[lane];
                c2 = (lane < MASKW - 64) ? r2[lane + 64] : 0ull;
            }
            if (b3 >= 0) {
                const u64* r3 = masks + (size_t)(jbase + b3) * MASKW;
                a3 = r3[lane];
                c3 = (lane < MASKW - 64) ? r3[lane + 64] : 0ull;
            }
            rem0 |= (a0 | a1) | (a2 | a3);
            rem1 |= (c0 | c1) | (c2 | c3);
        }
    }
    if (lane == 0) *keptOut = kept;
}

__global__ __launch_bounds__(256) void write_proposals(
    const float* __restrict__ props, const int* __restrict__ sel,
    const int* __restrict__ keptPtr, float* __restrict__ out2) {
    int i = blockIdx.x * 256 + threadIdx.x;
    if (i >= NPROP * 4) return;
    int p = i >> 2, d = i & 3;
    int kept = *keptPtr;
    out2[i] = (p < kept) ? props[sel[p] * 4 + d] : 0.f;
}

// ---------------------------------------------------------------------------
// ROI-align: 14x14 bilinear samples per proposal -> bf16 rois [1000][196*256]
// ---------------------------------------------------------------------------
__global__ __launch_bounds__(256) void roi_align_k(
    const float* __restrict__ X2, const float* __restrict__ boxes, u16* __restrict__ rois) {
    int p = blockIdx.x;
    int c = threadIdx.x;
    float y1 = boxes[p * 4], x1 = boxes[p * 4 + 1], y2 = boxes[p * 4 + 2], x2 = boxes[p * 4 + 3];
    for (int py = 0; py < 14; ++py) {
        float ty = (float)py / 13.0f;
        float ys = (y1 + ty * (y2 - y1)) * 63.0f;
        float fy = fminf(fmaxf(floorf(ys), 0.f), 62.f);
        int y0 = (int)fy;
        float wy = fminf(fmaxf(ys - fy, 0.f), 1.f);
        for (int px = 0; px < 14; ++px) {
            float tx = (float)px / 13.0f;
            float xs = (x1 + tx * (x2 - x1)) * 63.0f;
            float fx = fminf(fmaxf(floorf(xs), 0.f), 62.f);
            int x0 = (int)fx;
            float wx = fminf(fmaxf(xs - fx, 0.f), 1.f);
            const float* r0 = X2 + (size_t)((y0) * 64 + x0) * 256 + c;
            const float* r1 = r0 + 64 * 256;
            float v00 = r0[0], v01 = r0[256];
            float v10 = r1[0], v11 = r1[256];
            float top = v00 * (1.f - wx) + v01 * wx;
            float bot = v10 * (1.f - wx) + v11 * wx;
            float v = top * (1.f - wy) + bot * wy;
            rois[((size_t)p * 196 + py * 14 + px) * 256 + c] = f2bf(v);
        }
    }
}

// ---------------------------------------------------------------------------
// w_rc1 [50176][1024] f32 -> transposed bf16 [1024][50176]
// ---------------------------------------------------------------------------
__global__ __launch_bounds__(256) void convert_w1(
    const float* __restrict__ Wf, u16* __restrict__ WT) {
    __shared__ u16 tile[64][65];
    int k0 = blockIdx.x * 64, n0 = blockIdx.y * 64;
    int tid = threadIdx.x;
#pragma unroll
    for (int i = 0; i < 16; ++i) {
        int e = tid + 256 * i; int kk = e >> 6; int n = e & 63;
        tile[kk][n] = f2bf(Wf[(size_t)(k0 + kk) * 1024 + n0 + n]);
    }
    __syncthreads();
#pragma unroll
    for (int i = 0; i < 16; ++i) {
        int e = tid + 256 * i; int nn = e >> 6; int kk = e & 63;
        WT[(size_t)(n0 + nn) * KROI + k0 + kk] = tile[kk][nn];
    }
}

// ---------------------------------------------------------------------------
// h1 GEMM: [1000][50176]bf16 @ [50176][1024]bf16 -> split-K partials f32
// ---------------------------------------------------------------------------
__global__ __launch_bounds__(256) void h1_gemm(
    const u16* __restrict__ Abf, const u16* __restrict__ Bbf, float* __restrict__ part) {
    __shared__ u16 As[64][72];
    __shared__ u16 Bs[64][72];
    const int tid = threadIdx.x;
    const int bm = blockIdx.x * 64, bn = blockIdx.y * 64;
    const int ks = blockIdx.z;
    const size_t kbase = (size_t)ks * KCHUNK;
    const int wave = tid >> 6, lane = tid & 63;
    const int wm = (wave >> 1) * 32, wn = (wave & 1) * 32;
    const int fr = lane & 15, fg = lane >> 4;
    f32x4 acc[2][2] = {};
    const int srow = tid >> 2, soff = (tid & 3) * 16;
    const int gm = bm + srow;
    const size_t arow = (size_t)gm * KROI + soff;
    const size_t brow = (size_t)(bn + srow) * KROI + soff;
    for (int k0 = 0; k0 < KCHUNK; k0 += 64) {
        size_t gk = kbase + k0;
        u16x8 a0 = {0, 0, 0, 0, 0, 0, 0, 0}, a1 = {0, 0, 0, 0, 0, 0, 0, 0};
        if (gm < NPROP) {
            a0 = *(const u16x8*)&Abf[arow + gk];
            a1 = *(const u16x8*)&Abf[arow + gk + 8];
        }
        u16x8 b0 = *(const u16x8*)&Bbf[brow + gk];
        u16x8 b1 = *(const u16x8*)&Bbf[brow + gk + 8];
        __syncthreads();
        *(u16x8*)&As[srow][soff] = a0;
        *(u16x8*)&As[srow][soff + 8] = a1;
        *(u16x8*)&Bs[srow][soff] = b0;
        *(u16x8*)&Bs[srow][soff + 8] = b1;
        __syncthreads();
#pragma unroll
        for (int kk = 0; kk < 64; kk += 32) {
            bf16x8 fa0 = ldfrag(&As[wm + fr][kk + fg * 8]);
            bf16x8 fa1 = ldfrag(&As[wm + 16 + fr][kk + fg * 8]);
            bf16x8 fb0 = ldfrag(&Bs[wn + fr][kk + fg * 8]);
            bf16x8 fb1 = ldfrag(&Bs[wn + 16 + fr][kk + fg * 8]);
            acc[0][0] = __builtin_amdgcn_mfma_f32_16x16x32_bf16(fa0, fb0, acc[0][0], 0, 0, 0);
            acc[0][1] = __builtin_amdgcn_mfma_f32_16x16x32_bf16(fa0, fb1, acc[0][1], 0, 0, 0);
            acc[1][0] = __builtin_amdgcn_mfma_f32_16x16x32_bf16(fa1, fb0, acc[1][0], 0, 0, 0);
            acc[1][1] = __builtin_amdgcn_mfma_f32_16x16x32_bf16(fa1, fb1, acc[1][1], 0, 0, 0);
        }
    }
    float* P = part + ((size_t)ks << 20);
#pragma unroll
    for (int fi = 0; fi < 2; ++fi)
#pragma unroll
        for (int fj = 0; fj < 2; ++fj) {
            int r0 = bm + wm + fi * 16 + fg * 4;
            int c0 = bn + wn + fj * 16 + fr;
#pragma unroll
            for (int j = 0; j < 4; ++j) P[(size_t)(r0 + j) * 1024 + c0] = acc[fi][fj][j];
        }
}

__global__ __launch_bounds__(256) void reduce_h1(
    const float* __restrict__ part, const float* __restrict__ bias,
    const float* __restrict__ g, const float* __restrict__ be,
    const float* __restrict__ mu, const float* __restrict__ var, float* __restrict__ h1) {
    int i = blockIdx.x * 256 + threadIdx.x;
    if (i >= NPROP * 1024) return;
    int n = i & 1023, m = i >> 10;
    float s = 0.f;
#pragma unroll
    for (int k = 0; k < KSPLIT; ++k) s += part[((size_t)k << 20) + ((size_t)m << 10) + n];
    s += bias[n];
    float sc = g[n] / sqrtf(var[n] + BN_EPS);
    s = (s - mu[n]) * sc + be[n];
    h1[i] = fmaxf(s, 0.f);
}

__global__ __launch_bounds__(128) void softmax_cls(
    const float* __restrict__ logits, float* __restrict__ out3) {
    __shared__ float sm[128];
    int row = blockIdx.x, t = threadIdx.x;
    float v = (t < 81) ? logits[(size_t)row * 81 + t] : -1e30f;
    sm[t] = v;
    __syncthreads();
    for (int s = 64; s > 0; s >>= 1) {
        if (t < s) sm[t] = fmaxf(sm[t], sm[t + s]);
        __syncthreads();
    }
    float mx = sm[0];
    __syncthreads();
    float e = (t < 81) ? expf(v - mx) : 0.f;
    sm[t] = e;
    __syncthreads();
    for (int s = 64; s > 0; s >>= 1) {
        if (t < s) sm[t] += sm[t + s];
        __syncthreads();
    }
    float denom = sm[0];
    if (t < 81) out3[(size_t)row * 81 + t] = e / denom;
}

// ---------------------------------------------------------------------------
extern "C" void kernel_launch(void* const* d_in, const int* in_sizes, int n_in,
                              void* d_out, int out_size, void* d_ws, size_t ws_size,
                              hipStream_t stream) {
    const float* feature = (const float*)d_in[0];
    const float* w_fpn1 = (const float*)d_in[1];
    const float* b_fpn1 = (const float*)d_in[2];
    const float* w_fpn2 = (const float*)d_in[3];
    const float* b_fpn2 = (const float*)d_in[4];
    const float* w_rpn = (const float*)d_in[5];
    const float* b_rpn = (const float*)d_in[6];
    const float* w_cls = (const float*)d_in[7];
    const float* b_cls = (const float*)d_in[8];
    const float* w_dlt = (const float*)d_in[9];
    const float* b_dlt = (const float*)d_in[10];
    const float* w_rc1 = (const float*)d_in[11];
    const float* b_rc1 = (const float*)d_in[12];
    const float* g1 = (const float*)d_in[13];
    const float* be1 = (const float*)d_in[14];
    const float* m1 = (const float*)d_in[15];
    const float* v1 = (const float*)d_in[16];
    const float* w_rc2 = (const float*)d_in[17];
    const float* b_rc2 = (const float*)d_in[18];
    const float* g2 = (const float*)d_in[19];
    const float* be2 = (const float*)d_in[20];
    const float* m2 = (const float*)d_in[21];
    const float* v2 = (const float*)d_in[22];
    const float* w_log = (const float*)d_in[23];
    const float* b_log = (const float*)d_in[24];
    const float* w_bfc = (const float*)d_in[25];
    const float* b_bfc = (const float*)d_in[26];
    const int* image_h = (const int*)d_in[27];
    const int* image_w = (const int*)d_in[28];
    (void)in_sizes; (void)n_in; (void)out_size; (void)ws_size;

    float* out0 = (float*)d_out;          // rpn_probs  (36864,2)
    float* out1 = out0 + 73728;           // rpn_deltas (36864,4)
    float* out2 = out1 + 147456;          // proposals  (1000,4)
    float* out3 = out2 + 4000;            // cls_probs  (1000,81)
    float* out4 = out3 + 81000;           // box_deltas (1000,324)

    char* wsb = (char*)d_ws;
    size_t off = 0;
    auto take = [&](size_t b) -> void* {
        off = (off + 255) & ~(size_t)255;
        void* p = wsb + off;
        off += b;
        return p;
    };
    float* x1 = (float*)take((size_t)4096 * 256 * 4);
    float* x2 = (float*)take((size_t)4096 * 256 * 4);
    float* shr = (float*)take((size_t)4096 * 512 * 4);
    float* clsT = (float*)take((size_t)NA * 2 * 4);
    u64* keys = (u64*)take((size_t)NA * 8);
    u64* skeys = (u64*)take((size_t)SORTN * 8);
    float* props = (float*)take((size_t)PRE_NMS * 4 * 4);
    u64* masks = (u64*)take((size_t)PRE_NMS * MASKW * 8);
    u64* diag = (u64*)take((size_t)PRE_NMS * 8);
    int* sel = (int*)take((size_t)NPROP * 4);
    u64* misc = (u64*)take(256);
    u32* counter = (u32*)((char*)misc + 8);
    int* keptp = (int*)((char*)misc + 16);
    u16* rois = (u16*)take((size_t)NPROP * KROI * 2);
    u16* wT = (u16*)take((size_t)1024 * KROI * 2);
    float* part = (float*)take((size_t)KSPLIT * 1024 * 1024 * 4);
    float* h1 = (float*)take((size_t)NPROP * 1024 * 4);
    float* h2 = (float*)take((size_t)NPROP * 1024 * 4);
    float* logitsT = (float*)take((size_t)NPROP * 81 * 4);

    // RPN trunk (fp32 for score-ordering fidelity)
    gemm_f32<0><<<dim3(64, 4), 256, 0, stream>>>(feature, w_fpn1, x1, 4096, 256, 1024, b_fpn1, nullptr, nullptr, nullptr, nullptr);
    conv3_gemm<0><<<dim3(64, 4), 256, 0, stream>>>(x1, w_fpn2, x2, 256, b_fpn2);
    conv3_gemm<1><<<dim3(64, 8), 256, 0, stream>>>(x2, w_rpn, shr, 512, b_rpn);
    gemm_f32<0><<<dim3(64, 1), 256, 0, stream>>>(shr, w_cls, clsT, 4096, 18, 512, b_cls, nullptr, nullptr, nullptr, nullptr);
    gemm_f32<0><<<dim3(64, 1), 256, 0, stream>>>(shr, w_dlt, out1, 4096, 36, 512, b_dlt, nullptr, nullptr, nullptr, nullptr);
    rpn_probs_keys<<<dim3(144), 256, 0, stream>>>(clsT, out0, keys);

    // top-6000 (exact lax.top_k order) + NMS
    radix_select<<<1, 1024, 0, stream>>>(keys, misc, counter);
    compact_topk<<<dim3(144), 256, 0, stream>>>(keys, misc, counter, skeys);
    sort_topk<<<1, 1024, 0, stream>>>(skeys);
    decode_props<<<dim3(24), 256, 0, stream>>>(skeys, out1, image_h, image_w, props);
    nms_masks<<<dim3(24, 94), 256, 0, stream>>>(props, masks, diag);
    nms_greedy<<<1, 64, 0, stream>>>(masks, diag, sel, keptp);
    write_proposals<<<dim3(16), 256, 0, stream>>>(props, sel, keptp, out2);

    // ROI head
    convert_w1<<<dim3(784, 16), 256, 0, stream>>>(w_rc1, wT);
    roi_align_k<<<dim3(1000), 256, 0, stream>>>(x2, out2, rois);
    h1_gemm<<<dim3(16, 16, KSPLIT), 256, 0, stream>>>(rois, wT, part);
    reduce_h1<<<dim3(4000), 256, 0, stream>>>(part, b_rc1, g1, be1, m1, v1, h1);
    gemm_f32<2><<<dim3(16, 16), 256, 0, stream>>>(h1, w_rc2, h2, 1000, 1024, 1024, b_rc2, g2, be2, m2, v2);
    gemm_f32<0><<<dim3(16, 2), 256, 0, stream>>>(h2, w_log, logitsT, 1000, 81, 1024, b_log, nullptr, nullptr, nullptr, nullptr);
    gemm_f32<0><<<dim3(16, 6), 256, 0, stream>>>(h2, w_bfc, out4, 1000, 324, 1024, b_bfc, nullptr, nullptr, nullptr, nullptr);
    softmax_cls<<<dim3(1000), 128, 0, stream>>>(logitsT, out3);
}

// Round 3
// 1727.202 us; speedup vs baseline: 1.4317x; 1.1784x over previous
//
#include <hip/hip_runtime.h>
#include <hip/hip_bf16.h>

typedef unsigned int u32;
typedef unsigned long long u64;
typedef unsigned short u16;

typedef float f32x4 __attribute__((ext_vector_type(4)));
typedef __bf16 bf16x8 __attribute__((ext_vector_type(8)));
typedef unsigned short u16x8 __attribute__((ext_vector_type(8)));
typedef unsigned short u16x4 __attribute__((ext_vector_type(4)));

#define FH 64
#define NPIX 4096
#define NA 36864          // 64*64*9 anchors
#define PRE_NMS 6000
#define NPROP 1000
#define KROI 50176        // 14*14*256
#define SORTN 8192
#define MASKW 94          // ceil(6000/64)
#define KSPLIT 8
#define KCHUNK (KROI / KSPLIT)  // 6272
#define BN_EPS 1e-3f

__device__ __forceinline__ u16 f2bf(float v) {
    __bf16 h = (__bf16)v;
    return __builtin_bit_cast(u16, h);
}
__device__ __forceinline__ bf16x8 ldfrag(const u16* p) {
    return __builtin_bit_cast(bf16x8, *(const u16x8*)p);
}

// ---------------------------------------------------------------------------
// gemm_v2: fp32 C[M][N] = A[M][K] @ B[K][N], 64x64 tile, 128 thr, 4x8/thread.
// CONV3: A is implicit-im2col of X[64][64][256] with 3x3 SAME halo
//        (blockIdx.x = image row, K = 2304).
// EPI: 0 = +bias, 1 = relu(+bias), 2 = relu(bn(+bias))
// Software-pipelined: next K-tile global loads issue before compute phase.
// Requires: N % 64 == 0, K % 16 == 0, bn+64 <= N. M guarded.
// ---------------------------------------------------------------------------
template <int EPI, bool CONV3>
__global__ __launch_bounds__(128) void gemm_v2(
    const float* __restrict__ A, const float* __restrict__ B, float* __restrict__ C,
    int M, int N, int K, const float* __restrict__ bias,
    const float* __restrict__ g, const float* __restrict__ be,
    const float* __restrict__ mu, const float* __restrict__ var) {
    __shared__ float As[16][68];
    __shared__ float Bs[16][68];
    const int tid = threadIdx.x;
    const int bm = blockIdx.x * 64, bn = blockIdx.y * 64;
    const int tx = tid & 7, ty = tid >> 3;  // ty 0..15

    float4 ra[2], rb[2];
    auto loadA = [&](int k0, int i) -> float4 {
        int e = tid + 128 * i;
        int m = e >> 2, kq = e & 3;
        float4 v = {0.f, 0.f, 0.f, 0.f};
        if (CONV3) {
            int gg = k0 >> 8;
            int dy = gg / 3, dx = gg - 3 * dy;
            int sr = (int)blockIdx.x + dy - 1;
            int sc = m + dx - 1;
            int ch = (k0 & 255) + 4 * kq;
            if (sr >= 0 && sr < 64 && sc >= 0 && sc < 64)
                v = *(const float4*)&A[(size_t)((sr << 6) + sc) * 256 + ch];
        } else {
            int gm = bm + m;
            if (gm < M) v = *(const float4*)&A[(size_t)gm * K + k0 + 4 * kq];
        }
        return v;
    };
    auto loadB = [&](int k0, int i) -> float4 {
        int e = tid + 128 * i;
        int n4 = e & 15, kk = e >> 4;
        return *(const float4*)&B[(size_t)(k0 + kk) * N + bn + 4 * n4];
    };

    ra[0] = loadA(0, 0); ra[1] = loadA(0, 1);
    rb[0] = loadB(0, 0); rb[1] = loadB(0, 1);

    float acc[4][8] = {};
    const int m0 = tid >> 2, kq0 = (tid & 3) * 4;
    const int m1 = (tid + 128) >> 2, kq1 = ((tid + 128) & 3) * 4;
    const int bkk0 = tid >> 4, bn40 = (tid & 15) * 4;
    const int bkk1 = (tid + 128) >> 4, bn41 = ((tid + 128) & 15) * 4;

    for (int k0 = 0; k0 < K; k0 += 16) {
        __syncthreads();
        As[kq0 + 0][m0] = ra[0].x; As[kq0 + 1][m0] = ra[0].y;
        As[kq0 + 2][m0] = ra[0].z; As[kq0 + 3][m0] = ra[0].w;
        As[kq1 + 0][m1] = ra[1].x; As[kq1 + 1][m1] = ra[1].y;
        As[kq1 + 2][m1] = ra[1].z; As[kq1 + 3][m1] = ra[1].w;
        *(float4*)&Bs[bkk0][bn40] = rb[0];
        *(float4*)&Bs[bkk1][bn41] = rb[1];
        __syncthreads();
        if (k0 + 16 < K) {
            ra[0] = loadA(k0 + 16, 0); ra[1] = loadA(k0 + 16, 1);
            rb[0] = loadB(k0 + 16, 0); rb[1] = loadB(k0 + 16, 1);
        }
#pragma unroll
        for (int kk = 0; kk < 16; ++kk) {
            float4 a = *(const float4*)&As[kk][4 * ty];
            float4 b0 = *(const float4*)&Bs[kk][4 * tx];
            float4 b1 = *(const float4*)&Bs[kk][32 + 4 * tx];
            const float av[4] = {a.x, a.y, a.z, a.w};
            const float b0v[4] = {b0.x, b0.y, b0.z, b0.w};
            const float b1v[4] = {b1.x, b1.y, b1.z, b1.w};
#pragma unroll
            for (int r = 0; r < 4; ++r) {
#pragma unroll
                for (int c = 0; c < 4; ++c) {
                    acc[r][c] = fmaf(av[r], b0v[c], acc[r][c]);
                    acc[r][4 + c] = fmaf(av[r], b1v[c], acc[r][4 + c]);
                }
            }
        }
    }

#pragma unroll
    for (int r = 0; r < 4; ++r) {
        int gm = bm + 4 * ty + r;
        if (gm >= M) continue;
        float o[8];
#pragma unroll
        for (int h = 0; h < 2; ++h) {
#pragma unroll
            for (int c = 0; c < 4; ++c) {
                int gn = bn + 32 * h + 4 * tx + c;
                float v = acc[r][4 * h + c] + bias[gn];
                if constexpr (EPI == 1) v = fmaxf(v, 0.f);
                if constexpr (EPI == 2) {
                    float sc = g[gn] / sqrtf(var[gn] + BN_EPS);
                    v = (v - mu[gn]) * sc + be[gn];
                    v = fmaxf(v, 0.f);
                }
                o[4 * h + c] = v;
            }
        }
        *(float4*)&C[(size_t)gm * N + bn + 4 * tx] = *(float4*)&o[0];
        *(float4*)&C[(size_t)gm * N + bn + 32 + 4 * tx] = *(float4*)&o[4];
    }
}

// ---------------------------------------------------------------------------
// Generic fp32 tiled GEMM (64x64, 256 thr) — kept for small-N heads.
// ---------------------------------------------------------------------------
template <int EPI>
__global__ __launch_bounds__(256) void gemm_f32(
    const float* __restrict__ A, const float* __restrict__ B, float* __restrict__ C,
    int M, int N, int K, const float* __restrict__ bias,
    const float* __restrict__ g, const float* __restrict__ be,
    const float* __restrict__ mu, const float* __restrict__ var) {
    __shared__ float As[16][68];
    __shared__ float Bs[16][68];
    const int bm = blockIdx.x * 64, bn = blockIdx.y * 64;
    const int tid = threadIdx.x, tx = tid & 15, ty = tid >> 4;
    float acc[4][4] = {};
    for (int k0 = 0; k0 < K; k0 += 16) {
#pragma unroll
        for (int i = 0; i < 4; ++i) {
            int e = tid + 256 * i; int kk = e & 15; int m = e >> 4;
            int gm = bm + m;
            As[kk][m] = (gm < M) ? A[(size_t)gm * K + k0 + kk] : 0.f;
        }
#pragma unroll
        for (int i = 0; i < 4; ++i) {
            int e = tid + 256 * i; int n = e & 63; int kk = e >> 6;
            int gn = bn + n;
            Bs[kk][n] = (gn < N) ? B[(size_t)(k0 + kk) * N + gn] : 0.f;
        }
        __syncthreads();
#pragma unroll
        for (int kk = 0; kk < 16; ++kk) {
            float4 ra = *(const float4*)&As[kk][ty * 4];
            float4 rb = *(const float4*)&Bs[kk][tx * 4];
            const float av[4] = {ra.x, ra.y, ra.z, ra.w};
            const float bv[4] = {rb.x, rb.y, rb.z, rb.w};
#pragma unroll
            for (int i = 0; i < 4; ++i)
#pragma unroll
                for (int j = 0; j < 4; ++j) acc[i][j] = fmaf(av[i], bv[j], acc[i][j]);
        }
        __syncthreads();
    }
#pragma unroll
    for (int i = 0; i < 4; ++i) {
        int gm = bm + ty * 4 + i;
        if (gm >= M) continue;
#pragma unroll
        for (int j = 0; j < 4; ++j) {
            int gn = bn + tx * 4 + j;
            if (gn >= N) continue;
            float v = acc[i][j] + bias[gn];
            if constexpr (EPI == 1) v = fmaxf(v, 0.f);
            if constexpr (EPI == 2) {
                float sc = g[gn] / sqrtf(var[gn] + BN_EPS);
                v = (v - mu[gn]) * sc + be[gn];
                v = fmaxf(v, 0.f);
            }
            C[(size_t)gm * N + gn] = v;
        }
    }
}

// ---------------------------------------------------------------------------
// RPN softmax pair -> probs (out0) + sort keys (score_bits<<32 | ~index)
// ---------------------------------------------------------------------------
__global__ __launch_bounds__(256) void rpn_probs_keys(
    const float* __restrict__ cls, float* __restrict__ out0, u64* __restrict__ keys) {
    int i = blockIdx.x * 256 + threadIdx.x;
    if (i >= NA) return;
    float l0 = cls[2 * i], l1 = cls[2 * i + 1];
    float m = fmaxf(l0, l1);
    float e0 = expf(l0 - m), e1 = expf(l1 - m);
    float s = e0 + e1;
    float p0 = e0 / s, p1 = e1 / s;
    out0[2 * i] = p0;
    out0[2 * i + 1] = p1;
    keys[i] = ((u64)__float_as_uint(p1) << 32) | (u64)(0xFFFFFFFFu - (u32)i);
}

// ---------------------------------------------------------------------------
// Exact 6000-th largest key via 8-pass MSB radix select (single block).
// ---------------------------------------------------------------------------
__global__ __launch_bounds__(1024) void radix_select(
    const u64* __restrict__ keys, u64* __restrict__ thresh, u32* __restrict__ counter) {
    __shared__ u32 hist[256];
    __shared__ u64 sPrefix, sMask;
    __shared__ int sRank;
    int tid = threadIdx.x;
    if (tid == 0) { sPrefix = 0; sMask = 0; sRank = PRE_NMS; }
    __syncthreads();
    for (int p = 56; p >= 0; p -= 8) {
        if (tid < 256) hist[tid] = 0;
        __syncthreads();
        u64 pref = sPrefix, msk = sMask;
        for (int i = tid; i < NA; i += 1024) {
            u64 k = keys[i];
            if ((k & msk) == pref) atomicAdd(&hist[(u32)((k >> p) & 255)], 1u);
        }
        __syncthreads();
        if (tid == 0) {
            int cum = 0, rank = sRank, sel = 0;
            for (int d = 255; d >= 0; --d) {
                int c = (int)hist[d];
                if (cum + c >= rank) { sel = d; sRank = rank - cum; break; }
                cum += c;
            }
            sPrefix = pref | ((u64)(u32)sel << p);
            sMask = msk | (0xFFull << p);
        }
        __syncthreads();
    }
    if (tid == 0) { thresh[0] = sPrefix; *counter = 0; }
}

__global__ __launch_bounds__(256) void compact_topk(
    const u64* __restrict__ keys, const u64* __restrict__ thresh,
    u32* __restrict__ counter, u64* __restrict__ skeys) {
    int i = blockIdx.x * 256 + threadIdx.x;
    if (i < SORTN - PRE_NMS) skeys[PRE_NMS + i] = 0;  // pad slots (never hit by atomics)
    if (i >= NA) return;
    u64 k = keys[i];
    if (k >= thresh[0]) {
        u32 pos = atomicAdd(counter, 1u);
        skeys[pos] = k;
    }
}

// Bitonic sort 8192 u64 keys, descending, in 64KB LDS (single block).
__global__ __launch_bounds__(1024) void sort_topk(u64* __restrict__ skeys) {
    __shared__ u64 s[SORTN];
    int tid = threadIdx.x;
    for (int i = tid; i < SORTN; i += 1024) s[i] = skeys[i];
    __syncthreads();
    for (int k = 2; k <= SORTN; k <<= 1) {
        for (int j = k >> 1; j > 0; j >>= 1) {
            for (int i = tid; i < SORTN; i += 1024) {
                int ixj = i ^ j;
                if (ixj > i) {
                    u64 a = s[i], b = s[ixj];
                    bool up = ((i & k) == 0);
                    bool sw = up ? (a < b) : (a > b);  // descending overall
                    if (sw) { s[i] = b; s[ixj] = a; }
                }
            }
            __syncthreads();
        }
    }
    for (int i = tid; i < SORTN; i += 1024) skeys[i] = s[i];
}

// ---------------------------------------------------------------------------
// decode anchors+deltas -> clipped, normalized proposals (6000 x 4)
// ---------------------------------------------------------------------------
__global__ __launch_bounds__(256) void decode_props(
    const u64* __restrict__ skeys, const float* __restrict__ deltas,
    const int* __restrict__ ih, const int* __restrict__ iw, float* __restrict__ props) {
    int i = blockIdx.x * 256 + threadIdx.x;
    if (i >= PRE_NMS) return;
    u32 idx = 0xFFFFFFFFu - (u32)(skeys[i] & 0xFFFFFFFFull);
    float H = (float)(*ih), W = (float)(*iw);
    int a = idx % 9;
    int cell = idx / 9;
    int r = cell >> 6, c = cell & 63;
    float sy = H / 64.0f, sx = W / 64.0f;
    float cy = ((float)r + 0.5f) * sy, cx = ((float)c + 0.5f) * sx;
    const float scales[3] = {64.f, 128.f, 256.f};
    const float ratios[3] = {0.5f, 1.f, 2.f};
    float sq = sqrtf(ratios[a % 3]);
    float scl = scales[a / 3];
    float ah = scl * sq, aw = scl / sq;
    float ay1 = cy - ah * 0.5f, ax1 = cx - aw * 0.5f;
    float h = ah, w = aw;
    float d0 = deltas[(size_t)idx * 4 + 0], d1 = deltas[(size_t)idx * 4 + 1];
    float d2 = deltas[(size_t)idx * 4 + 2], d3 = deltas[(size_t)idx * 4 + 3];
    float ncy = ay1 + 0.5f * h + d0 * h;
    float ncx = ax1 + 0.5f * w + d1 * w;
    float nh = h * expf(d2), nw = w * expf(d3);
    float y1 = ncy - 0.5f * nh, x1 = ncx - 0.5f * nw;
    float y2 = ncy + 0.5f * nh, x2 = ncx + 0.5f * nw;
    props[i * 4 + 0] = fminf(fmaxf(y1, 0.f), H) / H;
    props[i * 4 + 1] = fminf(fmaxf(x1, 0.f), W) / W;
    props[i * 4 + 2] = fminf(fmaxf(y2, 0.f), H) / H;
    props[i * 4 + 3] = fminf(fmaxf(x2, 0.f), W) / W;
}

// ---------------------------------------------------------------------------
// NMS: pairwise suppression bitmask (+ diagonal words), chunked greedy scan.
// ---------------------------------------------------------------------------
__global__ __launch_bounds__(256) void nms_masks(
    const float* __restrict__ props, u64* __restrict__ masks, u64* __restrict__ diag) {
    int i = blockIdx.x * 256 + threadIdx.x;
    int w = blockIdx.y;
    if (i >= PRE_NMS) return;
    float y1 = props[i * 4], x1 = props[i * 4 + 1], y2 = props[i * 4 + 2], x2 = props[i * 4 + 3];
    float ai = (y2 - y1) * (x2 - x1);
    u64 bits = 0;
    int jbase = w * 64;
    for (int b = 0; b < 64; ++b) {
        int j = jbase + b;
        if (j >= PRE_NMS) break;
        float by1 = props[j * 4], bx1 = props[j * 4 + 1], by2 = props[j * 4 + 2], bx2 = props[j * 4 + 3];
        float iy1 = fmaxf(y1, by1), ix1 = fmaxf(x1, bx1);
        float iy2 = fminf(y2, by2), ix2 = fminf(x2, bx2);
        float inter = fmaxf(iy2 - iy1, 0.f) * fmaxf(ix2 - ix1, 0.f);
        float aj = (by2 - by1) * (bx2 - bx1);
        float iou = inter / (ai + aj - inter + 1e-8f);
        if (iou > 0.7f) bits |= (1ull << b);
    }
    masks[(size_t)i * MASKW + w] = bits;
    if (w == (i >> 6)) diag[i] = bits;
}

// Chunked greedy scan: per 64-box chunk, in-register resolve via shfl chain
// over alive bits only; kept-row suppression OR'd in batches of 4. Single wave.
__global__ __launch_bounds__(64) void nms_greedy(
    const u64* __restrict__ masks, const u64* __restrict__ diag,
    int* __restrict__ sel, int* __restrict__ keptOut) {
    __shared__ u64 sdiag[PRE_NMS];
    int lane = threadIdx.x;
    for (int i = lane; i < PRE_NMS; i += 64) sdiag[i] = diag[i];
    __syncthreads();
    u64 rem0 = 0, rem1 = 0;  // lane owns removed-words {lane, lane+64}
    int kept = 0;
    for (int c = 0; c < MASKW && kept < NPROP; ++c) {
        int jbase = c * 64;
        u64 word = (c < 64) ? rem0 : rem1;
        u64 removed = __shfl(word, c & 63);
        int limit = PRE_NMS - jbase;  // >= 48
        u64 alive = ~removed;
        if (limit < 64) alive &= (1ull << limit) - 1ull;
        if (!alive) continue;
        u64 mymask = (jbase + lane < PRE_NMS) ? sdiag[jbase + lane] : 0ull;
        u64 keptbits = 0;
        while (alive && kept < NPROP) {
            int b = __ffsll((long long)alive) - 1;
            alive &= ~(1ull << b);
            u64 m = __shfl(mymask, b);
            keptbits |= (1ull << b);
            if (lane == 0) sel[kept] = jbase + b;
            ++kept;
            alive &= ~m;
        }
        u64 kb = keptbits;
        while (kb) {
            int b0 = __ffsll((long long)kb) - 1; kb &= kb - 1;
            int b1 = -1, b2 = -1, b3 = -1;
            if (kb) { b1 = __ffsll((long long)kb) - 1; kb &= kb - 1; }
            if (kb) { b2 = __ffsll((long long)kb) - 1; kb &= kb - 1; }
            if (kb) { b3 = __ffsll((long long)kb) - 1; kb &= kb - 1; }
            const u64* r0 = masks + (size_t)(jbase + b0) * MASKW;
            u64 a0 = r0[lane];
            u64 c0 = (lane < MASKW - 64) ? r0[lane + 64] : 0ull;
            u64 a1 = 0, c1 = 0, a2 = 0, c2 = 0, a3 = 0, c3 = 0;
            if (b1 >= 0) {
                const u64* r1 = masks + (size_t)(jbase + b1) * MASKW;
                a1 = r1[lane];
                c1 = (lane < MASKW - 64) ? r1[lane + 64] : 0ull;
            }
            if (b2 >= 0) {
                const u64* r2 = masks + (size_t)(jbase + b2) * MASKW;
                a2 = r2[lane];
                c2 = (lane < MASKW - 64) ? r2[lane + 64] : 0ull;
            }
            if (b3 >= 0) {
                const u64* r3 = masks + (size_t)(jbase + b3) * MASKW;
                a3 = r3[lane];
                c3 = (lane < MASKW - 64) ? r3[lane + 64] : 0ull;
            }
            rem0 |= (a0 | a1) | (a2 | a3);
            rem1 |= (c0 | c1) | (c2 | c3);
        }
    }
    if (lane == 0) *keptOut = kept;
}

__global__ __launch_bounds__(256) void write_proposals(
    const float* __restrict__ props, const int* __restrict__ sel,
    const int* __restrict__ keptPtr, float* __restrict__ out2) {
    int i = blockIdx.x * 256 + threadIdx.x;
    if (i >= NPROP * 4) return;
    int p = i >> 2, d = i & 3;
    int kept = *keptPtr;
    out2[i] = (p < kept) ? props[sel[p] * 4 + d] : 0.f;
}

// ---------------------------------------------------------------------------
// ROI-align: 14x14 bilinear samples per proposal -> bf16 rois [1000][196*256]
// ---------------------------------------------------------------------------
__global__ __launch_bounds__(256) void roi_align_k(
    const float* __restrict__ X2, const float* __restrict__ boxes, u16* __restrict__ rois) {
    int p = blockIdx.x;
    int c = threadIdx.x;
    float y1 = boxes[p * 4], x1 = boxes[p * 4 + 1], y2 = boxes[p * 4 + 2], x2 = boxes[p * 4 + 3];
    for (int py = 0; py < 14; ++py) {
        float ty = (float)py / 13.0f;
        float ys = (y1 + ty * (y2 - y1)) * 63.0f;
        float fy = fminf(fmaxf(floorf(ys), 0.f), 62.f);
        int y0 = (int)fy;
        float wy = fminf(fmaxf(ys - fy, 0.f), 1.f);
        for (int px = 0; px < 14; ++px) {
            float tx = (float)px / 13.0f;
            float xs = (x1 + tx * (x2 - x1)) * 63.0f;
            float fx = fminf(fmaxf(floorf(xs), 0.f), 62.f);
            int x0 = (int)fx;
            float wx = fminf(fmaxf(xs - fx, 0.f), 1.f);
            const float* r0 = X2 + (size_t)((y0) * 64 + x0) * 256 + c;
            const float* r1 = r0 + 64 * 256;
            float v00 = r0[0], v01 = r0[256];
            float v10 = r1[0], v11 = r1[256];
            float top = v00 * (1.f - wx) + v01 * wx;
            float bot = v10 * (1.f - wx) + v11 * wx;
            float v = top * (1.f - wy) + bot * wy;
            rois[((size_t)p * 196 + py * 14 + px) * 256 + c] = f2bf(v);
        }
    }
}

// ---------------------------------------------------------------------------
// w_rc1 [50176][1024] f32 -> transposed bf16 [1024][50176] (vectorized)
// ---------------------------------------------------------------------------
__global__ __launch_bounds__(256) void convert_w1(
    const float* __restrict__ Wf, u16* __restrict__ WT) {
    __shared__ u16 tile[64][72];
    int k0 = blockIdx.x * 64, n0 = blockIdx.y * 64;
    int tid = threadIdx.x;
#pragma unroll
    for (int i = 0; i < 4; ++i) {
        int e = tid + 256 * i;  // 0..1023
        int kk = e >> 4, n4 = (e & 15) * 4;
        float4 v = *(const float4*)&Wf[(size_t)(k0 + kk) * 1024 + n0 + n4];
        tile[kk][n4 + 0] = f2bf(v.x);
        tile[kk][n4 + 1] = f2bf(v.y);
        tile[kk][n4 + 2] = f2bf(v.z);
        tile[kk][n4 + 3] = f2bf(v.w);
    }
    __syncthreads();
#pragma unroll
    for (int i = 0; i < 4; ++i) {
        int e = tid + 256 * i;
        int k4 = (e & 15) * 4, nn = e >> 4;
        u16x4 o = {tile[k4 + 0][nn], tile[k4 + 1][nn], tile[k4 + 2][nn], tile[k4 + 3][nn]};
        *(u16x4*)&WT[(size_t)(n0 + nn) * KROI + k0 + k4] = o;
    }
}

// ---------------------------------------------------------------------------
// h1 GEMM: [1000][50176]bf16 @ [50176][1024]bf16 -> split-K partials f32
// ---------------------------------------------------------------------------
__global__ __launch_bounds__(256) void h1_gemm(
    const u16* __restrict__ Abf, const u16* __restrict__ Bbf, float* __restrict__ part) {
    __shared__ u16 As[64][72];
    __shared__ u16 Bs[64][72];
    const int tid = threadIdx.x;
    const int bm = blockIdx.x * 64, bn = blockIdx.y * 64;
    const int ks = blockIdx.z;
    const size_t kbase = (size_t)ks * KCHUNK;
    const int wave = tid >> 6, lane = tid & 63;
    const int wm = (wave >> 1) * 32, wn = (wave & 1) * 32;
    const int fr = lane & 15, fg = lane >> 4;
    f32x4 acc[2][2] = {};
    const int srow = tid >> 2, soff = (tid & 3) * 16;
    const int gm = bm + srow;
    const size_t arow = (size_t)gm * KROI + soff;
    const size_t brow = (size_t)(bn + srow) * KROI + soff;
    for (int k0 = 0; k0 < KCHUNK; k0 += 64) {
        size_t gk = kbase + k0;
        u16x8 a0 = {0, 0, 0, 0, 0, 0, 0, 0}, a1 = {0, 0, 0, 0, 0, 0, 0, 0};
        if (gm < NPROP) {
            a0 = *(const u16x8*)&Abf[arow + gk];
            a1 = *(const u16x8*)&Abf[arow + gk + 8];
        }
        u16x8 b0 = *(const u16x8*)&Bbf[brow + gk];
        u16x8 b1 = *(const u16x8*)&Bbf[brow + gk + 8];
        __syncthreads();
        *(u16x8*)&As[srow][soff] = a0;
        *(u16x8*)&As[srow][soff + 8] = a1;
        *(u16x8*)&Bs[srow][soff] = b0;
        *(u16x8*)&Bs[srow][soff + 8] = b1;
        __syncthreads();
#pragma unroll
        for (int kk = 0; kk < 64; kk += 32) {
            bf16x8 fa0 = ldfrag(&As[wm + fr][kk + fg * 8]);
            bf16x8 fa1 = ldfrag(&As[wm + 16 + fr][kk + fg * 8]);
            bf16x8 fb0 = ldfrag(&Bs[wn + fr][kk + fg * 8]);
            bf16x8 fb1 = ldfrag(&Bs[wn + 16 + fr][kk + fg * 8]);
            acc[0][0] = __builtin_amdgcn_mfma_f32_16x16x32_bf16(fa0, fb0, acc[0][0], 0, 0, 0);
            acc[0][1] = __builtin_amdgcn_mfma_f32_16x16x32_bf16(fa0, fb1, acc[0][1], 0, 0, 0);
            acc[1][0] = __builtin_amdgcn_mfma_f32_16x16x32_bf16(fa1, fb0, acc[1][0], 0, 0, 0);
            acc[1][1] = __builtin_amdgcn_mfma_f32_16x16x32_bf16(fa1, fb1, acc[1][1], 0, 0, 0);
        }
    }
    float* P = part + ((size_t)ks << 20);
#pragma unroll
    for (int fi = 0; fi < 2; ++fi)
#pragma unroll
        for (int fj = 0; fj < 2; ++fj) {
            int r0 = bm + wm + fi * 16 + fg * 4;
            int c0 = bn + wn + fj * 16 + fr;
#pragma unroll
            for (int j = 0; j < 4; ++j) P[(size_t)(r0 + j) * 1024 + c0] = acc[fi][fj][j];
        }
}

__global__ __launch_bounds__(256) void reduce_h1(
    const float* __restrict__ part, const float* __restrict__ bias,
    const float* __restrict__ g, const float* __restrict__ be,
    const float* __restrict__ mu, const float* __restrict__ var, float* __restrict__ h1) {
    int i = blockIdx.x * 256 + threadIdx.x;
    if (i >= NPROP * 1024) return;
    int n = i & 1023, m = i >> 10;
    float s = 0.f;
#pragma unroll
    for (int k = 0; k < KSPLIT; ++k) s += part[((size_t)k << 20) + ((size_t)m << 10) + n];
    s += bias[n];
    float sc = g[n] / sqrtf(var[n] + BN_EPS);
    s = (s - mu[n]) * sc + be[n];
    h1[i] = fmaxf(s, 0.f);
}

__global__ __launch_bounds__(128) void softmax_cls(
    const float* __restrict__ logits, float* __restrict__ out3) {
    __shared__ float sm[128];
    int row = blockIdx.x, t = threadIdx.x;
    float v = (t < 81) ? logits[(size_t)row * 81 + t] : -1e30f;
    sm[t] = v;
    __syncthreads();
    for (int s = 64; s > 0; s >>= 1) {
        if (t < s) sm[t] = fmaxf(sm[t], sm[t + s]);
        __syncthreads();
    }
    float mx = sm[0];
    __syncthreads();
    float e = (t < 81) ? expf(v - mx) : 0.f;
    sm[t] = e;
    __syncthreads();
    for (int s = 64; s > 0; s >>= 1) {
        if (t < s) sm[t] += sm[t + s];
        __syncthreads();
    }
    float denom = sm[0];
    if (t < 81) out3[(size_t)row * 81 + t] = e / denom;
}

// ---------------------------------------------------------------------------
extern "C" void kernel_launch(void* const* d_in, const int* in_sizes, int n_in,
                              void* d_out, int out_size, void* d_ws, size_t ws_size,
                              hipStream_t stream) {
    const float* feature = (const float*)d_in[0];
    const float* w_fpn1 = (const float*)d_in[1];
    const float* b_fpn1 = (const float*)d_in[2];
    const float* w_fpn2 = (const float*)d_in[3];
    const float* b_fpn2 = (const float*)d_in[4];
    const float* w_rpn = (const float*)d_in[5];
    const float* b_rpn = (const float*)d_in[6];
    const float* w_cls = (const float*)d_in[7];
    const float* b_cls = (const float*)d_in[8];
    const float* w_dlt = (const float*)d_in[9];
    const float* b_dlt = (const float*)d_in[10];
    const float* w_rc1 = (const float*)d_in[11];
    const float* b_rc1 = (const float*)d_in[12];
    const float* g1 = (const float*)d_in[13];
    const float* be1 = (const float*)d_in[14];
    const float* m1 = (const float*)d_in[15];
    const float* v1 = (const float*)d_in[16];
    const float* w_rc2 = (const float*)d_in[17];
    const float* b_rc2 = (const float*)d_in[18];
    const float* g2 = (const float*)d_in[19];
    const float* be2 = (const float*)d_in[20];
    const float* m2 = (const float*)d_in[21];
    const float* v2 = (const float*)d_in[22];
    const float* w_log = (const float*)d_in[23];
    const float* b_log = (const float*)d_in[24];
    const float* w_bfc = (const float*)d_in[25];
    const float* b_bfc = (const float*)d_in[26];
    const int* image_h = (const int*)d_in[27];
    const int* image_w = (const int*)d_in[28];
    (void)in_sizes; (void)n_in; (void)out_size; (void)ws_size;

    float* out0 = (float*)d_out;          // rpn_probs  (36864,2)
    float* out1 = out0 + 73728;           // rpn_deltas (36864,4)
    float* out2 = out1 + 147456;          // proposals  (1000,4)
    float* out3 = out2 + 4000;            // cls_probs  (1000,81)
    float* out4 = out3 + 81000;           // box_deltas (1000,324)

    char* wsb = (char*)d_ws;
    size_t off = 0;
    auto take = [&](size_t b) -> void* {
        off = (off + 255) & ~(size_t)255;
        void* p = wsb + off;
        off += b;
        return p;
    };
    float* x1 = (float*)take((size_t)4096 * 256 * 4);
    float* x2 = (float*)take((size_t)4096 * 256 * 4);
    float* shr = (float*)take((size_t)4096 * 512 * 4);
    float* clsT = (float*)take((size_t)NA * 2 * 4);
    u64* keys = (u64*)take((size_t)NA * 8);
    u64* skeys = (u64*)take((size_t)SORTN * 8);
    float* props = (float*)take((size_t)PRE_NMS * 4 * 4);
    u64* masks = (u64*)take((size_t)PRE_NMS * MASKW * 8);
    u64* diag = (u64*)take((size_t)PRE_NMS * 8);
    int* sel = (int*)take((size_t)NPROP * 4);
    u64* misc = (u64*)take(256);
    u32* counter = (u32*)((char*)misc + 8);
    int* keptp = (int*)((char*)misc + 16);
    u16* rois = (u16*)take((size_t)NPROP * KROI * 2);
    u16* wT = (u16*)take((size_t)1024 * KROI * 2);
    float* part = (float*)take((size_t)KSPLIT * 1024 * 1024 * 4);
    float* h1 = (float*)take((size_t)NPROP * 1024 * 4);
    float* h2 = (float*)take((size_t)NPROP * 1024 * 4);
    float* logitsT = (float*)take((size_t)NPROP * 81 * 4);

    // RPN trunk (fp32 for score-ordering fidelity)
    gemm_v2<0, false><<<dim3(64, 4), 128, 0, stream>>>(feature, w_fpn1, x1, 4096, 256, 1024, b_fpn1, nullptr, nullptr, nullptr, nullptr);
    gemm_v2<0, true><<<dim3(64, 4), 128, 0, stream>>>(x1, w_fpn2, x2, 4096, 256, 2304, b_fpn2, nullptr, nullptr, nullptr, nullptr);
    gemm_v2<1, true><<<dim3(64, 8), 128, 0, stream>>>(x2, w_rpn, shr, 4096, 512, 2304, b_rpn, nullptr, nullptr, nullptr, nullptr);
    gemm_f32<0><<<dim3(64, 1), 256, 0, stream>>>(shr, w_cls, clsT, 4096, 18, 512, b_cls, nullptr, nullptr, nullptr, nullptr);
    gemm_f32<0><<<dim3(64, 1), 256, 0, stream>>>(shr, w_dlt, out1, 4096, 36, 512, b_dlt, nullptr, nullptr, nullptr, nullptr);
    rpn_probs_keys<<<dim3(144), 256, 0, stream>>>(clsT, out0, keys);

    // top-6000 (exact lax.top_k order) + NMS
    radix_select<<<1, 1024, 0, stream>>>(keys, misc, counter);
    compact_topk<<<dim3(144), 256, 0, stream>>>(keys, misc, counter, skeys);
    sort_topk<<<1, 1024, 0, stream>>>(skeys);
    decode_props<<<dim3(24), 256, 0, stream>>>(skeys, out1, image_h, image_w, props);
    nms_masks<<<dim3(24, 94), 256, 0, stream>>>(props, masks, diag);
    nms_greedy<<<1, 64, 0, stream>>>(masks, diag, sel, keptp);
    write_proposals<<<dim3(16), 256, 0, stream>>>(props, sel, keptp, out2);

    // ROI head
    convert_w1<<<dim3(784, 16), 256, 0, stream>>>(w_rc1, wT);
    roi_align_k<<<dim3(1000), 256, 0, stream>>>(x2, out2, rois);
    h1_gemm<<<dim3(16, 16, KSPLIT), 256, 0, stream>>>(rois, wT, part);
    reduce_h1<<<dim3(4000), 256, 0, stream>>>(part, b_rc1, g1, be1, m1, v1, h1);
    gemm_v2<2, false><<<dim3(16, 16), 128, 0, stream>>>(h1, w_rc2, h2, 1000, 1024, 1024, b_rc2, g2, be2, m2, v2);
    gemm_f32<0><<<dim3(16, 2), 256, 0, stream>>>(h2, w_log, logitsT, 1000, 81, 1024, b_log, nullptr, nullptr, nullptr, nullptr);
    gemm_f32<0><<<dim3(16, 6), 256, 0, stream>>>(h2, w_bfc, out4, 1000, 324, 1024, b_bfc, nullptr, nullptr, nullptr, nullptr);
    softmax_cls<<<dim3(1000), 128, 0, stream>>>(logitsT, out3);
}

// Round 4
// 1563.702 us; speedup vs baseline: 1.5814x; 1.1046x over previous
//
#include <hip/hip_runtime.h>
#include <hip/hip_bf16.h>

typedef unsigned int u32;
typedef unsigned long long u64;
typedef unsigned short u16;

typedef float f32x4 __attribute__((ext_vector_type(4)));
typedef __bf16 bf16x8 __attribute__((ext_vector_type(8)));
typedef unsigned short u16x8 __attribute__((ext_vector_type(8)));
typedef unsigned short u16x4 __attribute__((ext_vector_type(4)));

#define FH 64
#define NPIX 4096
#define NA 36864          // 64*64*9 anchors
#define PRE_NMS 6000
#define NPROP 1000
#define KROI 50176        // 14*14*256
#define SORTN 8192
#define MASKW 94          // ceil(6000/64)
#define MASKT_STRIDE 6144 // padded row stride of transposed mask
#define KSPLIT 8
#define KCHUNK (KROI / KSPLIT)  // 6272
#define BN_EPS 1e-3f

__device__ __forceinline__ u16 f2bf(float v) {
    __bf16 h = (__bf16)v;
    return __builtin_bit_cast(u16, h);
}
__device__ __forceinline__ bf16x8 ldfrag(const u16* p) {
    return __builtin_bit_cast(bf16x8, *(const u16x8*)p);
}
__device__ __forceinline__ void gload16(const void* g, void* l) {
    __builtin_amdgcn_global_load_lds(
        (const __attribute__((address_space(1))) unsigned int*)g,
        (__attribute__((address_space(3))) unsigned int*)l, 16, 0, 0);
}

// ---------------------------------------------------------------------------
// gemm_v2: fp32 C[M][N] = A[M][K] @ B[K][N], 64x64 tile, 128 thr, 4x8/thread.
// CONV3: A is implicit-im2col of X[64][64][256] with 3x3 SAME halo.
// EPI: 0 = +bias, 1 = relu(+bias), 2 = relu(bn(+bias))
// ---------------------------------------------------------------------------
template <int EPI, bool CONV3>
__global__ __launch_bounds__(128) void gemm_v2(
    const float* __restrict__ A, const float* __restrict__ B, float* __restrict__ C,
    int M, int N, int K, const float* __restrict__ bias,
    const float* __restrict__ g, const float* __restrict__ be,
    const float* __restrict__ mu, const float* __restrict__ var) {
    __shared__ float As[16][68];
    __shared__ float Bs[16][68];
    const int tid = threadIdx.x;
    const int bm = blockIdx.x * 64, bn = blockIdx.y * 64;
    const int tx = tid & 7, ty = tid >> 3;  // ty 0..15

    float4 ra[2], rb[2];
    auto loadA = [&](int k0, int i) -> float4 {
        int e = tid + 128 * i;
        int m = e >> 2, kq = e & 3;
        float4 v = {0.f, 0.f, 0.f, 0.f};
        if (CONV3) {
            int gg = k0 >> 8;
            int dy = gg / 3, dx = gg - 3 * dy;
            int sr = (int)blockIdx.x + dy - 1;
            int sc = m + dx - 1;
            int ch = (k0 & 255) + 4 * kq;
            if (sr >= 0 && sr < 64 && sc >= 0 && sc < 64)
                v = *(const float4*)&A[(size_t)((sr << 6) + sc) * 256 + ch];
        } else {
            int gm = bm + m;
            if (gm < M) v = *(const float4*)&A[(size_t)gm * K + k0 + 4 * kq];
        }
        return v;
    };
    auto loadB = [&](int k0, int i) -> float4 {
        int e = tid + 128 * i;
        int n4 = e & 15, kk = e >> 4;
        return *(const float4*)&B[(size_t)(k0 + kk) * N + bn + 4 * n4];
    };

    ra[0] = loadA(0, 0); ra[1] = loadA(0, 1);
    rb[0] = loadB(0, 0); rb[1] = loadB(0, 1);

    float acc[4][8] = {};
    const int m0 = tid >> 2, kq0 = (tid & 3) * 4;
    const int m1 = (tid + 128) >> 2, kq1 = ((tid + 128) & 3) * 4;
    const int bkk0 = tid >> 4, bn40 = (tid & 15) * 4;
    const int bkk1 = (tid + 128) >> 4, bn41 = ((tid + 128) & 15) * 4;

    for (int k0 = 0; k0 < K; k0 += 16) {
        __syncthreads();
        As[kq0 + 0][m0] = ra[0].x; As[kq0 + 1][m0] = ra[0].y;
        As[kq0 + 2][m0] = ra[0].z; As[kq0 + 3][m0] = ra[0].w;
        As[kq1 + 0][m1] = ra[1].x; As[kq1 + 1][m1] = ra[1].y;
        As[kq1 + 2][m1] = ra[1].z; As[kq1 + 3][m1] = ra[1].w;
        *(float4*)&Bs[bkk0][bn40] = rb[0];
        *(float4*)&Bs[bkk1][bn41] = rb[1];
        __syncthreads();
        if (k0 + 16 < K) {
            ra[0] = loadA(k0 + 16, 0); ra[1] = loadA(k0 + 16, 1);
            rb[0] = loadB(k0 + 16, 0); rb[1] = loadB(k0 + 16, 1);
        }
#pragma unroll
        for (int kk = 0; kk < 16; ++kk) {
            float4 a = *(const float4*)&As[kk][4 * ty];
            float4 b0 = *(const float4*)&Bs[kk][4 * tx];
            float4 b1 = *(const float4*)&Bs[kk][32 + 4 * tx];
            const float av[4] = {a.x, a.y, a.z, a.w};
            const float b0v[4] = {b0.x, b0.y, b0.z, b0.w};
            const float b1v[4] = {b1.x, b1.y, b1.z, b1.w};
#pragma unroll
            for (int r = 0; r < 4; ++r) {
#pragma unroll
                for (int c = 0; c < 4; ++c) {
                    acc[r][c] = fmaf(av[r], b0v[c], acc[r][c]);
                    acc[r][4 + c] = fmaf(av[r], b1v[c], acc[r][4 + c]);
                }
            }
        }
    }

#pragma unroll
    for (int r = 0; r < 4; ++r) {
        int gm = bm + 4 * ty + r;
        if (gm >= M) continue;
        float o[8];
#pragma unroll
        for (int h = 0; h < 2; ++h) {
#pragma unroll
            for (int c = 0; c < 4; ++c) {
                int gn = bn + 32 * h + 4 * tx + c;
                float v = acc[r][4 * h + c] + bias[gn];
                if constexpr (EPI == 1) v = fmaxf(v, 0.f);
                if constexpr (EPI == 2) {
                    float sc = g[gn] / sqrtf(var[gn] + BN_EPS);
                    v = (v - mu[gn]) * sc + be[gn];
                    v = fmaxf(v, 0.f);
                }
                o[4 * h + c] = v;
            }
        }
        *(float4*)&C[(size_t)gm * N + bn + 4 * tx] = *(float4*)&o[0];
        *(float4*)&C[(size_t)gm * N + bn + 32 + 4 * tx] = *(float4*)&o[4];
    }
}

// ---------------------------------------------------------------------------
// Generic fp32 tiled GEMM (64x64, 256 thr) — kept for small-N heads.
// ---------------------------------------------------------------------------
template <int EPI>
__global__ __launch_bounds__(256) void gemm_f32(
    const float* __restrict__ A, const float* __restrict__ B, float* __restrict__ C,
    int M, int N, int K, const float* __restrict__ bias,
    const float* __restrict__ g, const float* __restrict__ be,
    const float* __restrict__ mu, const float* __restrict__ var) {
    __shared__ float As[16][68];
    __shared__ float Bs[16][68];
    const int bm = blockIdx.x * 64, bn = blockIdx.y * 64;
    const int tid = threadIdx.x, tx = tid & 15, ty = tid >> 4;
    float acc[4][4] = {};
    for (int k0 = 0; k0 < K; k0 += 16) {
#pragma unroll
        for (int i = 0; i < 4; ++i) {
            int e = tid + 256 * i; int kk = e & 15; int m = e >> 4;
            int gm = bm + m;
            As[kk][m] = (gm < M) ? A[(size_t)gm * K + k0 + kk] : 0.f;
        }
#pragma unroll
        for (int i = 0; i < 4; ++i) {
            int e = tid + 256 * i; int n = e & 63; int kk = e >> 6;
            int gn = bn + n;
            Bs[kk][n] = (gn < N) ? B[(size_t)(k0 + kk) * N + gn] : 0.f;
        }
        __syncthreads();
#pragma unroll
        for (int kk = 0; kk < 16; ++kk) {
            float4 ra = *(const float4*)&As[kk][ty * 4];
            float4 rb = *(const float4*)&Bs[kk][tx * 4];
            const float av[4] = {ra.x, ra.y, ra.z, ra.w};
            const float bv[4] = {rb.x, rb.y, rb.z, rb.w};
#pragma unroll
            for (int i = 0; i < 4; ++i)
#pragma unroll
                for (int j = 0; j < 4; ++j) acc[i][j] = fmaf(av[i], bv[j], acc[i][j]);
        }
        __syncthreads();
    }
#pragma unroll
    for (int i = 0; i < 4; ++i) {
        int gm = bm + ty * 4 + i;
        if (gm >= M) continue;
#pragma unroll
        for (int j = 0; j < 4; ++j) {
            int gn = bn + tx * 4 + j;
            if (gn >= N) continue;
            float v = acc[i][j] + bias[gn];
            if constexpr (EPI == 1) v = fmaxf(v, 0.f);
            if constexpr (EPI == 2) {
                float sc = g[gn] / sqrtf(var[gn] + BN_EPS);
                v = (v - mu[gn]) * sc + be[gn];
                v = fmaxf(v, 0.f);
            }
            C[(size_t)gm * N + gn] = v;
        }
    }
}

// ---------------------------------------------------------------------------
// RPN softmax pair -> probs (out0) + sort keys (score_bits<<32 | ~index)
// ---------------------------------------------------------------------------
__global__ __launch_bounds__(256) void rpn_probs_keys(
    const float* __restrict__ cls, float* __restrict__ out0, u64* __restrict__ keys) {
    int i = blockIdx.x * 256 + threadIdx.x;
    if (i >= NA) return;
    float l0 = cls[2 * i], l1 = cls[2 * i + 1];
    float m = fmaxf(l0, l1);
    float e0 = expf(l0 - m), e1 = expf(l1 - m);
    float s = e0 + e1;
    float p0 = e0 / s, p1 = e1 / s;
    out0[2 * i] = p0;
    out0[2 * i + 1] = p1;
    keys[i] = ((u64)__float_as_uint(p1) << 32) | (u64)(0xFFFFFFFFu - (u32)i);
}

// ---------------------------------------------------------------------------
// Exact 6000-th largest key via 8-pass MSB radix select (single block).
// ---------------------------------------------------------------------------
__global__ __launch_bounds__(1024) void radix_select(
    const u64* __restrict__ keys, u64* __restrict__ thresh, u32* __restrict__ counter) {
    __shared__ u32 hist[256];
    __shared__ u64 sPrefix, sMask;
    __shared__ int sRank;
    int tid = threadIdx.x;
    if (tid == 0) { sPrefix = 0; sMask = 0; sRank = PRE_NMS; }
    __syncthreads();
    for (int p = 56; p >= 0; p -= 8) {
        if (tid < 256) hist[tid] = 0;
        __syncthreads();
        u64 pref = sPrefix, msk = sMask;
        for (int i = tid; i < NA; i += 1024) {
            u64 k = keys[i];
            if ((k & msk) == pref) atomicAdd(&hist[(u32)((k >> p) & 255)], 1u);
        }
        __syncthreads();
        if (tid == 0) {
            int cum = 0, rank = sRank, sel = 0;
            for (int d = 255; d >= 0; --d) {
                int c = (int)hist[d];
                if (cum + c >= rank) { sel = d; sRank = rank - cum; break; }
                cum += c;
            }
            sPrefix = pref | ((u64)(u32)sel << p);
            sMask = msk | (0xFFull << p);
        }
        __syncthreads();
    }
    if (tid == 0) { thresh[0] = sPrefix; *counter = 0; }
}

__global__ __launch_bounds__(256) void compact_topk(
    const u64* __restrict__ keys, const u64* __restrict__ thresh,
    u32* __restrict__ counter, u64* __restrict__ skeys) {
    int i = blockIdx.x * 256 + threadIdx.x;
    if (i < SORTN - PRE_NMS) skeys[PRE_NMS + i] = 0;  // pad slots (never hit by atomics)
    if (i >= NA) return;
    u64 k = keys[i];
    if (k >= thresh[0]) {
        u32 pos = atomicAdd(counter, 1u);
        skeys[pos] = k;
    }
}

// Bitonic sort 8192 u64 keys, descending, in 64KB LDS (single block).
__global__ __launch_bounds__(1024) void sort_topk(u64* __restrict__ skeys) {
    __shared__ u64 s[SORTN];
    int tid = threadIdx.x;
    for (int i = tid; i < SORTN; i += 1024) s[i] = skeys[i];
    __syncthreads();
    for (int k = 2; k <= SORTN; k <<= 1) {
        for (int j = k >> 1; j > 0; j >>= 1) {
            for (int i = tid; i < SORTN; i += 1024) {
                int ixj = i ^ j;
                if (ixj > i) {
                    u64 a = s[i], b = s[ixj];
                    bool up = ((i & k) == 0);
                    bool sw = up ? (a < b) : (a > b);  // descending overall
                    if (sw) { s[i] = b; s[ixj] = a; }
                }
            }
            __syncthreads();
        }
    }
    for (int i = tid; i < SORTN; i += 1024) skeys[i] = s[i];
}

// ---------------------------------------------------------------------------
// decode anchors+deltas -> clipped, normalized proposals (6000 x 4)
// ---------------------------------------------------------------------------
__global__ __launch_bounds__(256) void decode_props(
    const u64* __restrict__ skeys, const float* __restrict__ deltas,
    const int* __restrict__ ih, const int* __restrict__ iw, float* __restrict__ props) {
    int i = blockIdx.x * 256 + threadIdx.x;
    if (i >= PRE_NMS) return;
    u32 idx = 0xFFFFFFFFu - (u32)(skeys[i] & 0xFFFFFFFFull);
    float H = (float)(*ih), W = (float)(*iw);
    int a = idx % 9;
    int cell = idx / 9;
    int r = cell >> 6, c = cell & 63;
    float sy = H / 64.0f, sx = W / 64.0f;
    float cy = ((float)r + 0.5f) * sy, cx = ((float)c + 0.5f) * sx;
    const float scales[3] = {64.f, 128.f, 256.f};
    const float ratios[3] = {0.5f, 1.f, 2.f};
    float sq = sqrtf(ratios[a % 3]);
    float scl = scales[a / 3];
    float ah = scl * sq, aw = scl / sq;
    float ay1 = cy - ah * 0.5f, ax1 = cx - aw * 0.5f;
    float h = ah, w = aw;
    float d0 = deltas[(size_t)idx * 4 + 0], d1 = deltas[(size_t)idx * 4 + 1];
    float d2 = deltas[(size_t)idx * 4 + 2], d3 = deltas[(size_t)idx * 4 + 3];
    float ncy = ay1 + 0.5f * h + d0 * h;
    float ncx = ax1 + 0.5f * w + d1 * w;
    float nh = h * expf(d2), nw = w * expf(d3);
    float y1 = ncy - 0.5f * nh, x1 = ncx - 0.5f * nw;
    float y2 = ncy + 0.5f * nh, x2 = ncx + 0.5f * nw;
    props[i * 4 + 0] = fminf(fmaxf(y1, 0.f), H) / H;
    props[i * 4 + 1] = fminf(fmaxf(x1, 0.f), W) / W;
    props[i * 4 + 2] = fminf(fmaxf(y2, 0.f), H) / H;
    props[i * 4 + 3] = fminf(fmaxf(x2, 0.f), W) / W;
}

// ---------------------------------------------------------------------------
// NMS: transposed pairwise suppression bitmask + diag words.
// masksT[w][i] = word w of row i (does box i suppress boxes in chunk w).
// ---------------------------------------------------------------------------
__global__ __launch_bounds__(256) void nms_masks(
    const float* __restrict__ props, u64* __restrict__ masksT, u64* __restrict__ diag) {
    int i = blockIdx.x * 256 + threadIdx.x;
    int w = blockIdx.y;
    if (i >= PRE_NMS) return;
    float y1 = props[i * 4], x1 = props[i * 4 + 1], y2 = props[i * 4 + 2], x2 = props[i * 4 + 3];
    float ai = (y2 - y1) * (x2 - x1);
    u64 bits = 0;
    int jbase = w * 64;
    for (int b = 0; b < 64; ++b) {
        int j = jbase + b;
        if (j >= PRE_NMS) break;
        float by1 = props[j * 4], bx1 = props[j * 4 + 1], by2 = props[j * 4 + 2], bx2 = props[j * 4 + 3];
        float iy1 = fmaxf(y1, by1), ix1 = fmaxf(x1, bx1);
        float iy2 = fminf(y2, by2), ix2 = fminf(x2, bx2);
        float inter = fmaxf(iy2 - iy1, 0.f) * fmaxf(ix2 - ix1, 0.f);
        float aj = (by2 - by1) * (bx2 - bx1);
        float iou = inter / (ai + aj - inter + 1e-8f);
        if (iou > 0.7f) bits |= (1ull << b);
    }
    masksT[(size_t)w * MASKT_STRIDE + i] = bits;
    if (w == (i >> 6)) diag[i] = bits;
}

// Lazy chunked greedy: removed[c] gathered fresh per chunk from the kept list
// (parallel over 512 threads), wave-OR reduce, wave-0 shfl-chain resolve.
__global__ __launch_bounds__(512) void nms_greedy(
    const u64* __restrict__ masksT, const u64* __restrict__ diag,
    int* __restrict__ sel, int* __restrict__ keptOut) {
    __shared__ u64 sdiag[PRE_NMS];
    __shared__ int skept[NPROP];
    __shared__ u64 sword[2];
    __shared__ int skcount;
    const int tid = threadIdx.x;
    const int lane = tid & 63;
    for (int i = tid; i < PRE_NMS; i += 512) sdiag[i] = diag[i];
    if (tid == 0) { sword[0] = 0; sword[1] = 0; skcount = 0; }
    __syncthreads();
    int kept = 0;  // meaningful in wave 0 only
    for (int c = 0; c < MASKW; ++c) {
        int keptNow = skcount;
        if (keptNow >= NPROP) break;
        // phase A: gather removed word for chunk c over full kept list
        u64 acc = 0;
        const u64* mrow = masksT + (size_t)c * MASKT_STRIDE;
        for (int t = tid; t < keptNow; t += 512) acc |= mrow[skept[t]];
#pragma unroll
        for (int s = 32; s > 0; s >>= 1) acc |= __shfl_xor(acc, s);
        if (lane == 0 && acc) {
            u32* p = (u32*)&sword[c & 1];
            u32 lo = (u32)acc, hi = (u32)(acc >> 32);
            if (lo) atomicOr(&p[0], lo);
            if (hi) atomicOr(&p[1], hi);
        }
        __syncthreads();
        // phase B: wave 0 resolves chunk c in-register
        if (tid < 64) {
            int jbase = c * 64;
            u64 removed = sword[c & 1];
            int limit = PRE_NMS - jbase;
            u64 alive = ~removed;
            if (limit < 64) alive &= (1ull << limit) - 1ull;
            u64 mymask = (jbase + lane < PRE_NMS) ? sdiag[jbase + lane] : 0ull;
            while (alive && kept < NPROP) {
                int b = __ffsll((long long)alive) - 1;
                alive &= ~(1ull << b);
                u64 m = __shfl(mymask, b);
                if (lane == 0) {
                    sel[kept] = jbase + b;
                    skept[kept] = jbase + b;
                }
                ++kept;
                alive &= ~m;
            }
            if (lane == 0) skcount = kept;
        } else if (tid == 64) {
            sword[(c + 1) & 1] = 0;
        }
        __syncthreads();
    }
    if (tid == 0) *keptOut = skcount;
}

__global__ __launch_bounds__(256) void write_proposals(
    const float* __restrict__ props, const int* __restrict__ sel,
    const int* __restrict__ keptPtr, float* __restrict__ out2) {
    int i = blockIdx.x * 256 + threadIdx.x;
    if (i >= NPROP * 4) return;
    int p = i >> 2, d = i & 3;
    int kept = *keptPtr;
    out2[i] = (p < kept) ? props[sel[p] * 4 + d] : 0.f;
}

// ---------------------------------------------------------------------------
// ROI-align: 14x14 bilinear samples per proposal -> bf16 rois [1000][196*256]
// ---------------------------------------------------------------------------
__global__ __launch_bounds__(256) void roi_align_k(
    const float* __restrict__ X2, const float* __restrict__ boxes, u16* __restrict__ rois) {
    int p = blockIdx.x;
    int c = threadIdx.x;
    float y1 = boxes[p * 4], x1 = boxes[p * 4 + 1], y2 = boxes[p * 4 + 2], x2 = boxes[p * 4 + 3];
    for (int py = 0; py < 14; ++py) {
        float ty = (float)py / 13.0f;
        float ys = (y1 + ty * (y2 - y1)) * 63.0f;
        float fy = fminf(fmaxf(floorf(ys), 0.f), 62.f);
        int y0 = (int)fy;
        float wy = fminf(fmaxf(ys - fy, 0.f), 1.f);
        for (int px = 0; px < 14; ++px) {
            float tx = (float)px / 13.0f;
            float xs = (x1 + tx * (x2 - x1)) * 63.0f;
            float fx = fminf(fmaxf(floorf(xs), 0.f), 62.f);
            int x0 = (int)fx;
            float wx = fminf(fmaxf(xs - fx, 0.f), 1.f);
            const float* r0 = X2 + (size_t)((y0) * 64 + x0) * 256 + c;
            const float* r1 = r0 + 64 * 256;
            float v00 = r0[0], v01 = r0[256];
            float v10 = r1[0], v11 = r1[256];
            float top = v00 * (1.f - wx) + v01 * wx;
            float bot = v10 * (1.f - wx) + v11 * wx;
            float v = top * (1.f - wy) + bot * wy;
            rois[((size_t)p * 196 + py * 14 + px) * 256 + c] = f2bf(v);
        }
    }
}

// ---------------------------------------------------------------------------
// w_rc1 [50176][1024] f32 -> transposed bf16 [1024][50176] (vectorized)
// ---------------------------------------------------------------------------
__global__ __launch_bounds__(256) void convert_w1(
    const float* __restrict__ Wf, u16* __restrict__ WT) {
    __shared__ u16 tile[64][72];
    int k0 = blockIdx.x * 64, n0 = blockIdx.y * 64;
    int tid = threadIdx.x;
#pragma unroll
    for (int i = 0; i < 4; ++i) {
        int e = tid + 256 * i;  // 0..1023
        int kk = e >> 4, n4 = (e & 15) * 4;
        float4 v = *(const float4*)&Wf[(size_t)(k0 + kk) * 1024 + n0 + n4];
        tile[kk][n4 + 0] = f2bf(v.x);
        tile[kk][n4 + 1] = f2bf(v.y);
        tile[kk][n4 + 2] = f2bf(v.z);
        tile[kk][n4 + 3] = f2bf(v.w);
    }
    __syncthreads();
#pragma unroll
    for (int i = 0; i < 4; ++i) {
        int e = tid + 256 * i;
        int k4 = (e & 15) * 4, nn = e >> 4;
        u16x4 o = {tile[k4 + 0][nn], tile[k4 + 1][nn], tile[k4 + 2][nn], tile[k4 + 3][nn]};
        *(u16x4*)&WT[(size_t)(n0 + nn) * KROI + k0 + k4] = o;
    }
}

// ---------------------------------------------------------------------------
// h1 GEMM v2: [1000][50176]bf16 @ [50176][1024]bf16 (B^T rows = out cols)
// 128x128 tile, BK=64, 4 waves x 64x64 quadrant, global_load_lds staging.
// grid (8, 8, KSPLIT); split-K partials f32.
// ---------------------------------------------------------------------------
__global__ __launch_bounds__(256) void h1_gemm(
    const u16* __restrict__ Abf, const u16* __restrict__ Bbf, float* __restrict__ part) {
    __shared__ u16 As[128 * 64];
    __shared__ u16 Bs[128 * 64];
    const int tid = threadIdx.x;
    const int wave = tid >> 6, lane = tid & 63;
    const int bm = blockIdx.x * 128, bn = blockIdx.y * 128;
    const int ks = blockIdx.z;
    const size_t kbase = (size_t)ks * KCHUNK;
    const int wm = (wave >> 1) * 64, wn = (wave & 1) * 64;
    const int fr = lane & 15, fg = lane >> 4;
    // staging: wave stages rows [wave*32, wave*32+32), call i covers 8 rows
    const int srow = wave * 32 + (lane >> 3);
    const int scol = (lane & 7) * 8;
    const size_t abase = (size_t)(bm + srow) * KROI + kbase + scol;
    const size_t bbase = (size_t)(bn + srow) * KROI + kbase + scol;
    u16* AsW = &As[wave * 2048];
    u16* BsW = &Bs[wave * 2048];

    f32x4 acc[4][4] = {};
    for (int k0 = 0; k0 < KCHUNK; k0 += 64) {
        __syncthreads();
#pragma unroll
        for (int i = 0; i < 4; ++i) {
            gload16(Abf + abase + (size_t)(i * 8) * KROI + k0, AsW + i * 512);
            gload16(Bbf + bbase + (size_t)(i * 8) * KROI + k0, BsW + i * 512);
        }
        __syncthreads();
        bf16x8 fa[4][2], fb[4][2];
#pragma unroll
        for (int t = 0; t < 4; ++t) {
#pragma unroll
            for (int s = 0; s < 2; ++s) {
                fa[t][s] = ldfrag(&As[(wm + t * 16 + fr) * 64 + s * 32 + fg * 8]);
                fb[t][s] = ldfrag(&Bs[(wn + t * 16 + fr) * 64 + s * 32 + fg * 8]);
            }
        }
#pragma unroll
        for (int s = 0; s < 2; ++s)
#pragma unroll
            for (int mi = 0; mi < 4; ++mi)
#pragma unroll
                for (int nj = 0; nj < 4; ++nj)
                    acc[mi][nj] = __builtin_amdgcn_mfma_f32_16x16x32_bf16(
                        fa[mi][s], fb[nj][s], acc[mi][nj], 0, 0, 0);
    }
    float* P = part + ((size_t)ks << 20);
#pragma unroll
    for (int mi = 0; mi < 4; ++mi) {
#pragma unroll
        for (int nj = 0; nj < 4; ++nj) {
            int r0 = bm + wm + mi * 16 + fg * 4;
            int c0 = bn + wn + nj * 16 + fr;
#pragma unroll
            for (int j = 0; j < 4; ++j)
                if (r0 + j < NPROP) P[(size_t)(r0 + j) * 1024 + c0] = acc[mi][nj][j];
        }
    }
}

__global__ __launch_bounds__(256) void reduce_h1(
    const float* __restrict__ part, const float* __restrict__ bias,
    const float* __restrict__ g, const float* __restrict__ be,
    const float* __restrict__ mu, const float* __restrict__ var, float* __restrict__ h1) {
    int i = blockIdx.x * 256 + threadIdx.x;
    if (i >= NPROP * 1024) return;
    int n = i & 1023, m = i >> 10;
    float s = 0.f;
#pragma unroll
    for (int k = 0; k < KSPLIT; ++k) s += part[((size_t)k << 20) + ((size_t)m << 10) + n];
    s += bias[n];
    float sc = g[n] / sqrtf(var[n] + BN_EPS);
    s = (s - mu[n]) * sc + be[n];
    h1[i] = fmaxf(s, 0.f);
}

__global__ __launch_bounds__(128) void softmax_cls(
    const float* __restrict__ logits, float* __restrict__ out3) {
    __shared__ float sm[128];
    int row = blockIdx.x, t = threadIdx.x;
    float v = (t < 81) ? logits[(size_t)row * 81 + t] : -1e30f;
    sm[t] = v;
    __syncthreads();
    for (int s = 64; s > 0; s >>= 1) {
        if (t < s) sm[t] = fmaxf(sm[t], sm[t + s]);
        __syncthreads();
    }
    float mx = sm[0];
    __syncthreads();
    float e = (t < 81) ? expf(v - mx) : 0.f;
    sm[t] = e;
    __syncthreads();
    for (int s = 64; s > 0; s >>= 1) {
        if (t < s) sm[t] += sm[t + s];
        __syncthreads();
    }
    float denom = sm[0];
    if (t < 81) out3[(size_t)row * 81 + t] = e / denom;
}

// ---------------------------------------------------------------------------
extern "C" void kernel_launch(void* const* d_in, const int* in_sizes, int n_in,
                              void* d_out, int out_size, void* d_ws, size_t ws_size,
                              hipStream_t stream) {
    const float* feature = (const float*)d_in[0];
    const float* w_fpn1 = (const float*)d_in[1];
    const float* b_fpn1 = (const float*)d_in[2];
    const float* w_fpn2 = (const float*)d_in[3];
    const float* b_fpn2 = (const float*)d_in[4];
    const float* w_rpn = (const float*)d_in[5];
    const float* b_rpn = (const float*)d_in[6];
    const float* w_cls = (const float*)d_in[7];
    const float* b_cls = (const float*)d_in[8];
    const float* w_dlt = (const float*)d_in[9];
    const float* b_dlt = (const float*)d_in[10];
    const float* w_rc1 = (const float*)d_in[11];
    const float* b_rc1 = (const float*)d_in[12];
    const float* g1 = (const float*)d_in[13];
    const float* be1 = (const float*)d_in[14];
    const float* m1 = (const float*)d_in[15];
    const float* v1 = (const float*)d_in[16];
    const float* w_rc2 = (const float*)d_in[17];
    const float* b_rc2 = (const float*)d_in[18];
    const float* g2 = (const float*)d_in[19];
    const float* be2 = (const float*)d_in[20];
    const float* m2 = (const float*)d_in[21];
    const float* v2 = (const float*)d_in[22];
    const float* w_log = (const float*)d_in[23];
    const float* b_log = (const float*)d_in[24];
    const float* w_bfc = (const float*)d_in[25];
    const float* b_bfc = (const float*)d_in[26];
    const int* image_h = (const int*)d_in[27];
    const int* image_w = (const int*)d_in[28];
    (void)in_sizes; (void)n_in; (void)out_size; (void)ws_size;

    float* out0 = (float*)d_out;          // rpn_probs  (36864,2)
    float* out1 = out0 + 73728;           // rpn_deltas (36864,4)
    float* out2 = out1 + 147456;          // proposals  (1000,4)
    float* out3 = out2 + 4000;            // cls_probs  (1000,81)
    float* out4 = out3 + 81000;           // box_deltas (1000,324)

    char* wsb = (char*)d_ws;
    size_t off = 0;
    auto take = [&](size_t b) -> void* {
        off = (off + 255) & ~(size_t)255;
        void* p = wsb + off;
        off += b;
        return p;
    };
    float* x1 = (float*)take((size_t)4096 * 256 * 4);
    float* x2 = (float*)take((size_t)4096 * 256 * 4);
    float* shr = (float*)take((size_t)4096 * 512 * 4);
    float* clsT = (float*)take((size_t)NA * 2 * 4);
    u64* keys = (u64*)take((size_t)NA * 8);
    u64* skeys = (u64*)take((size_t)SORTN * 8);
    float* props = (float*)take((size_t)PRE_NMS * 4 * 4);
    u64* masksT = (u64*)take((size_t)MASKW * MASKT_STRIDE * 8);
    u64* diag = (u64*)take((size_t)PRE_NMS * 8);
    int* sel = (int*)take((size_t)NPROP * 4);
    u64* misc = (u64*)take(256);
    u32* counter = (u32*)((char*)misc + 8);
    int* keptp = (int*)((char*)misc + 16);
    u16* rois = (u16*)take((size_t)NPROP * KROI * 2);
    u16* wT = (u16*)take((size_t)1024 * KROI * 2);
    float* part = (float*)take((size_t)KSPLIT * 1024 * 1024 * 4);
    float* h1 = (float*)take((size_t)NPROP * 1024 * 4);
    float* h2 = (float*)take((size_t)NPROP * 1024 * 4);
    float* logitsT = (float*)take((size_t)NPROP * 81 * 4);

    // RPN trunk (fp32 for score-ordering fidelity)
    gemm_v2<0, false><<<dim3(64, 4), 128, 0, stream>>>(feature, w_fpn1, x1, 4096, 256, 1024, b_fpn1, nullptr, nullptr, nullptr, nullptr);
    gemm_v2<0, true><<<dim3(64, 4), 128, 0, stream>>>(x1, w_fpn2, x2, 4096, 256, 2304, b_fpn2, nullptr, nullptr, nullptr, nullptr);
    gemm_v2<1, true><<<dim3(64, 8), 128, 0, stream>>>(x2, w_rpn, shr, 4096, 512, 2304, b_rpn, nullptr, nullptr, nullptr, nullptr);
    gemm_f32<0><<<dim3(64, 1), 256, 0, stream>>>(shr, w_cls, clsT, 4096, 18, 512, b_cls, nullptr, nullptr, nullptr, nullptr);
    gemm_f32<0><<<dim3(64, 1), 256, 0, stream>>>(shr, w_dlt, out1, 4096, 36, 512, b_dlt, nullptr, nullptr, nullptr, nullptr);
    rpn_probs_keys<<<dim3(144), 256, 0, stream>>>(clsT, out0, keys);

    // top-6000 (exact lax.top_k order) + NMS
    radix_select<<<1, 1024, 0, stream>>>(keys, misc, counter);
    compact_topk<<<dim3(144), 256, 0, stream>>>(keys, misc, counter, skeys);
    sort_topk<<<1, 1024, 0, stream>>>(skeys);
    decode_props<<<dim3(24), 256, 0, stream>>>(skeys, out1, image_h, image_w, props);
    nms_masks<<<dim3(24, 94), 256, 0, stream>>>(props, masksT, diag);
    nms_greedy<<<1, 512, 0, stream>>>(masksT, diag, sel, keptp);
    write_proposals<<<dim3(16), 256, 0, stream>>>(props, sel, keptp, out2);

    // ROI head
    convert_w1<<<dim3(784, 16), 256, 0, stream>>>(w_rc1, wT);
    roi_align_k<<<dim3(1000), 256, 0, stream>>>(x2, out2, rois);
    h1_gemm<<<dim3(8, 8, KSPLIT), 256, 0, stream>>>(rois, wT, part);
    reduce_h1<<<dim3(4000), 256, 0, stream>>>(part, b_rc1, g1, be1, m1, v1, h1);
    gemm_v2<2, false><<<dim3(16, 16), 128, 0, stream>>>(h1, w_rc2, h2, 1000, 1024, 1024, b_rc2, g2, be2, m2, v2);
    gemm_f32<0><<<dim3(16, 2), 256, 0, stream>>>(h2, w_log, logitsT, 1000, 81, 1024, b_log, nullptr, nullptr, nullptr, nullptr);
    gemm_f32<0><<<dim3(16, 6), 256, 0, stream>>>(h2, w_bfc, out4, 1000, 324, 1024, b_bfc, nullptr, nullptr, nullptr, nullptr);
    softmax_cls<<<dim3(1000), 128, 0, stream>>>(logitsT, out3);
}

// Round 5
// 1296.869 us; speedup vs baseline: 1.9068x; 1.2058x over previous
//
#include <hip/hip_runtime.h>
#include <hip/hip_bf16.h>

typedef unsigned int u32;
typedef unsigned long long u64;
typedef unsigned short u16;

typedef float f32x4 __attribute__((ext_vector_type(4)));
typedef __bf16 bf16x8 __attribute__((ext_vector_type(8)));
typedef unsigned short u16x8 __attribute__((ext_vector_type(8)));
typedef unsigned short u16x4 __attribute__((ext_vector_type(4)));

#define NA 36864          // 64*64*9 anchors
#define PRE_NMS 6000
#define NPROP 1000
#define KROI 50176        // 14*14*256
#define SORTN 8192
#define MASKW 94          // ceil(6000/64)
#define MASKT_STRIDE 6144 // padded row stride of transposed mask
#define KSPLIT 8
#define KCHUNK (KROI / KSPLIT)  // 6272
#define BN_EPS 1e-3f

__device__ __forceinline__ u16 f2bf(float v) {
    __bf16 h = (__bf16)v;
    return __builtin_bit_cast(u16, h);
}
__device__ __forceinline__ bf16x8 ldfrag(const u16* p) {
    return __builtin_bit_cast(bf16x8, *(const u16x8*)p);
}
__device__ __forceinline__ void gload16(const void* g, void* l) {
    __builtin_amdgcn_global_load_lds(
        (const __attribute__((address_space(1))) unsigned int*)g,
        (__attribute__((address_space(3))) unsigned int*)l, 16, 0, 0);
}

// ---------------------------------------------------------------------------
// gemm_v3: fp32 partial GEMM. C_part[ks] = A[M][kchunk] @ B[kchunk][N].
// 128x64 tile, 128 threads, 8x8 per thread, double-buffered LDS.
// CONV3: A is implicit im2col of X[64][64][256], 3x3 SAME (K = 2304).
// Requires N%64==0, kchunk%16==0. M guarded.
// ---------------------------------------------------------------------------
template <bool CONV3>
__global__ __launch_bounds__(128) void gemm_v3(
    const float* __restrict__ A, const float* __restrict__ B, float* __restrict__ part,
    int M, int N, int K, int kchunk) {
    __shared__ float As[2][16][132];
    __shared__ float Bs[2][16][68];
    const int tid = threadIdx.x;
    const int bm = blockIdx.x * 128, bn = blockIdx.y * 64;
    const int ks = blockIdx.z;
    const int kbeg = ks * kchunk, kend = kbeg + kchunk;
    const int tx = tid & 7, ty = tid >> 3;
    (void)K;

    float4 ra[4], rb[2];
    auto loadA = [&](int k0, int i) -> float4 {
        int e = tid + 128 * i;  // 0..511
        int m = e >> 2, kq = (e & 3) * 4;
        float4 v = {0.f, 0.f, 0.f, 0.f};
        int gm = bm + m;
        if (CONV3) {
            int gg = k0 >> 8;
            int dy = gg / 3, dx = gg - 3 * dy;
            int pr = gm >> 6, pc = gm & 63;
            int sr = pr + dy - 1, sc = pc + dx - 1;
            int ch = (k0 & 255) + kq;
            if (sr >= 0 && sr < 64 && sc >= 0 && sc < 64)
                v = *(const float4*)&A[(size_t)((sr << 6) + sc) * 256 + ch];
        } else {
            if (gm < M) v = *(const float4*)&A[(size_t)gm * K + k0 + kq];
        }
        return v;
    };
    auto loadB = [&](int k0, int i) -> float4 {
        int e = tid + 128 * i;  // 0..255
        int n4 = (e & 15) * 4, kk = e >> 4;
        return *(const float4*)&B[(size_t)(k0 + kk) * N + bn + n4];
    };
    auto stage = [&](int s) {
#pragma unroll
        for (int i = 0; i < 4; ++i) {
            int e = tid + 128 * i; int m = e >> 2, kq = (e & 3) * 4;
            As[s][kq + 0][m] = ra[i].x; As[s][kq + 1][m] = ra[i].y;
            As[s][kq + 2][m] = ra[i].z; As[s][kq + 3][m] = ra[i].w;
        }
#pragma unroll
        for (int i = 0; i < 2; ++i) {
            int e = tid + 128 * i; int n4 = (e & 15) * 4, kk = e >> 4;
            *(float4*)&Bs[s][kk][n4] = rb[i];
        }
    };

    float acc[8][8] = {};
#pragma unroll
    for (int i = 0; i < 4; ++i) ra[i] = loadA(kbeg, i);
#pragma unroll
    for (int i = 0; i < 2; ++i) rb[i] = loadB(kbeg, i);
    stage(0);
    if (kbeg + 16 < kend) {
#pragma unroll
        for (int i = 0; i < 4; ++i) ra[i] = loadA(kbeg + 16, i);
#pragma unroll
        for (int i = 0; i < 2; ++i) rb[i] = loadB(kbeg + 16, i);
    }
    __syncthreads();
    int s = 0;
    for (int k0 = kbeg; k0 < kend; k0 += 16) {
        if (k0 + 16 < kend) {
            stage(s ^ 1);
            if (k0 + 32 < kend) {
#pragma unroll
                for (int i = 0; i < 4; ++i) ra[i] = loadA(k0 + 32, i);
#pragma unroll
                for (int i = 0; i < 2; ++i) rb[i] = loadB(k0 + 32, i);
            }
        }
#pragma unroll
        for (int kk = 0; kk < 16; ++kk) {
            float4 a0 = *(const float4*)&As[s][kk][8 * ty];
            float4 a1 = *(const float4*)&As[s][kk][8 * ty + 4];
            float4 b0 = *(const float4*)&Bs[s][kk][8 * tx];
            float4 b1 = *(const float4*)&Bs[s][kk][8 * tx + 4];
            const float av[8] = {a0.x, a0.y, a0.z, a0.w, a1.x, a1.y, a1.z, a1.w};
            const float bv[8] = {b0.x, b0.y, b0.z, b0.w, b1.x, b1.y, b1.z, b1.w};
#pragma unroll
            for (int r = 0; r < 8; ++r)
#pragma unroll
                for (int c = 0; c < 8; ++c) acc[r][c] = fmaf(av[r], bv[c], acc[r][c]);
        }
        __syncthreads();
        s ^= 1;
    }
    float* P = part + (size_t)ks * ((size_t)M * N);
#pragma unroll
    for (int r = 0; r < 8; ++r) {
        int gm = bm + 8 * ty + r;
        if (gm >= M) continue;
        *(float4*)&P[(size_t)gm * N + bn + 8 * tx * 0 + 8 * tx] = *(const float4*)&acc[r][0];
        *(float4*)&P[(size_t)gm * N + bn + 8 * tx + 4] = *(const float4*)&acc[r][4];
    }
}

// ---------------------------------------------------------------------------
// reduce K-split partials + bias + epilogue. EPI: 0 none, 1 relu, 2 bn+relu.
// ---------------------------------------------------------------------------
template <int EPI>
__global__ __launch_bounds__(256) void reduce_part(
    const float* __restrict__ part, float* __restrict__ C, int M, int N, int KS,
    const float* __restrict__ bias, const float* __restrict__ g,
    const float* __restrict__ be, const float* __restrict__ mu,
    const float* __restrict__ var) {
    int i = blockIdx.x * 256 + threadIdx.x;
    int total = (M * N) >> 2;
    if (i >= total) return;
    size_t off = (size_t)i * 4;
    int n = (int)(off % (size_t)N);
    size_t slice = (size_t)M * N;
    float4 sv = {0.f, 0.f, 0.f, 0.f};
    for (int k = 0; k < KS; ++k) {
        float4 v = *(const float4*)&part[(size_t)k * slice + off];
        sv.x += v.x; sv.y += v.y; sv.z += v.z; sv.w += v.w;
    }
    float o[4] = {sv.x, sv.y, sv.z, sv.w};
#pragma unroll
    for (int j = 0; j < 4; ++j) {
        float v = o[j] + bias[n + j];
        if constexpr (EPI == 1) v = fmaxf(v, 0.f);
        if constexpr (EPI == 2) {
            float sc = g[n + j] / sqrtf(var[n + j] + BN_EPS);
            v = (v - mu[n + j]) * sc + be[n + j];
            v = fmaxf(v, 0.f);
        }
        o[j] = v;
    }
    *(float4*)&C[off] = *(const float4*)&o[0];
}

// pack w_cls [512][18] + w_dlt [512][36] -> wCat [512][64] (zero pad), bCat[64]
__global__ __launch_bounds__(256) void pack_heads(
    const float* __restrict__ wc, const float* __restrict__ wd,
    const float* __restrict__ bc, const float* __restrict__ bd,
    float* __restrict__ wCat, float* __restrict__ bCat) {
    int i = blockIdx.x * 256 + threadIdx.x;
    if (i < 512 * 64) {
        int k = i >> 6, n = i & 63;
        float v = 0.f;
        if (n < 18) v = wc[k * 18 + n];
        else if (n < 54) v = wd[k * 36 + (n - 18)];
        wCat[i] = v;
    }
    if (i < 64) bCat[i] = (i < 18) ? bc[i] : ((i < 54) ? bd[i - 18] : 0.f);
}

// hcat [4096][64] cols 18..53 -> out1 (rpn_deltas, [4096][36] flat)
__global__ __launch_bounds__(256) void split_dlt(
    const float* __restrict__ hc, float* __restrict__ out1) {
    int i = blockIdx.x * 256 + threadIdx.x;
    if (i >= 4096 * 36) return;
    int cell = i / 36, r = i - cell * 36;
    out1[i] = hc[cell * 64 + 18 + r];
}

// ---------------------------------------------------------------------------
// Generic fp32 tiled GEMM (64x64, 256 thr) — kept for small-N ROI heads.
// ---------------------------------------------------------------------------
template <int EPI>
__global__ __launch_bounds__(256) void gemm_f32(
    const float* __restrict__ A, const float* __restrict__ B, float* __restrict__ C,
    int M, int N, int K, const float* __restrict__ bias,
    const float* __restrict__ g, const float* __restrict__ be,
    const float* __restrict__ mu, const float* __restrict__ var) {
    __shared__ float As[16][68];
    __shared__ float Bs[16][68];
    const int bm = blockIdx.x * 64, bn = blockIdx.y * 64;
    const int tid = threadIdx.x, tx = tid & 15, ty = tid >> 4;
    float acc[4][4] = {};
    for (int k0 = 0; k0 < K; k0 += 16) {
#pragma unroll
        for (int i = 0; i < 4; ++i) {
            int e = tid + 256 * i; int kk = e & 15; int m = e >> 4;
            int gm = bm + m;
            As[kk][m] = (gm < M) ? A[(size_t)gm * K + k0 + kk] : 0.f;
        }
#pragma unroll
        for (int i = 0; i < 4; ++i) {
            int e = tid + 256 * i; int n = e & 63; int kk = e >> 6;
            int gn = bn + n;
            Bs[kk][n] = (gn < N) ? B[(size_t)(k0 + kk) * N + gn] : 0.f;
        }
        __syncthreads();
#pragma unroll
        for (int kk = 0; kk < 16; ++kk) {
            float4 ra = *(const float4*)&As[kk][ty * 4];
            float4 rb = *(const float4*)&Bs[kk][tx * 4];
            const float av[4] = {ra.x, ra.y, ra.z, ra.w};
            const float bv[4] = {rb.x, rb.y, rb.z, rb.w};
#pragma unroll
            for (int i = 0; i < 4; ++i)
#pragma unroll
                for (int j = 0; j < 4; ++j) acc[i][j] = fmaf(av[i], bv[j], acc[i][j]);
        }
        __syncthreads();
    }
#pragma unroll
    for (int i = 0; i < 4; ++i) {
        int gm = bm + ty * 4 + i;
        if (gm >= M) continue;
#pragma unroll
        for (int j = 0; j < 4; ++j) {
            int gn = bn + tx * 4 + j;
            if (gn >= N) continue;
            float v = acc[i][j] + bias[gn];
            if constexpr (EPI == 1) v = fmaxf(v, 0.f);
            if constexpr (EPI == 2) {
                float sc = g[gn] / sqrtf(var[gn] + BN_EPS);
                v = (v - mu[gn]) * sc + be[gn];
                v = fmaxf(v, 0.f);
            }
            C[(size_t)gm * N + gn] = v;
        }
    }
}

// ---------------------------------------------------------------------------
// RPN softmax pair (from hcat [4096][64]) -> probs (out0) + sort keys
// ---------------------------------------------------------------------------
__global__ __launch_bounds__(256) void rpn_probs_keys(
    const float* __restrict__ hc, float* __restrict__ out0, u64* __restrict__ keys) {
    int i = blockIdx.x * 256 + threadIdx.x;
    if (i >= NA) return;
    int cell = i / 9, a = i - cell * 9;
    float l0 = hc[cell * 64 + 2 * a], l1 = hc[cell * 64 + 2 * a + 1];
    float m = fmaxf(l0, l1);
    float e0 = expf(l0 - m), e1 = expf(l1 - m);
    float ssum = e0 + e1;
    float p0 = e0 / ssum, p1 = e1 / ssum;
    out0[2 * i] = p0;
    out0[2 * i + 1] = p1;
    keys[i] = ((u64)__float_as_uint(p1) << 32) | (u64)(0xFFFFFFFFu - (u32)i);
}

// ---------------------------------------------------------------------------
// Exact 6000-th largest key via 8-pass MSB radix select (single block).
// ---------------------------------------------------------------------------
__global__ __launch_bounds__(1024) void radix_select(
    const u64* __restrict__ keys, u64* __restrict__ thresh, u32* __restrict__ counter) {
    __shared__ u32 hist[256];
    __shared__ u64 sPrefix, sMask;
    __shared__ int sRank;
    int tid = threadIdx.x;
    if (tid == 0) { sPrefix = 0; sMask = 0; sRank = PRE_NMS; }
    __syncthreads();
    for (int p = 56; p >= 0; p -= 8) {
        if (tid < 256) hist[tid] = 0;
        __syncthreads();
        u64 pref = sPrefix, msk = sMask;
        for (int i = tid; i < NA; i += 1024) {
            u64 k = keys[i];
            if ((k & msk) == pref) atomicAdd(&hist[(u32)((k >> p) & 255)], 1u);
        }
        __syncthreads();
        if (tid == 0) {
            int cum = 0, rank = sRank, sel = 0;
            for (int d = 255; d >= 0; --d) {
                int c = (int)hist[d];
                if (cum + c >= rank) { sel = d; sRank = rank - cum; break; }
                cum += c;
            }
            sPrefix = pref | ((u64)(u32)sel << p);
            sMask = msk | (0xFFull << p);
        }
        __syncthreads();
    }
    if (tid == 0) { thresh[0] = sPrefix; *counter = 0; }
}

__global__ __launch_bounds__(256) void compact_topk(
    const u64* __restrict__ keys, const u64* __restrict__ thresh,
    u32* __restrict__ counter, u64* __restrict__ skeys) {
    int i = blockIdx.x * 256 + threadIdx.x;
    if (i < SORTN - PRE_NMS) skeys[PRE_NMS + i] = 0;  // pad slots
    if (i >= NA) return;
    u64 k = keys[i];
    if (k >= thresh[0]) {
        u32 pos = atomicAdd(counter, 1u);
        skeys[pos] = k;
    }
}

// Bitonic sort 8192 u64 keys, descending, in 64KB LDS (single block).
__global__ __launch_bounds__(1024) void sort_topk(u64* __restrict__ skeys) {
    __shared__ u64 s[SORTN];
    int tid = threadIdx.x;
    for (int i = tid; i < SORTN; i += 1024) s[i] = skeys[i];
    __syncthreads();
    for (int k = 2; k <= SORTN; k <<= 1) {
        for (int j = k >> 1; j > 0; j >>= 1) {
            for (int i = tid; i < SORTN; i += 1024) {
                int ixj = i ^ j;
                if (ixj > i) {
                    u64 a = s[i], b = s[ixj];
                    bool up = ((i & k) == 0);
                    bool sw = up ? (a < b) : (a > b);
                    if (sw) { s[i] = b; s[ixj] = a; }
                }
            }
            __syncthreads();
        }
    }
    for (int i = tid; i < SORTN; i += 1024) skeys[i] = s[i];
}

// ---------------------------------------------------------------------------
// decode anchors+deltas -> clipped, normalized proposals (6000 x 4)
// ---------------------------------------------------------------------------
__global__ __launch_bounds__(256) void decode_props(
    const u64* __restrict__ skeys, const float* __restrict__ deltas,
    const int* __restrict__ ih, const int* __restrict__ iw, float* __restrict__ props) {
    int i = blockIdx.x * 256 + threadIdx.x;
    if (i >= PRE_NMS) return;
    u32 idx = 0xFFFFFFFFu - (u32)(skeys[i] & 0xFFFFFFFFull);
    float H = (float)(*ih), W = (float)(*iw);
    int a = idx % 9;
    int cell = idx / 9;
    int r = cell >> 6, c = cell & 63;
    float sy = H / 64.0f, sx = W / 64.0f;
    float cy = ((float)r + 0.5f) * sy, cx = ((float)c + 0.5f) * sx;
    const float scales[3] = {64.f, 128.f, 256.f};
    const float ratios[3] = {0.5f, 1.f, 2.f};
    float sq = sqrtf(ratios[a % 3]);
    float scl = scales[a / 3];
    float ah = scl * sq, aw = scl / sq;
    float ay1 = cy - ah * 0.5f, ax1 = cx - aw * 0.5f;
    float h = ah, w = aw;
    float d0 = deltas[(size_t)idx * 4 + 0], d1 = deltas[(size_t)idx * 4 + 1];
    float d2 = deltas[(size_t)idx * 4 + 2], d3 = deltas[(size_t)idx * 4 + 3];
    float ncy = ay1 + 0.5f * h + d0 * h;
    float ncx = ax1 + 0.5f * w + d1 * w;
    float nh = h * expf(d2), nw = w * expf(d3);
    float y1 = ncy - 0.5f * nh, x1 = ncx - 0.5f * nw;
    float y2 = ncy + 0.5f * nh, x2 = ncx + 0.5f * nw;
    props[i * 4 + 0] = fminf(fmaxf(y1, 0.f), H) / H;
    props[i * 4 + 1] = fminf(fmaxf(x1, 0.f), W) / W;
    props[i * 4 + 2] = fminf(fmaxf(y2, 0.f), H) / H;
    props[i * 4 + 3] = fminf(fmaxf(x2, 0.f), W) / W;
}

// ---------------------------------------------------------------------------
// NMS: transposed pairwise suppression bitmask + diag words.
// ---------------------------------------------------------------------------
__global__ __launch_bounds__(256) void nms_masks(
    const float* __restrict__ props, u64* __restrict__ masksT, u64* __restrict__ diag) {
    int i = blockIdx.x * 256 + threadIdx.x;
    int w = blockIdx.y;
    if (i >= PRE_NMS) return;
    float y1 = props[i * 4], x1 = props[i * 4 + 1], y2 = props[i * 4 + 2], x2 = props[i * 4 + 3];
    float ai = (y2 - y1) * (x2 - x1);
    u64 bits = 0;
    int jbase = w * 64;
    for (int b = 0; b < 64; ++b) {
        int j = jbase + b;
        if (j >= PRE_NMS) break;
        float by1 = props[j * 4], bx1 = props[j * 4 + 1], by2 = props[j * 4 + 2], bx2 = props[j * 4 + 3];
        float iy1 = fmaxf(y1, by1), ix1 = fmaxf(x1, bx1);
        float iy2 = fminf(y2, by2), ix2 = fminf(x2, bx2);
        float inter = fmaxf(iy2 - iy1, 0.f) * fmaxf(ix2 - ix1, 0.f);
        float aj = (by2 - by1) * (bx2 - bx1);
        float iou = inter / (ai + aj - inter + 1e-8f);
        if (iou > 0.7f) bits |= (1ull << b);
    }
    masksT[(size_t)w * MASKT_STRIDE + i] = bits;
    if (w == (i >> 6)) diag[i] = bits;
}

// Lazy chunked greedy: removed[c] gathered per chunk from kept list (parallel),
// wave-OR reduce, wave-0 shfl-chain resolve.
__global__ __launch_bounds__(512) void nms_greedy(
    const u64* __restrict__ masksT, const u64* __restrict__ diag,
    int* __restrict__ sel, int* __restrict__ keptOut) {
    __shared__ u64 sdiag[PRE_NMS];
    __shared__ int skept[NPROP];
    __shared__ u64 sword[2];
    __shared__ int skcount;
    const int tid = threadIdx.x;
    const int lane = tid & 63;
    for (int i = tid; i < PRE_NMS; i += 512) sdiag[i] = diag[i];
    if (tid == 0) { sword[0] = 0; sword[1] = 0; skcount = 0; }
    __syncthreads();
    int kept = 0;  // meaningful in wave 0 only
    for (int c = 0; c < MASKW; ++c) {
        int keptNow = skcount;
        if (keptNow >= NPROP) break;
        u64 acc = 0;
        const u64* mrow = masksT + (size_t)c * MASKT_STRIDE;
        for (int t = tid; t < keptNow; t += 512) acc |= mrow[skept[t]];
#pragma unroll
        for (int s = 32; s > 0; s >>= 1) acc |= __shfl_xor(acc, s);
        if (lane == 0 && acc) {
            u32* p = (u32*)&sword[c & 1];
            u32 lo = (u32)acc, hi = (u32)(acc >> 32);
            if (lo) atomicOr(&p[0], lo);
            if (hi) atomicOr(&p[1], hi);
        }
        __syncthreads();
        if (tid < 64) {
            int jbase = c * 64;
            u64 removed = sword[c & 1];
            int limit = PRE_NMS - jbase;
            u64 alive = ~removed;
            if (limit < 64) alive &= (1ull << limit) - 1ull;
            u64 mymask = (jbase + lane < PRE_NMS) ? sdiag[jbase + lane] : 0ull;
            while (alive && kept < NPROP) {
                int b = __ffsll((long long)alive) - 1;
                alive &= ~(1ull << b);
                u64 m = __shfl(mymask, b);
                if (lane == 0) {
                    sel[kept] = jbase + b;
                    skept[kept] = jbase + b;
                }
                ++kept;
                alive &= ~m;
            }
            if (lane == 0) skcount = kept;
        } else if (tid == 64) {
            sword[(c + 1) & 1] = 0;
        }
        __syncthreads();
    }
    if (tid == 0) *keptOut = skcount;
}

__global__ __launch_bounds__(256) void write_proposals(
    const float* __restrict__ props, const int* __restrict__ sel,
    const int* __restrict__ keptPtr, float* __restrict__ out2) {
    int i = blockIdx.x * 256 + threadIdx.x;
    if (i >= NPROP * 4) return;
    int p = i >> 2, d = i & 3;
    int kept = *keptPtr;
    out2[i] = (p < kept) ? props[sel[p] * 4 + d] : 0.f;
}

// ---------------------------------------------------------------------------
// ROI-align: 14x14 bilinear samples per proposal -> bf16 rois [1000][196*256]
// ---------------------------------------------------------------------------
__global__ __launch_bounds__(256) void roi_align_k(
    const float* __restrict__ X2, const float* __restrict__ boxes, u16* __restrict__ rois) {
    int p = blockIdx.x;
    int c = threadIdx.x;
    float y1 = boxes[p * 4], x1 = boxes[p * 4 + 1], y2 = boxes[p * 4 + 2], x2 = boxes[p * 4 + 3];
    for (int py = 0; py < 14; ++py) {
        float ty = (float)py / 13.0f;
        float ys = (y1 + ty * (y2 - y1)) * 63.0f;
        float fy = fminf(fmaxf(floorf(ys), 0.f), 62.f);
        int y0 = (int)fy;
        float wy = fminf(fmaxf(ys - fy, 0.f), 1.f);
        for (int px = 0; px < 14; ++px) {
            float tx = (float)px / 13.0f;
            float xs = (x1 + tx * (x2 - x1)) * 63.0f;
            float fx = fminf(fmaxf(floorf(xs), 0.f), 62.f);
            int x0 = (int)fx;
            float wx = fminf(fmaxf(xs - fx, 0.f), 1.f);
            const float* r0 = X2 + (size_t)((y0) * 64 + x0) * 256 + c;
            const float* r1 = r0 + 64 * 256;
            float v00 = r0[0], v01 = r0[256];
            float v10 = r1[0], v11 = r1[256];
            float top = v00 * (1.f - wx) + v01 * wx;
            float bot = v10 * (1.f - wx) + v11 * wx;
            float v = top * (1.f - wy) + bot * wy;
            rois[((size_t)p * 196 + py * 14 + px) * 256 + c] = f2bf(v);
        }
    }
}

// ---------------------------------------------------------------------------
// w_rc1 [50176][1024] f32 -> transposed bf16 [1024][50176] (vectorized)
// ---------------------------------------------------------------------------
__global__ __launch_bounds__(256) void convert_w1(
    const float* __restrict__ Wf, u16* __restrict__ WT) {
    __shared__ u16 tile[64][72];
    int k0 = blockIdx.x * 64, n0 = blockIdx.y * 64;
    int tid = threadIdx.x;
#pragma unroll
    for (int i = 0; i < 4; ++i) {
        int e = tid + 256 * i;  // 0..1023
        int kk = e >> 4, n4 = (e & 15) * 4;
        float4 v = *(const float4*)&Wf[(size_t)(k0 + kk) * 1024 + n0 + n4];
        tile[kk][n4 + 0] = f2bf(v.x);
        tile[kk][n4 + 1] = f2bf(v.y);
        tile[kk][n4 + 2] = f2bf(v.z);
        tile[kk][n4 + 3] = f2bf(v.w);
    }
    __syncthreads();
#pragma unroll
    for (int i = 0; i < 4; ++i) {
        int e = tid + 256 * i;
        int k4 = (e & 15) * 4, nn = e >> 4;
        u16x4 o = {tile[k4 + 0][nn], tile[k4 + 1][nn], tile[k4 + 2][nn], tile[k4 + 3][nn]};
        *(u16x4*)&WT[(size_t)(n0 + nn) * KROI + k0 + k4] = o;
    }
}

// ---------------------------------------------------------------------------
// h1 GEMM: [1000][50176]bf16 @ [50176][1024]bf16 (B^T rows = out cols)
// 128x128 tile, BK=64, 4 waves x 64x64 quadrant, global_load_lds staging.
// ---------------------------------------------------------------------------
__global__ __launch_bounds__(256) void h1_gemm(
    const u16* __restrict__ Abf, const u16* __restrict__ Bbf, float* __restrict__ part) {
    __shared__ u16 As[128 * 64];
    __shared__ u16 Bs[128 * 64];
    const int tid = threadIdx.x;
    const int wave = tid >> 6, lane = tid & 63;
    const int bm = blockIdx.x * 128, bn = blockIdx.y * 128;
    const int ks = blockIdx.z;
    const size_t kbase = (size_t)ks * KCHUNK;
    const int wm = (wave >> 1) * 64, wn = (wave & 1) * 64;
    const int fr = lane & 15, fg = lane >> 4;
    const int srow = wave * 32 + (lane >> 3);
    const int scol = (lane & 7) * 8;
    const size_t abase = (size_t)(bm + srow) * KROI + kbase + scol;
    const size_t bbase = (size_t)(bn + srow) * KROI + kbase + scol;
    u16* AsW = &As[wave * 2048];
    u16* BsW = &Bs[wave * 2048];

    f32x4 acc[4][4] = {};
    for (int k0 = 0; k0 < KCHUNK; k0 += 64) {
        __syncthreads();
#pragma unroll
        for (int i = 0; i < 4; ++i) {
            gload16(Abf + abase + (size_t)(i * 8) * KROI + k0, AsW + i * 512);
            gload16(Bbf + bbase + (size_t)(i * 8) * KROI + k0, BsW + i * 512);
        }
        __syncthreads();
        bf16x8 fa[4][2], fb[4][2];
#pragma unroll
        for (int t = 0; t < 4; ++t) {
#pragma unroll
            for (int s = 0; s < 2; ++s) {
                fa[t][s] = ldfrag(&As[(wm + t * 16 + fr) * 64 + s * 32 + fg * 8]);
                fb[t][s] = ldfrag(&Bs[(wn + t * 16 + fr) * 64 + s * 32 + fg * 8]);
            }
        }
#pragma unroll
        for (int s = 0; s < 2; ++s)
#pragma unroll
            for (int mi = 0; mi < 4; ++mi)
#pragma unroll
                for (int nj = 0; nj < 4; ++nj)
                    acc[mi][nj] = __builtin_amdgcn_mfma_f32_16x16x32_bf16(
                        fa[mi][s], fb[nj][s], acc[mi][nj], 0, 0, 0);
    }
    float* P = part + ((size_t)ks << 20);
#pragma unroll
    for (int mi = 0; mi < 4; ++mi) {
#pragma unroll
        for (int nj = 0; nj < 4; ++nj) {
            int r0 = bm + wm + mi * 16 + fg * 4;
            int c0 = bn + wn + nj * 16 + fr;
#pragma unroll
            for (int j = 0; j < 4; ++j)
                if (r0 + j < NPROP) P[(size_t)(r0 + j) * 1024 + c0] = acc[mi][nj][j];
        }
    }
}

__global__ __launch_bounds__(256) void reduce_h1(
    const float* __restrict__ part, const float* __restrict__ bias,
    const float* __restrict__ g, const float* __restrict__ be,
    const float* __restrict__ mu, const float* __restrict__ var, float* __restrict__ h1) {
    int i = blockIdx.x * 256 + threadIdx.x;
    if (i >= NPROP * 1024) return;
    int n = i & 1023, m = i >> 10;
    float s = 0.f;
#pragma unroll
    for (int k = 0; k < KSPLIT; ++k) s += part[((size_t)k << 20) + ((size_t)m << 10) + n];
    s += bias[n];
    float sc = g[n] / sqrtf(var[n] + BN_EPS);
    s = (s - mu[n]) * sc + be[n];
    h1[i] = fmaxf(s, 0.f);
}

__global__ __launch_bounds__(128) void softmax_cls(
    const float* __restrict__ logits, float* __restrict__ out3) {
    __shared__ float sm[128];
    int row = blockIdx.x, t = threadIdx.x;
    float v = (t < 81) ? logits[(size_t)row * 81 + t] : -1e30f;
    sm[t] = v;
    __syncthreads();
    for (int s = 64; s > 0; s >>= 1) {
        if (t < s) sm[t] = fmaxf(sm[t], sm[t + s]);
        __syncthreads();
    }
    float mx = sm[0];
    __syncthreads();
    float e = (t < 81) ? expf(v - mx) : 0.f;
    sm[t] = e;
    __syncthreads();
    for (int s = 64; s > 0; s >>= 1) {
        if (t < s) sm[t] += sm[t + s];
        __syncthreads();
    }
    float denom = sm[0];
    if (t < 81) out3[(size_t)row * 81 + t] = e / denom;
}

// ---------------------------------------------------------------------------
extern "C" void kernel_launch(void* const* d_in, const int* in_sizes, int n_in,
                              void* d_out, int out_size, void* d_ws, size_t ws_size,
                              hipStream_t stream) {
    const float* feature = (const float*)d_in[0];
    const float* w_fpn1 = (const float*)d_in[1];
    const float* b_fpn1 = (const float*)d_in[2];
    const float* w_fpn2 = (const float*)d_in[3];
    const float* b_fpn2 = (const float*)d_in[4];
    const float* w_rpn = (const float*)d_in[5];
    const float* b_rpn = (const float*)d_in[6];
    const float* w_cls = (const float*)d_in[7];
    const float* b_cls = (const float*)d_in[8];
    const float* w_dlt = (const float*)d_in[9];
    const float* b_dlt = (const float*)d_in[10];
    const float* w_rc1 = (const float*)d_in[11];
    const float* b_rc1 = (const float*)d_in[12];
    const float* g1 = (const float*)d_in[13];
    const float* be1 = (const float*)d_in[14];
    const float* m1 = (const float*)d_in[15];
    const float* v1 = (const float*)d_in[16];
    const float* w_rc2 = (const float*)d_in[17];
    const float* b_rc2 = (const float*)d_in[18];
    const float* g2 = (const float*)d_in[19];
    const float* be2 = (const float*)d_in[20];
    const float* m2 = (const float*)d_in[21];
    const float* v2 = (const float*)d_in[22];
    const float* w_log = (const float*)d_in[23];
    const float* b_log = (const float*)d_in[24];
    const float* w_bfc = (const float*)d_in[25];
    const float* b_bfc = (const float*)d_in[26];
    const int* image_h = (const int*)d_in[27];
    const int* image_w = (const int*)d_in[28];
    (void)in_sizes; (void)n_in; (void)out_size; (void)ws_size;

    float* out0 = (float*)d_out;          // rpn_probs  (36864,2)
    float* out1 = out0 + 73728;           // rpn_deltas (36864,4)
    float* out2 = out1 + 147456;          // proposals  (1000,4)
    float* out3 = out2 + 4000;            // cls_probs  (1000,81)
    float* out4 = out3 + 81000;           // box_deltas (1000,324)

    char* wsb = (char*)d_ws;
    size_t off = 0;
    auto take = [&](size_t b) -> void* {
        off = (off + 255) & ~(size_t)255;
        void* p = wsb + off;
        off += b;
        return p;
    };
    float* x1 = (float*)take((size_t)4096 * 256 * 4);
    float* x2 = (float*)take((size_t)4096 * 256 * 4);
    float* shr = (float*)take((size_t)4096 * 512 * 4);
    float* hcat = (float*)take((size_t)4096 * 64 * 4);
    float* wCat = (float*)take((size_t)512 * 64 * 4);
    float* bCat = (float*)take((size_t)64 * 4);
    u64* keys = (u64*)take((size_t)NA * 8);
    u64* skeys = (u64*)take((size_t)SORTN * 8);
    float* props = (float*)take((size_t)PRE_NMS * 4 * 4);
    u64* masksT = (u64*)take((size_t)MASKW * MASKT_STRIDE * 8);
    u64* diag = (u64*)take((size_t)PRE_NMS * 8);
    int* sel = (int*)take((size_t)NPROP * 4);
    u64* misc = (u64*)take(256);
    u32* counter = (u32*)((char*)misc + 8);
    int* keptp = (int*)((char*)misc + 16);
    u16* rois = (u16*)take((size_t)NPROP * KROI * 2);
    u16* wT = (u16*)take((size_t)1024 * KROI * 2);
    float* part = (float*)take((size_t)KSPLIT * 1024 * 1024 * 4);  // 32 MB scratch
    float* h1 = (float*)take((size_t)NPROP * 1024 * 4);
    float* h2 = (float*)take((size_t)NPROP * 1024 * 4);
    float* logitsT = (float*)take((size_t)NPROP * 81 * 4);

    // ---- RPN trunk (fp32, K-split + fused reduce epilogues) ----
    gemm_v3<false><<<dim3(32, 4, 8), 128, 0, stream>>>(feature, w_fpn1, part, 4096, 256, 1024, 128);
    reduce_part<0><<<dim3(1024), 256, 0, stream>>>(part, x1, 4096, 256, 8, b_fpn1, nullptr, nullptr, nullptr, nullptr);
    gemm_v3<true><<<dim3(32, 4, 8), 128, 0, stream>>>(x1, w_fpn2, part, 4096, 256, 2304, 288);
    reduce_part<0><<<dim3(1024), 256, 0, stream>>>(part, x2, 4096, 256, 8, b_fpn2, nullptr, nullptr, nullptr, nullptr);
    gemm_v3<true><<<dim3(32, 8, 4), 128, 0, stream>>>(x2, w_rpn, part, 4096, 512, 2304, 576);
    reduce_part<1><<<dim3(2048), 256, 0, stream>>>(part, shr, 4096, 512, 4, b_rpn, nullptr, nullptr, nullptr, nullptr);
    // merged cls+dlt heads: [4096][512] @ [512][64]
    pack_heads<<<dim3(128), 256, 0, stream>>>(w_cls, w_dlt, b_cls, b_dlt, wCat, bCat);
    gemm_v3<false><<<dim3(32, 1, 8), 128, 0, stream>>>(shr, wCat, part, 4096, 64, 512, 64);
    reduce_part<0><<<dim3(256), 256, 0, stream>>>(part, hcat, 4096, 64, 8, bCat, nullptr, nullptr, nullptr, nullptr);
    split_dlt<<<dim3(576), 256, 0, stream>>>(hcat, out1);
    rpn_probs_keys<<<dim3(144), 256, 0, stream>>>(hcat, out0, keys);

    // ---- top-6000 (exact lax.top_k order) + NMS ----
    radix_select<<<1, 1024, 0, stream>>>(keys, misc, counter);
    compact_topk<<<dim3(144), 256, 0, stream>>>(keys, misc, counter, skeys);
    sort_topk<<<1, 1024, 0, stream>>>(skeys);
    decode_props<<<dim3(24), 256, 0, stream>>>(skeys, out1, image_h, image_w, props);
    nms_masks<<<dim3(24, 94), 256, 0, stream>>>(props, masksT, diag);
    nms_greedy<<<1, 512, 0, stream>>>(masksT, diag, sel, keptp);
    write_proposals<<<dim3(16), 256, 0, stream>>>(props, sel, keptp, out2);

    // ---- ROI head ----
    convert_w1<<<dim3(784, 16), 256, 0, stream>>>(w_rc1, wT);
    roi_align_k<<<dim3(1000), 256, 0, stream>>>(x2, out2, rois);
    h1_gemm<<<dim3(8, 8, KSPLIT), 256, 0, stream>>>(rois, wT, part);
    reduce_h1<<<dim3(4000), 256, 0, stream>>>(part, b_rc1, g1, be1, m1, v1, h1);
    gemm_v3<false><<<dim3(8, 16, 2), 128, 0, stream>>>(h1, w_rc2, part, 1000, 1024, 1024, 512);
    reduce_part<2><<<dim3(1000), 256, 0, stream>>>(part, h2, 1000, 1024, 2, b_rc2, g2, be2, m2, v2);
    gemm_f32<0><<<dim3(16, 2), 256, 0, stream>>>(h2, w_log, logitsT, 1000, 81, 1024, b_log, nullptr, nullptr, nullptr, nullptr);
    gemm_f32<0><<<dim3(16, 6), 256, 0, stream>>>(h2, w_bfc, out4, 1000, 324, 1024, b_bfc, nullptr, nullptr, nullptr, nullptr);
    softmax_cls<<<dim3(1000), 128, 0, stream>>>(logitsT, out3);
}

// Round 6
// 1288.911 us; speedup vs baseline: 1.9185x; 1.0062x over previous
//
#include <hip/hip_runtime.h>
#include <hip/hip_bf16.h>

typedef unsigned int u32;
typedef unsigned long long u64;
typedef unsigned short u16;

typedef float f32x4 __attribute__((ext_vector_type(4)));
typedef __bf16 bf16x8 __attribute__((ext_vector_type(8)));
typedef unsigned short u16x8 __attribute__((ext_vector_type(8)));
typedef unsigned short u16x4 __attribute__((ext_vector_type(4)));

#define NA 36864          // 64*64*9 anchors
#define PRE_NMS 6000
#define NPROP 1000
#define KROI 50176        // 14*14*256
#define SORTN 8192
#define MASKW 94          // ceil(6000/64)
#define MASKT_STRIDE 6144 // padded row stride of transposed mask
#define KSPLIT 8
#define KCHUNK (KROI / KSPLIT)  // 6272
#define BN_EPS 1e-3f

__device__ __forceinline__ u16 f2bf(float v) {
    __bf16 h = (__bf16)v;
    return __builtin_bit_cast(u16, h);
}
__device__ __forceinline__ bf16x8 ldfrag(const u16* p) {
    return __builtin_bit_cast(bf16x8, *(const u16x8*)p);
}
__device__ __forceinline__ void gload16(const void* g, void* l) {
    __builtin_amdgcn_global_load_lds(
        (const __attribute__((address_space(1))) unsigned int*)g,
        (__attribute__((address_space(3))) unsigned int*)l, 16, 0, 0);
}

// ---------------------------------------------------------------------------
// gemm_v3: fp32 partial GEMM. C_part[ks] = A[M][kchunk] @ B[kchunk][N].
// 128x64 tile, 128 threads, 8x8 per thread, double-buffered LDS.
// CONV3: A is implicit im2col of X[64][64][256], 3x3 SAME (K = 2304).
// ---------------------------------------------------------------------------
template <bool CONV3>
__global__ __launch_bounds__(128) void gemm_v3(
    const float* __restrict__ A, const float* __restrict__ B, float* __restrict__ part,
    int M, int N, int K, int kchunk) {
    __shared__ float As[2][16][132];
    __shared__ float Bs[2][16][68];
    const int tid = threadIdx.x;
    const int bm = blockIdx.x * 128, bn = blockIdx.y * 64;
    const int ks = blockIdx.z;
    const int kbeg = ks * kchunk, kend = kbeg + kchunk;
    const int tx = tid & 7, ty = tid >> 3;
    (void)K;

    float4 ra[4], rb[2];
    auto loadA = [&](int k0, int i) -> float4 {
        int e = tid + 128 * i;  // 0..511
        int m = e >> 2, kq = (e & 3) * 4;
        float4 v = {0.f, 0.f, 0.f, 0.f};
        int gm = bm + m;
        if (CONV3) {
            int gg = k0 >> 8;
            int dy = gg / 3, dx = gg - 3 * dy;
            int pr = gm >> 6, pc = gm & 63;
            int sr = pr + dy - 1, sc = pc + dx - 1;
            int ch = (k0 & 255) + kq;
            if (sr >= 0 && sr < 64 && sc >= 0 && sc < 64)
                v = *(const float4*)&A[(size_t)((sr << 6) + sc) * 256 + ch];
        } else {
            if (gm < M) v = *(const float4*)&A[(size_t)gm * K + k0 + kq];
        }
        return v;
    };
    auto loadB = [&](int k0, int i) -> float4 {
        int e = tid + 128 * i;  // 0..255
        int n4 = (e & 15) * 4, kk = e >> 4;
        return *(const float4*)&B[(size_t)(k0 + kk) * N + bn + n4];
    };
    auto stage = [&](int s) {
#pragma unroll
        for (int i = 0; i < 4; ++i) {
            int e = tid + 128 * i; int m = e >> 2, kq = (e & 3) * 4;
            As[s][kq + 0][m] = ra[i].x; As[s][kq + 1][m] = ra[i].y;
            As[s][kq + 2][m] = ra[i].z; As[s][kq + 3][m] = ra[i].w;
        }
#pragma unroll
        for (int i = 0; i < 2; ++i) {
            int e = tid + 128 * i; int n4 = (e & 15) * 4, kk = e >> 4;
            *(float4*)&Bs[s][kk][n4] = rb[i];
        }
    };

    float acc[8][8] = {};
#pragma unroll
    for (int i = 0; i < 4; ++i) ra[i] = loadA(kbeg, i);
#pragma unroll
    for (int i = 0; i < 2; ++i) rb[i] = loadB(kbeg, i);
    stage(0);
    if (kbeg + 16 < kend) {
#pragma unroll
        for (int i = 0; i < 4; ++i) ra[i] = loadA(kbeg + 16, i);
#pragma unroll
        for (int i = 0; i < 2; ++i) rb[i] = loadB(kbeg + 16, i);
    }
    __syncthreads();
    int s = 0;
    for (int k0 = kbeg; k0 < kend; k0 += 16) {
        if (k0 + 16 < kend) {
            stage(s ^ 1);
            if (k0 + 32 < kend) {
#pragma unroll
                for (int i = 0; i < 4; ++i) ra[i] = loadA(k0 + 32, i);
#pragma unroll
                for (int i = 0; i < 2; ++i) rb[i] = loadB(k0 + 32, i);
            }
        }
#pragma unroll
        for (int kk = 0; kk < 16; ++kk) {
            float4 a0 = *(const float4*)&As[s][kk][8 * ty];
            float4 a1 = *(const float4*)&As[s][kk][8 * ty + 4];
            float4 b0 = *(const float4*)&Bs[s][kk][8 * tx];
            float4 b1 = *(const float4*)&Bs[s][kk][8 * tx + 4];
            const float av[8] = {a0.x, a0.y, a0.z, a0.w, a1.x, a1.y, a1.z, a1.w};
            const float bv[8] = {b0.x, b0.y, b0.z, b0.w, b1.x, b1.y, b1.z, b1.w};
#pragma unroll
            for (int r = 0; r < 8; ++r)
#pragma unroll
                for (int c = 0; c < 8; ++c) acc[r][c] = fmaf(av[r], bv[c], acc[r][c]);
        }
        __syncthreads();
        s ^= 1;
    }
    float* P = part + (size_t)ks * ((size_t)M * N);
#pragma unroll
    for (int r = 0; r < 8; ++r) {
        int gm = bm + 8 * ty + r;
        if (gm >= M) continue;
        *(float4*)&P[(size_t)gm * N + bn + 8 * tx] = *(const float4*)&acc[r][0];
        *(float4*)&P[(size_t)gm * N + bn + 8 * tx + 4] = *(const float4*)&acc[r][4];
    }
}

// ---------------------------------------------------------------------------
// reduce K-split partials + bias + epilogue. EPI: 0 none, 1 relu, 2 bn+relu.
// ---------------------------------------------------------------------------
template <int EPI>
__global__ __launch_bounds__(256) void reduce_part(
    const float* __restrict__ part, float* __restrict__ C, int M, int N, int KS,
    const float* __restrict__ bias, const float* __restrict__ g,
    const float* __restrict__ be, const float* __restrict__ mu,
    const float* __restrict__ var) {
    int i = blockIdx.x * 256 + threadIdx.x;
    int total = (M * N) >> 2;
    if (i >= total) return;
    size_t off = (size_t)i * 4;
    int n = (int)(off % (size_t)N);
    size_t slice = (size_t)M * N;
    float4 sv = {0.f, 0.f, 0.f, 0.f};
    for (int k = 0; k < KS; ++k) {
        float4 v = *(const float4*)&part[(size_t)k * slice + off];
        sv.x += v.x; sv.y += v.y; sv.z += v.z; sv.w += v.w;
    }
    float o[4] = {sv.x, sv.y, sv.z, sv.w};
#pragma unroll
    for (int j = 0; j < 4; ++j) {
        float v = o[j] + bias[n + j];
        if constexpr (EPI == 1) v = fmaxf(v, 0.f);
        if constexpr (EPI == 2) {
            float sc = g[n + j] / sqrtf(var[n + j] + BN_EPS);
            v = (v - mu[n + j]) * sc + be[n + j];
            v = fmaxf(v, 0.f);
        }
        o[j] = v;
    }
    *(float4*)&C[off] = *(const float4*)&o[0];
}

// pack w_cls [512][18] + w_dlt [512][36] -> wCat [512][64] (zero pad), bCat[64]
__global__ __launch_bounds__(256) void pack_heads(
    const float* __restrict__ wc, const float* __restrict__ wd,
    const float* __restrict__ bc, const float* __restrict__ bd,
    float* __restrict__ wCat, float* __restrict__ bCat) {
    int i = blockIdx.x * 256 + threadIdx.x;
    if (i < 512 * 64) {
        int k = i >> 6, n = i & 63;
        float v = 0.f;
        if (n < 18) v = wc[k * 18 + n];
        else if (n < 54) v = wd[k * 36 + (n - 18)];
        wCat[i] = v;
    }
    if (i < 64) bCat[i] = (i < 18) ? bc[i] : ((i < 54) ? bd[i - 18] : 0.f);
}

// hcat [4096][64] cols 18..53 -> out1 (rpn_deltas, [4096][36] flat)
__global__ __launch_bounds__(256) void split_dlt(
    const float* __restrict__ hc, float* __restrict__ out1) {
    int i = blockIdx.x * 256 + threadIdx.x;
    if (i >= 4096 * 36) return;
    int cell = i / 36, r = i - cell * 36;
    out1[i] = hc[cell * 64 + 18 + r];
}

// ---------------------------------------------------------------------------
// Generic fp32 tiled GEMM (64x64, 256 thr) — kept for small-N ROI heads.
// ---------------------------------------------------------------------------
template <int EPI>
__global__ __launch_bounds__(256) void gemm_f32(
    const float* __restrict__ A, const float* __restrict__ B, float* __restrict__ C,
    int M, int N, int K, const float* __restrict__ bias,
    const float* __restrict__ g, const float* __restrict__ be,
    const float* __restrict__ mu, const float* __restrict__ var) {
    __shared__ float As[16][68];
    __shared__ float Bs[16][68];
    const int bm = blockIdx.x * 64, bn = blockIdx.y * 64;
    const int tid = threadIdx.x, tx = tid & 15, ty = tid >> 4;
    float acc[4][4] = {};
    for (int k0 = 0; k0 < K; k0 += 16) {
#pragma unroll
        for (int i = 0; i < 4; ++i) {
            int e = tid + 256 * i; int kk = e & 15; int m = e >> 4;
            int gm = bm + m;
            As[kk][m] = (gm < M) ? A[(size_t)gm * K + k0 + kk] : 0.f;
        }
#pragma unroll
        for (int i = 0; i < 4; ++i) {
            int e = tid + 256 * i; int n = e & 63; int kk = e >> 6;
            int gn = bn + n;
            Bs[kk][n] = (gn < N) ? B[(size_t)(k0 + kk) * N + gn] : 0.f;
        }
        __syncthreads();
#pragma unroll
        for (int kk = 0; kk < 16; ++kk) {
            float4 ra = *(const float4*)&As[kk][ty * 4];
            float4 rb = *(const float4*)&Bs[kk][tx * 4];
            const float av[4] = {ra.x, ra.y, ra.z, ra.w};
            const float bv[4] = {rb.x, rb.y, rb.z, rb.w};
#pragma unroll
            for (int i = 0; i < 4; ++i)
#pragma unroll
                for (int j = 0; j < 4; ++j) acc[i][j] = fmaf(av[i], bv[j], acc[i][j]);
        }
        __syncthreads();
    }
#pragma unroll
    for (int i = 0; i < 4; ++i) {
        int gm = bm + ty * 4 + i;
        if (gm >= M) continue;
#pragma unroll
        for (int j = 0; j < 4; ++j) {
            int gn = bn + tx * 4 + j;
            if (gn >= N) continue;
            float v = acc[i][j] + bias[gn];
            if constexpr (EPI == 1) v = fmaxf(v, 0.f);
            if constexpr (EPI == 2) {
                float sc = g[gn] / sqrtf(var[gn] + BN_EPS);
                v = (v - mu[gn]) * sc + be[gn];
                v = fmaxf(v, 0.f);
            }
            C[(size_t)gm * N + gn] = v;
        }
    }
}

// ---------------------------------------------------------------------------
// RPN softmax pair (from hcat [4096][64]) -> probs (out0) + sort keys
// ---------------------------------------------------------------------------
__global__ __launch_bounds__(256) void rpn_probs_keys(
    const float* __restrict__ hc, float* __restrict__ out0, u64* __restrict__ keys) {
    int i = blockIdx.x * 256 + threadIdx.x;
    if (i >= NA) return;
    int cell = i / 9, a = i - cell * 9;
    float l0 = hc[cell * 64 + 2 * a], l1 = hc[cell * 64 + 2 * a + 1];
    float m = fmaxf(l0, l1);
    float e0 = expf(l0 - m), e1 = expf(l1 - m);
    float ssum = e0 + e1;
    float p0 = e0 / ssum, p1 = e1 / ssum;
    out0[2 * i] = p0;
    out0[2 * i + 1] = p1;
    keys[i] = ((u64)__float_as_uint(p1) << 32) | (u64)(0xFFFFFFFFu - (u32)i);
}

// ---------------------------------------------------------------------------
// Exact 6000-th largest key via 8-pass MSB radix select (single block).
// ---------------------------------------------------------------------------
__global__ __launch_bounds__(1024) void radix_select(
    const u64* __restrict__ keys, u64* __restrict__ thresh, u32* __restrict__ counter) {
    __shared__ u32 hist[256];
    __shared__ u64 sPrefix, sMask;
    __shared__ int sRank;
    int tid = threadIdx.x;
    if (tid == 0) { sPrefix = 0; sMask = 0; sRank = PRE_NMS; }
    __syncthreads();
    for (int p = 56; p >= 0; p -= 8) {
        if (tid < 256) hist[tid] = 0;
        __syncthreads();
        u64 pref = sPrefix, msk = sMask;
        for (int i = tid; i < NA; i += 1024) {
            u64 k = keys[i];
            if ((k & msk) == pref) atomicAdd(&hist[(u32)((k >> p) & 255)], 1u);
        }
        __syncthreads();
        if (tid == 0) {
            int cum = 0, rank = sRank, sel = 0;
            for (int d = 255; d >= 0; --d) {
                int c = (int)hist[d];
                if (cum + c >= rank) { sel = d; sRank = rank - cum; break; }
                cum += c;
            }
            sPrefix = pref | ((u64)(u32)sel << p);
            sMask = msk | (0xFFull << p);
        }
        __syncthreads();
    }
    if (tid == 0) { thresh[0] = sPrefix; *counter = 0; }
}

__global__ __launch_bounds__(256) void compact_topk(
    const u64* __restrict__ keys, const u64* __restrict__ thresh,
    u32* __restrict__ counter, u64* __restrict__ skeys) {
    int i = blockIdx.x * 256 + threadIdx.x;
    if (i < SORTN - PRE_NMS) skeys[PRE_NMS + i] = 0;  // pad slots
    if (i >= NA) return;
    u64 k = keys[i];
    if (k >= thresh[0]) {
        u32 pos = atomicAdd(counter, 1u);
        skeys[pos] = k;
    }
}

// Bitonic sort 8192 u64 keys, descending, in 64KB LDS (single block).
__global__ __launch_bounds__(1024) void sort_topk(u64* __restrict__ skeys) {
    __shared__ u64 s[SORTN];
    int tid = threadIdx.x;
    for (int i = tid; i < SORTN; i += 1024) s[i] = skeys[i];
    __syncthreads();
    for (int k = 2; k <= SORTN; k <<= 1) {
        for (int j = k >> 1; j > 0; j >>= 1) {
            for (int i = tid; i < SORTN; i += 1024) {
                int ixj = i ^ j;
                if (ixj > i) {
                    u64 a = s[i], b = s[ixj];
                    bool up = ((i & k) == 0);
                    bool sw = up ? (a < b) : (a > b);
                    if (sw) { s[i] = b; s[ixj] = a; }
                }
            }
            __syncthreads();
        }
    }
    for (int i = tid; i < SORTN; i += 1024) skeys[i] = s[i];
}

// ---------------------------------------------------------------------------
// decode anchors+deltas -> clipped, normalized proposals (6000 x 4)
// ---------------------------------------------------------------------------
__global__ __launch_bounds__(256) void decode_props(
    const u64* __restrict__ skeys, const float* __restrict__ deltas,
    const int* __restrict__ ih, const int* __restrict__ iw, float* __restrict__ props) {
    int i = blockIdx.x * 256 + threadIdx.x;
    if (i >= PRE_NMS) return;
    u32 idx = 0xFFFFFFFFu - (u32)(skeys[i] & 0xFFFFFFFFull);
    float H = (float)(*ih), W = (float)(*iw);
    int a = idx % 9;
    int cell = idx / 9;
    int r = cell >> 6, c = cell & 63;
    float sy = H / 64.0f, sx = W / 64.0f;
    float cy = ((float)r + 0.5f) * sy, cx = ((float)c + 0.5f) * sx;
    const float scales[3] = {64.f, 128.f, 256.f};
    const float ratios[3] = {0.5f, 1.f, 2.f};
    float sq = sqrtf(ratios[a % 3]);
    float scl = scales[a / 3];
    float ah = scl * sq, aw = scl / sq;
    float ay1 = cy - ah * 0.5f, ax1 = cx - aw * 0.5f;
    float h = ah, w = aw;
    float d0 = deltas[(size_t)idx * 4 + 0], d1 = deltas[(size_t)idx * 4 + 1];
    float d2 = deltas[(size_t)idx * 4 + 2], d3 = deltas[(size_t)idx * 4 + 3];
    float ncy = ay1 + 0.5f * h + d0 * h;
    float ncx = ax1 + 0.5f * w + d1 * w;
    float nh = h * expf(d2), nw = w * expf(d3);
    float y1 = ncy - 0.5f * nh, x1 = ncx - 0.5f * nw;
    float y2 = ncy + 0.5f * nh, x2 = ncx + 0.5f * nw;
    props[i * 4 + 0] = fminf(fmaxf(y1, 0.f), H) / H;
    props[i * 4 + 1] = fminf(fmaxf(x1, 0.f), W) / W;
    props[i * 4 + 2] = fminf(fmaxf(y2, 0.f), H) / H;
    props[i * 4 + 3] = fminf(fmaxf(x2, 0.f), W) / W;
}

// ---------------------------------------------------------------------------
// NMS: transposed pairwise suppression bitmask + diag words.
// ---------------------------------------------------------------------------
__global__ __launch_bounds__(256) void nms_masks(
    const float* __restrict__ props, u64* __restrict__ masksT, u64* __restrict__ diag) {
    int i = blockIdx.x * 256 + threadIdx.x;
    int w = blockIdx.y;
    if (i >= PRE_NMS) return;
    float y1 = props[i * 4], x1 = props[i * 4 + 1], y2 = props[i * 4 + 2], x2 = props[i * 4 + 3];
    float ai = (y2 - y1) * (x2 - x1);
    u64 bits = 0;
    int jbase = w * 64;
    for (int b = 0; b < 64; ++b) {
        int j = jbase + b;
        if (j >= PRE_NMS) break;
        float by1 = props[j * 4], bx1 = props[j * 4 + 1], by2 = props[j * 4 + 2], bx2 = props[j * 4 + 3];
        float iy1 = fmaxf(y1, by1), ix1 = fmaxf(x1, bx1);
        float iy2 = fminf(y2, by2), ix2 = fminf(x2, bx2);
        float inter = fmaxf(iy2 - iy1, 0.f) * fmaxf(ix2 - ix1, 0.f);
        float aj = (by2 - by1) * (bx2 - bx1);
        float iou = inter / (ai + aj - inter + 1e-8f);
        if (iou > 0.7f) bits |= (1ull << b);
    }
    masksT[(size_t)w * MASKT_STRIDE + i] = bits;
    if (w == (i >> 6)) diag[i] = bits;
}

// Lazy chunked greedy: removed[c] gathered per chunk from kept list (parallel),
// wave-OR reduce, wave-0 shfl-chain resolve.
__global__ __launch_bounds__(512) void nms_greedy(
    const u64* __restrict__ masksT, const u64* __restrict__ diag,
    int* __restrict__ sel, int* __restrict__ keptOut) {
    __shared__ u64 sdiag[PRE_NMS];
    __shared__ int skept[NPROP];
    __shared__ u64 sword[2];
    __shared__ int skcount;
    const int tid = threadIdx.x;
    const int lane = tid & 63;
    for (int i = tid; i < PRE_NMS; i += 512) sdiag[i] = diag[i];
    if (tid == 0) { sword[0] = 0; sword[1] = 0; skcount = 0; }
    __syncthreads();
    int kept = 0;  // meaningful in wave 0 only
    for (int c = 0; c < MASKW; ++c) {
        int keptNow = skcount;
        if (keptNow >= NPROP) break;
        u64 acc = 0;
        const u64* mrow = masksT + (size_t)c * MASKT_STRIDE;
        for (int t = tid; t < keptNow; t += 512) acc |= mrow[skept[t]];
#pragma unroll
        for (int s = 32; s > 0; s >>= 1) acc |= __shfl_xor(acc, s);
        if (lane == 0 && acc) {
            u32* p = (u32*)&sword[c & 1];
            u32 lo = (u32)acc, hi = (u32)(acc >> 32);
            if (lo) atomicOr(&p[0], lo);
            if (hi) atomicOr(&p[1], hi);
        }
        __syncthreads();
        if (tid < 64) {
            int jbase = c * 64;
            u64 removed = sword[c & 1];
            int limit = PRE_NMS - jbase;
            u64 alive = ~removed;
            if (limit < 64) alive &= (1ull << limit) - 1ull;
            u64 mymask = (jbase + lane < PRE_NMS) ? sdiag[jbase + lane] : 0ull;
            while (alive && kept < NPROP) {
                int b = __ffsll((long long)alive) - 1;
                alive &= ~(1ull << b);
                u64 m = __shfl(mymask, b);
                if (lane == 0) {
                    sel[kept] = jbase + b;
                    skept[kept] = jbase + b;
                }
                ++kept;
                alive &= ~m;
            }
            if (lane == 0) skcount = kept;
        } else if (tid == 64) {
            sword[(c + 1) & 1] = 0;
        }
        __syncthreads();
    }
    if (tid == 0) *keptOut = skcount;
}

__global__ __launch_bounds__(256) void write_proposals(
    const float* __restrict__ props, const int* __restrict__ sel,
    const int* __restrict__ keptPtr, float* __restrict__ out2) {
    int i = blockIdx.x * 256 + threadIdx.x;
    if (i >= NPROP * 4) return;
    int p = i >> 2, d = i & 3;
    int kept = *keptPtr;
    out2[i] = (p < kept) ? props[sel[p] * 4 + d] : 0.f;
}

// ---------------------------------------------------------------------------
// ROI-align: 14x14 bilinear samples per proposal -> bf16 rois [1000][196*256]
// ---------------------------------------------------------------------------
__global__ __launch_bounds__(256) void roi_align_k(
    const float* __restrict__ X2, const float* __restrict__ boxes, u16* __restrict__ rois) {
    int p = blockIdx.x;
    int c = threadIdx.x;
    float y1 = boxes[p * 4], x1 = boxes[p * 4 + 1], y2 = boxes[p * 4 + 2], x2 = boxes[p * 4 + 3];
    for (int py = 0; py < 14; ++py) {
        float ty = (float)py / 13.0f;
        float ys = (y1 + ty * (y2 - y1)) * 63.0f;
        float fy = fminf(fmaxf(floorf(ys), 0.f), 62.f);
        int y0 = (int)fy;
        float wy = fminf(fmaxf(ys - fy, 0.f), 1.f);
        for (int px = 0; px < 14; ++px) {
            float tx = (float)px / 13.0f;
            float xs = (x1 + tx * (x2 - x1)) * 63.0f;
            float fx = fminf(fmaxf(floorf(xs), 0.f), 62.f);
            int x0 = (int)fx;
            float wx = fminf(fmaxf(xs - fx, 0.f), 1.f);
            const float* r0 = X2 + (size_t)((y0) * 64 + x0) * 256 + c;
            const float* r1 = r0 + 64 * 256;
            float v00 = r0[0], v01 = r0[256];
            float v10 = r1[0], v11 = r1[256];
            float top = v00 * (1.f - wx) + v01 * wx;
            float bot = v10 * (1.f - wx) + v11 * wx;
            float v = top * (1.f - wy) + bot * wy;
            rois[((size_t)p * 196 + py * 14 + px) * 256 + c] = f2bf(v);
        }
    }
}

// ---------------------------------------------------------------------------
// w_rc1 [50176][1024] f32 -> transposed bf16 [1024][50176] (vectorized)
// ---------------------------------------------------------------------------
__global__ __launch_bounds__(256) void convert_w1(
    const float* __restrict__ Wf, u16* __restrict__ WT) {
    __shared__ u16 tile[64][72];
    int k0 = blockIdx.x * 64, n0 = blockIdx.y * 64;
    int tid = threadIdx.x;
#pragma unroll
    for (int i = 0; i < 4; ++i) {
        int e = tid + 256 * i;  // 0..1023
        int kk = e >> 4, n4 = (e & 15) * 4;
        float4 v = *(const float4*)&Wf[(size_t)(k0 + kk) * 1024 + n0 + n4];
        tile[kk][n4 + 0] = f2bf(v.x);
        tile[kk][n4 + 1] = f2bf(v.y);
        tile[kk][n4 + 2] = f2bf(v.z);
        tile[kk][n4 + 3] = f2bf(v.w);
    }
    __syncthreads();
#pragma unroll
    for (int i = 0; i < 4; ++i) {
        int e = tid + 256 * i;
        int k4 = (e & 15) * 4, nn = e >> 4;
        u16x4 o = {tile[k4 + 0][nn], tile[k4 + 1][nn], tile[k4 + 2][nn], tile[k4 + 3][nn]};
        *(u16x4*)&WT[(size_t)(n0 + nn) * KROI + k0 + k4] = o;
    }
}

// ---------------------------------------------------------------------------
// h1 GEMM: [1000][50176]bf16 @ [50176][1024]bf16 (B^T rows = out cols)
// 128x128 tile, BK=64, 4 waves x 64x64 quadrant, global_load_lds staging.
// T2 XOR-swizzle via pre-swizzled global source (rule #21: swizzle BOTH the
// staged source chunk and the ds_read chunk with chunk ^= (row & 7)).
// ---------------------------------------------------------------------------
__global__ __launch_bounds__(256) void h1_gemm(
    const u16* __restrict__ Abf, const u16* __restrict__ Bbf, float* __restrict__ part) {
    __shared__ u16 As[128 * 64];
    __shared__ u16 Bs[128 * 64];
    const int tid = threadIdx.x;
    const int wave = tid >> 6, lane = tid & 63;
    const int bm = blockIdx.x * 128, bn = blockIdx.y * 128;
    const int ks = blockIdx.z;
    const size_t kbase = (size_t)ks * KCHUNK;
    const int wm = (wave >> 1) * 64, wn = (wave & 1) * 64;
    const int fr = lane & 15, fg = lane >> 4;
    // staging: wave stages rows [wave*32, wave*32+32), call i covers 8 rows.
    // Pre-swizzled source: lane sources chunk (lane&7)^(lane>>3) so that
    // LDS[row][c] holds global[row][c ^ (row&7)]  (row&7 == lane>>3).
    const int srow = wave * 32 + (lane >> 3);
    const int scol = (((lane & 7) ^ (lane >> 3)) * 8);
    const size_t abase = (size_t)(bm + srow) * KROI + kbase + scol;
    const size_t bbase = (size_t)(bn + srow) * KROI + kbase + scol;
    u16* AsW = &As[wave * 2048];
    u16* BsW = &Bs[wave * 2048];

    f32x4 acc[4][4] = {};
    for (int k0 = 0; k0 < KCHUNK; k0 += 64) {
        __syncthreads();
#pragma unroll
        for (int i = 0; i < 4; ++i) {
            gload16(Abf + abase + (size_t)(i * 8) * KROI + k0, AsW + i * 512);
            gload16(Bbf + bbase + (size_t)(i * 8) * KROI + k0, BsW + i * 512);
        }
        __syncthreads();
        bf16x8 fa[4][2], fb[4][2];
#pragma unroll
        for (int t = 0; t < 4; ++t) {
#pragma unroll
            for (int s = 0; s < 2; ++s) {
                // logical chunk = s*4+fg; swizzled with row&7 = fr&7
                int ca = ((s * 4 + fg) ^ (fr & 7)) * 8;
                fa[t][s] = ldfrag(&As[(wm + t * 16 + fr) * 64 + ca]);
                fb[t][s] = ldfrag(&Bs[(wn + t * 16 + fr) * 64 + ca]);
            }
        }
#pragma unroll
        for (int s = 0; s < 2; ++s)
#pragma unroll
            for (int mi = 0; mi < 4; ++mi)
#pragma unroll
                for (int nj = 0; nj < 4; ++nj)
                    acc[mi][nj] = __builtin_amdgcn_mfma_f32_16x16x32_bf16(
                        fa[mi][s], fb[nj][s], acc[mi][nj], 0, 0, 0);
    }
    float* P = part + ((size_t)ks << 20);
#pragma unroll
    for (int mi = 0; mi < 4; ++mi) {
#pragma unroll
        for (int nj = 0; nj < 4; ++nj) {
            int r0 = bm + wm + mi * 16 + fg * 4;
            int c0 = bn + wn + nj * 16 + fr;
#pragma unroll
            for (int j = 0; j < 4; ++j)
                if (r0 + j < NPROP) P[(size_t)(r0 + j) * 1024 + c0] = acc[mi][nj][j];
        }
    }
}

__global__ __launch_bounds__(256) void reduce_h1(
    const float* __restrict__ part, const float* __restrict__ bias,
    const float* __restrict__ g, const float* __restrict__ be,
    const float* __restrict__ mu, const float* __restrict__ var, float* __restrict__ h1) {
    int i = blockIdx.x * 256 + threadIdx.x;
    if (i >= NPROP * 1024) return;
    int n = i & 1023, m = i >> 10;
    float s = 0.f;
#pragma unroll
    for (int k = 0; k < KSPLIT; ++k) s += part[((size_t)k << 20) + ((size_t)m << 10) + n];
    s += bias[n];
    float sc = g[n] / sqrtf(var[n] + BN_EPS);
    s = (s - mu[n]) * sc + be[n];
    h1[i] = fmaxf(s, 0.f);
}

__global__ __launch_bounds__(128) void softmax_cls(
    const float* __restrict__ logits, float* __restrict__ out3) {
    __shared__ float sm[128];
    int row = blockIdx.x, t = threadIdx.x;
    float v = (t < 81) ? logits[(size_t)row * 81 + t] : -1e30f;
    sm[t] = v;
    __syncthreads();
    for (int s = 64; s > 0; s >>= 1) {
        if (t < s) sm[t] = fmaxf(sm[t], sm[t + s]);
        __syncthreads();
    }
    float mx = sm[0];
    __syncthreads();
    float e = (t < 81) ? expf(v - mx) : 0.f;
    sm[t] = e;
    __syncthreads();
    for (int s = 64; s > 0; s >>= 1) {
        if (t < s) sm[t] += sm[t + s];
        __syncthreads();
    }
    float denom = sm[0];
    if (t < 81) out3[(size_t)row * 81 + t] = e / denom;
}

// ---------------------------------------------------------------------------
extern "C" void kernel_launch(void* const* d_in, const int* in_sizes, int n_in,
                              void* d_out, int out_size, void* d_ws, size_t ws_size,
                              hipStream_t stream) {
    const float* feature = (const float*)d_in[0];
    const float* w_fpn1 = (const float*)d_in[1];
    const float* b_fpn1 = (const float*)d_in[2];
    const float* w_fpn2 = (const float*)d_in[3];
    const float* b_fpn2 = (const float*)d_in[4];
    const float* w_rpn = (const float*)d_in[5];
    const float* b_rpn = (const float*)d_in[6];
    const float* w_cls = (const float*)d_in[7];
    const float* b_cls = (const float*)d_in[8];
    const float* w_dlt = (const float*)d_in[9];
    const float* b_dlt = (const float*)d_in[10];
    const float* w_rc1 = (const float*)d_in[11];
    const float* b_rc1 = (const float*)d_in[12];
    const float* g1 = (const float*)d_in[13];
    const float* be1 = (const float*)d_in[14];
    const float* m1 = (const float*)d_in[15];
    const float* v1 = (const float*)d_in[16];
    const float* w_rc2 = (const float*)d_in[17];
    const float* b_rc2 = (const float*)d_in[18];
    const float* g2 = (const float*)d_in[19];
    const float* be2 = (const float*)d_in[20];
    const float* m2 = (const float*)d_in[21];
    const float* v2 = (const float*)d_in[22];
    const float* w_log = (const float*)d_in[23];
    const float* b_log = (const float*)d_in[24];
    const float* w_bfc = (const float*)d_in[25];
    const float* b_bfc = (const float*)d_in[26];
    const int* image_h = (const int*)d_in[27];
    const int* image_w = (const int*)d_in[28];
    (void)in_sizes; (void)n_in; (void)out_size; (void)ws_size;

    float* out0 = (float*)d_out;          // rpn_probs  (36864,2)
    float* out1 = out0 + 73728;           // rpn_deltas (36864,4)
    float* out2 = out1 + 147456;          // proposals  (1000,4)
    float* out3 = out2 + 4000;            // cls_probs  (1000,81)
    float* out4 = out3 + 81000;           // box_deltas (1000,324)

    char* wsb = (char*)d_ws;
    size_t off = 0;
    auto take = [&](size_t b) -> void* {
        off = (off + 255) & ~(size_t)255;
        void* p = wsb + off;
        off += b;
        return p;
    };
    float* x1 = (float*)take((size_t)4096 * 256 * 4);
    float* x2 = (float*)take((size_t)4096 * 256 * 4);
    float* shr = (float*)take((size_t)4096 * 512 * 4);
    float* hcat = (float*)take((size_t)4096 * 64 * 4);
    float* wCat = (float*)take((size_t)512 * 64 * 4);
    float* bCat = (float*)take((size_t)64 * 4);
    u64* keys = (u64*)take((size_t)NA * 8);
    u64* skeys = (u64*)take((size_t)SORTN * 8);
    float* props = (float*)take((size_t)PRE_NMS * 4 * 4);
    u64* masksT = (u64*)take((size_t)MASKW * MASKT_STRIDE * 8);
    u64* diag = (u64*)take((size_t)PRE_NMS * 8);
    int* sel = (int*)take((size_t)NPROP * 4);
    u64* misc = (u64*)take(256);
    u32* counter = (u32*)((char*)misc + 8);
    int* keptp = (int*)((char*)misc + 16);
    u16* rois = (u16*)take((size_t)NPROP * KROI * 2);
    u16* wT = (u16*)take((size_t)1024 * KROI * 2);
    float* part = (float*)take((size_t)KSPLIT * 1024 * 1024 * 4);  // 32 MB scratch
    float* h1 = (float*)take((size_t)NPROP * 1024 * 4);
    float* h2 = (float*)take((size_t)NPROP * 1024 * 4);
    float* logitsT = (float*)take((size_t)NPROP * 81 * 4);

    // ---- RPN trunk (fp32, K-split + fused reduce epilogues) ----
    gemm_v3<false><<<dim3(32, 4, 8), 128, 0, stream>>>(feature, w_fpn1, part, 4096, 256, 1024, 128);
    reduce_part<0><<<dim3(1024), 256, 0, stream>>>(part, x1, 4096, 256, 8, b_fpn1, nullptr, nullptr, nullptr, nullptr);
    gemm_v3<true><<<dim3(32, 4, 8), 128, 0, stream>>>(x1, w_fpn2, part, 4096, 256, 2304, 288);
    reduce_part<0><<<dim3(1024), 256, 0, stream>>>(part, x2, 4096, 256, 8, b_fpn2, nullptr, nullptr, nullptr, nullptr);
    gemm_v3<true><<<dim3(32, 8, 4), 128, 0, stream>>>(x2, w_rpn, part, 4096, 512, 2304, 576);
    reduce_part<1><<<dim3(2048), 256, 0, stream>>>(part, shr, 4096, 512, 4, b_rpn, nullptr, nullptr, nullptr, nullptr);
    // merged cls+dlt heads: [4096][512] @ [512][64]
    pack_heads<<<dim3(128), 256, 0, stream>>>(w_cls, w_dlt, b_cls, b_dlt, wCat, bCat);
    gemm_v3<false><<<dim3(32, 1, 8), 128, 0, stream>>>(shr, wCat, part, 4096, 64, 512, 64);
    reduce_part<0><<<dim3(256), 256, 0, stream>>>(part, hcat, 4096, 64, 8, bCat, nullptr, nullptr, nullptr, nullptr);
    split_dlt<<<dim3(576), 256, 0, stream>>>(hcat, out1);
    rpn_probs_keys<<<dim3(144), 256, 0, stream>>>(hcat, out0, keys);

    // ---- top-6000 (exact lax.top_k order) + NMS ----
    radix_select<<<1, 1024, 0, stream>>>(keys, misc, counter);
    compact_topk<<<dim3(144), 256, 0, stream>>>(keys, misc, counter, skeys);
    sort_topk<<<1, 1024, 0, stream>>>(skeys);
    decode_props<<<dim3(24), 256, 0, stream>>>(skeys, out1, image_h, image_w, props);
    nms_masks<<<dim3(24, 94), 256, 0, stream>>>(props, masksT, diag);
    nms_greedy<<<1, 512, 0, stream>>>(masksT, diag, sel, keptp);
    write_proposals<<<dim3(16), 256, 0, stream>>>(props, sel, keptp, out2);

    // ---- ROI head ----
    convert_w1<<<dim3(784, 16), 256, 0, stream>>>(w_rc1, wT);
    roi_align_k<<<dim3(1000), 256, 0, stream>>>(x2, out2, rois);
    h1_gemm<<<dim3(8, 8, KSPLIT), 256, 0, stream>>>(rois, wT, part);
    reduce_h1<<<dim3(4000), 256, 0, stream>>>(part, b_rc1, g1, be1, m1, v1, h1);
    gemm_v3<false><<<dim3(8, 16, 2), 128, 0, stream>>>(h1, w_rc2, part, 1000, 1024, 1024, 512);
    reduce_part<2><<<dim3(1000), 256, 0, stream>>>(part, h2, 1000, 1024, 2, b_rc2, g2, be2, m2, v2);
    gemm_f32<0><<<dim3(16, 2), 256, 0, stream>>>(h2, w_log, logitsT, 1000, 81, 1024, b_log, nullptr, nullptr, nullptr, nullptr);
    gemm_f32<0><<<dim3(16, 6), 256, 0, stream>>>(h2, w_bfc, out4, 1000, 324, 1024, b_bfc, nullptr, nullptr, nullptr, nullptr);
    softmax_cls<<<dim3(1000), 128, 0, stream>>>(logitsT, out3);
}